// Round 13
// baseline (3687.352 us; speedup 1.0000x reference)
//
#include <hip/hip_runtime.h>

typedef __bf16 bf16_t;
typedef __bf16 bf16x8 __attribute__((ext_vector_type(8)));
typedef __bf16 bf16x4 __attribute__((ext_vector_type(4)));
typedef float  f32x4  __attribute__((ext_vector_type(4)));

#define AS1 __attribute__((address_space(1)))
#define AS3 __attribute__((address_space(3)))

#define CMAX 16.0f   // static softmax max bound (true scores |s| ~ 1)

// ---------------------------------------------------------------------------
// Unified NT GEMM:  D[m][n] = sum_k A[m][k] * Bt[n][k]   (both K-contiguous)
// OUTMN=0: store C[n][m] (activation layout), OUTMN=1: store C[m][n].
// CONV=1: K = 3*CIN fused tap loop. CONV=2: split-K, blockIdx.z = tap,
//         K = CIN, writes bf16 partial at C + (tap<<22) + n*512 + m.
// ---------------------------------------------------------------------------
template<int BM, int BN, int OUTMN, int CONV, int BIAS, int RELU, int MASK>
__global__ __launch_bounds__(256)
void gemm_nt(const bf16_t* __restrict__ A, const bf16_t* __restrict__ B,
             bf16_t* __restrict__ C, const float* __restrict__ bias,
             const float* __restrict__ mask, const bf16_t* __restrict__ zpage,
             int K, int lda, int ldb, int ldc, int CIN,
             long sAb, long sAh, long sBb, long sBh, long sCb, long sCh)
{
    constexpr int BK = 32;
    __shared__ bf16_t As[BM * BK];
    __shared__ bf16_t Bs[BN * BK];
    const int z = blockIdx.z;
    int tap0 = 0;
    if constexpr (CONV == 2) {
        tap0 = z;
        A += (long)tap0 * CIN;             // tap's K-slice of the weight
    } else {
        A += (long)(z >> 3) * sAb + (long)(z & 7) * sAh;
        B += (long)(z >> 3) * sBb + (long)(z & 7) * sBh;
        C += (long)(z >> 3) * sCb + (long)(z & 7) * sCh;
    }
    const int m0 = blockIdx.y * BM;
    const int n0 = blockIdx.x * BN;
    const int tid = threadIdx.x;
    const int wid = tid >> 6, lane = tid & 63;
    constexpr int WM = BM / 2, WN = BN / 2;
    constexpr int FM = WM / 16, FN = WN / 16;
    const int wm = wid >> 1, wn = wid & 1;

    f32x4 acc[FM][FN] = {};

    constexpr int ACH = BM / 64;   // A chunks (16 rows = 1KB) per wave
    constexpr int BCH = BN / 64;
    const int rquad = lane >> 2;          // row within 16-row chunk
    const int koff  = (lane & 3) * 8;     // element offset along K

    int tap = 0, cc0 = 0;
    for (int k0 = 0; k0 < K; k0 += BK) {
        #pragma unroll
        for (int q = 0; q < ACH; ++q) {
            int ch  = wid * ACH + q;
            int row = ch * 16 + rquad;
            const bf16_t* src = A + (long)(m0 + row) * lda + (k0 + koff);
            __builtin_amdgcn_global_load_lds((const AS1 void*)src,
                                             (AS3 void*)(As + ch * 512), 16, 0, 0);
        }
        #pragma unroll
        for (int q = 0; q < BCH; ++q) {
            int ch  = wid * BCH + q;
            int row = ch * 16 + rquad;
            const bf16_t* src;
            if constexpr (CONV == 1) {
                int tl = (n0 & 1023) + row + tap - 1;
                src = ((unsigned)tl < 1024u)
                    ? B + (long)(n0 + row + tap - 1) * ldb + (cc0 + koff)
                    : zpage + koff;
            } else if constexpr (CONV == 2) {
                int tl = (n0 & 1023) + row + tap0 - 1;
                src = ((unsigned)tl < 1024u)
                    ? B + (long)(n0 + row + tap0 - 1) * ldb + (k0 + koff)
                    : zpage + koff;
            } else {
                src = B + (long)(n0 + row) * ldb + (k0 + koff);
            }
            __builtin_amdgcn_global_load_lds((const AS1 void*)src,
                                             (AS3 void*)(Bs + ch * 512), 16, 0, 0);
        }
        if constexpr (CONV == 1) { cc0 += BK; if (cc0 == CIN) { cc0 = 0; ++tap; } }
        __syncthreads();

        const bf16_t* Ab = As + (wm * WM + (lane & 15)) * BK + ((lane >> 4) * 8);
        const bf16_t* Bb = Bs + (wn * WN + (lane & 15)) * BK + ((lane >> 4) * 8);
        bf16x8 af[FM], bv[FN];
        #pragma unroll
        for (int i = 0; i < FM; ++i) af[i] = *(const bf16x8*)(Ab + i * 16 * BK);
        #pragma unroll
        for (int j = 0; j < FN; ++j) bv[j] = *(const bf16x8*)(Bb + j * 16 * BK);
        #pragma unroll
        for (int i = 0; i < FM; ++i)
            #pragma unroll
            for (int j = 0; j < FN; ++j)
                acc[i][j] = __builtin_amdgcn_mfma_f32_16x16x32_bf16(af[i], bv[j], acc[i][j], 0, 0, 0);
        __syncthreads();
    }

    const int mw = m0 + wm * WM, nw = n0 + wn * WN;
    #pragma unroll
    for (int i = 0; i < FM; ++i) {
        const int mb = mw + i * 16 + (lane >> 4) * 4;
        f32x4 bvv = {};
        if constexpr (BIAS) bvv = *(const f32x4*)(bias + mb);
        #pragma unroll
        for (int j = 0; j < FN; ++j) {
            const int nn = nw + j * 16 + (lane & 15);
            f32x4 v = acc[i][j];
            if constexpr (BIAS) v += bvv;
            if constexpr (RELU) {
                #pragma unroll
                for (int r = 0; r < 4; ++r) v[r] = fmaxf(v[r], 0.f);
            }
            if constexpr (MASK) v *= mask[nn];
            bf16x4 o;
            #pragma unroll
            for (int r = 0; r < 4; ++r) o[r] = (bf16_t)v[r];
            if constexpr (CONV == 2) {
                *(bf16x4*)(C + ((long)tap0 << 22) + (long)nn * 512 + mb) = o;
            } else if constexpr (OUTMN) {
                #pragma unroll
                for (int r = 0; r < 4; ++r) C[(long)(mb + r) * ldc + nn] = (bf16_t)v[r];
            } else {
                *(bf16x4*)(C + (long)nn * ldc + mb) = o;
            }
        }
    }
}

// ---------------------------------------------------------------------------
// R[bh,t,j] = sum_d q_scaled[b*1024+t][h*64+d] * erk[j][d]   (wave per (bh,t))
// ---------------------------------------------------------------------------
__global__ __launch_bounds__(256)
void rel_qk(const bf16_t* __restrict__ qk, const float* __restrict__ erk_l,
            float* __restrict__ R)
{
    int gw = blockIdx.x * 4 + (threadIdx.x >> 6);
    int z = gw >> 10, t = gw & 1023;
    int b = z >> 3, h = z & 7;
    int lane = threadIdx.x & 63;
    float qv = (float)qk[(long)(b * 1024 + t) * 1024 + h * 64 + lane];
    float r[9];
    #pragma unroll
    for (int j = 0; j < 9; ++j) r[j] = qv * erk_l[j * 64 + lane];
    #pragma unroll
    for (int o = 1; o < 64; o <<= 1)
        #pragma unroll
        for (int j = 0; j < 9; ++j) r[j] += __shfl_xor(r[j], o);
    if (lane == 0) {
        #pragma unroll
        for (int j = 0; j < 9; ++j) R[(long)gw * 9 + j] = r[j];
    }
}

// ---------------------------------------------------------------------------
// kb[n] = -1e4 if mask[n]==0 else 0   (additive key-side mask bias)
// ---------------------------------------------------------------------------
__global__ __launch_bounds__(256)
void mask_bias(const float* __restrict__ mask, float* __restrict__ kb)
{
    int i = blockIdx.x * 256 + threadIdx.x;
    if (i < 8192) kb[i] = (mask[i] == 0.f) ? -1e4f : 0.f;
}

// ---------------------------------------------------------------------------
// Fused flash attention with static-max softmax (p = exp(s - CMAX)), row-sum
// via ones-MFMA, AND in-register banded rel-v accumulation (pb[4][9]).
// Static max removes the per-iteration rescale (r4's first spill cause);
// the predicated compile-time-indexed accumulation (jbc unrolled compare)
// avoids runtime-indexed local memory (r4's second spill cause, rule #20).
// Grid (64 bh, 16 qtiles), 4 waves, wave owns 16 q-rows, 16 s-iters of 64.
// Writes fully-finished attention output (PV + rel-v, normalized).
// ---------------------------------------------------------------------------
__global__ __launch_bounds__(256, 4)
void flash_attn(const bf16_t* __restrict__ qk, const bf16_t* __restrict__ vt,
                const float* __restrict__ R, const float* __restrict__ kb,
                const float* __restrict__ erv_l, bf16_t* __restrict__ out)
{
    __shared__ bf16_t P_lds[4 * 1024];             // 2KB per wave
    const int w = threadIdx.x >> 6, lane = threadIdx.x & 63;
    const int hi = lane >> 4, li = lane & 15;
    const int bh = blockIdx.x, b = bh >> 3, h = bh & 7;
    const int q0 = blockIdx.y * 64 + w * 16;
    const long nbase = (long)b * 1024;
    char* pw = (char*)(P_lds + w * 1024);

    const bf16_t* qrow = qk + (nbase + q0 + li) * 1024 + h * 64 + hi * 8;
    bf16x8 aq0 = *(const bf16x8*)(qrow);
    bf16x8 aq1 = *(const bf16x8*)(qrow + 32);

    bf16x8 ones;
    #pragma unroll
    for (int e = 0; e < 8; ++e) ones[e] = (bf16_t)1.0f;

    f32x4 acc_o[4] = {};
    f32x4 acc_l = {};
    float pb[4][9] = {};          // banded rel-v P (static-indexed, no rescale)

    const bf16_t* kbase = qk + nbase * 1024 + 512 + h * 64 + hi * 8;
    const bf16_t* vbase = vt + (long)(h * 64 + li) * 8192 + nbase + hi * 8;
    const float* kbp = kb + b * 1024;

    bf16x8 kc[4][2], vv[4][2];
    #pragma unroll
    for (int j = 0; j < 4; ++j) {
        const bf16_t* kr = kbase + (long)(j * 16 + li) * 1024;
        kc[j][0] = *(const bf16x8*)kr;
        kc[j][1] = *(const bf16x8*)(kr + 32);
    }

    for (int it = 0; it < 16; ++it) {
        const int s0 = it * 64;
        #pragma unroll
        for (int j2 = 0; j2 < 4; ++j2) {
            const bf16_t* vr = vbase + (long)(j2 * 16) * 8192 + s0;
            vv[j2][0] = *(const bf16x8*)vr;
            vv[j2][1] = *(const bf16x8*)(vr + 32);
        }
        float kbv[4];
        #pragma unroll
        for (int j = 0; j < 4; ++j) kbv[j] = kbp[s0 + j * 16 + li];
        f32x4 sc[4];
        __builtin_amdgcn_s_setprio(1);
        #pragma unroll
        for (int j = 0; j < 4; ++j) {
            f32x4 a = {};
            a = __builtin_amdgcn_mfma_f32_16x16x32_bf16(aq0, kc[j][0], a, 0, 0, 0);
            a = __builtin_amdgcn_mfma_f32_16x16x32_bf16(aq1, kc[j][1], a, 0, 0, 0);
            sc[j] = a;
        }
        __builtin_amdgcn_s_setprio(0);
        const int s1 = (s0 + 64) & 1023;
        #pragma unroll
        for (int j = 0; j < 4; ++j) {
            const bf16_t* kr = kbase + (long)(s1 + j * 16 + li) * 1024;
            kc[j][0] = *(const bf16x8*)kr;
            kc[j][1] = *(const bf16x8*)(kr + 32);
        }
        #pragma unroll
        for (int j = 0; j < 4; ++j) {
            const int sb = s0 + j * 16;
            const bool near = (sb + 15 >= q0 - 4) && (sb <= q0 + 19);
            const int s_abs = sb + li;
            #pragma unroll
            for (int r = 0; r < 4; ++r) {
                const int q_abs = q0 + hi * 4 + r;
                float v = sc[j][r] + kbv[j];
                if (near) {
                    int jb = s_abs - q_abs + 4;
                    if ((unsigned)jb < 9u)
                        v += R[((long)bh * 1024 + q_abs) * 9 + jb];
                }
                float pex = __expf(v - CMAX);
                sc[j][r] = pex;
                if (near) {
                    const int jb = s_abs - q_abs + 4;
                    #pragma unroll
                    for (int jbc = 0; jbc < 9; ++jbc)
                        if (jbc == jb) pb[r][jbc] += pex;   // static index
                }
            }
        }
        #pragma unroll
        for (int j = 0; j < 4; ++j)
            #pragma unroll
            for (int r = 0; r < 4; ++r) {
                int q = hi * 4 + r;
                int c = (j * 32 + li * 2) ^ ((q & 7) << 4);
                *(bf16_t*)(pw + q * 128 + c) = (bf16_t)sc[j][r];
            }
        asm volatile("s_waitcnt lgkmcnt(0)" ::: "memory");
        __builtin_amdgcn_s_setprio(1);
        #pragma unroll
        for (int half = 0; half < 2; ++half) {
            int cr = (half * 64 + hi * 16) ^ ((li & 7) << 4);
            bf16x8 pa = *(const bf16x8*)(pw + li * 128 + cr);
            #pragma unroll
            for (int j2 = 0; j2 < 4; ++j2)
                acc_o[j2] = __builtin_amdgcn_mfma_f32_16x16x32_bf16(pa, vv[j2][half], acc_o[j2], 0, 0, 0);
            acc_l = __builtin_amdgcn_mfma_f32_16x16x32_bf16(pa, ones, acc_l, 0, 0, 0);
        }
        __builtin_amdgcn_s_setprio(0);
    }

    // reduce pb across the 16-lane group (contributions disjoint -> sum)
    #pragma unroll
    for (int o = 1; o < 16; o <<= 1)
        #pragma unroll
        for (int r = 0; r < 4; ++r)
            #pragma unroll
            for (int jb = 0; jb < 9; ++jb)
                pb[r][jb] += __shfl_xor(pb[r][jb], o);

    #pragma unroll
    for (int r = 0; r < 4; ++r) {
        const float inv = 1.f / acc_l[r];
        const int q_abs = q0 + hi * 4 + r;
        #pragma unroll
        for (int j2 = 0; j2 < 4; ++j2) {
            const int d = j2 * 16 + li;
            float v = acc_o[j2][r];
            #pragma unroll
            for (int jb = 0; jb < 9; ++jb) v += pb[r][jb] * erv_l[jb * 64 + d];
            out[(nbase + q_abs) * 512 + h * 64 + d] = (bf16_t)(v * inv);
        }
    }
}

// ---------------------------------------------------------------------------
// Residual + LayerNorm over C=512 (wave per row n).
// ---------------------------------------------------------------------------
template<int MASKOUT>
__global__ __launch_bounds__(256)
void ln_residual(float* __restrict__ xres, const bf16_t* __restrict__ y,
                 bf16_t* __restrict__ xbf, const float* __restrict__ g,
                 const float* __restrict__ bvec, const float* __restrict__ mask)
{
    int gw = blockIdx.x * 4 + (threadIdx.x >> 6);
    int lane = threadIdx.x & 63;
    long base = (long)gw * 512 + lane * 8;
    f32x4 x0 = *(const f32x4*)(xres + base);
    f32x4 x1 = *(const f32x4*)(xres + base + 4);
    bf16x8 yv = *(const bf16x8*)(y + base);
    float s[8];
    #pragma unroll
    for (int e = 0; e < 4; ++e) { s[e] = x0[e] + (float)yv[e]; s[4 + e] = x1[e] + (float)yv[4 + e]; }
    float sum = 0.f, sq = 0.f;
    #pragma unroll
    for (int e = 0; e < 8; ++e) { sum += s[e]; sq += s[e] * s[e]; }
    #pragma unroll
    for (int o = 1; o < 64; o <<= 1) { sum += __shfl_xor(sum, o); sq += __shfl_xor(sq, o); }
    float mean = sum * (1.f / 512.f);
    float var  = sq * (1.f / 512.f) - mean * mean;
    float rstd = rsqrtf(var + 1e-5f);
    f32x4 g0 = *(const f32x4*)(g + lane * 8);
    f32x4 g1 = *(const f32x4*)(g + lane * 8 + 4);
    f32x4 b0 = *(const f32x4*)(bvec + lane * 8);
    f32x4 b1 = *(const f32x4*)(bvec + lane * 8 + 4);
    float mk = MASKOUT ? mask[gw] : 1.f;
    f32x4 o0, o1; bf16x8 ob;
    #pragma unroll
    for (int e = 0; e < 4; ++e) {
        float v0 = (s[e] - mean) * rstd * g0[e] + b0[e];
        float v1 = (s[4 + e] - mean) * rstd * g1[e] + b1[e];
        o0[e] = v0; o1[e] = v1;
        ob[e] = (bf16_t)(v0 * mk); ob[4 + e] = (bf16_t)(v1 * mk);
    }
    *(f32x4*)(xres + base) = o0;
    *(f32x4*)(xres + base + 4) = o1;
    *(bf16x8*)(xbf + base) = ob;
}

// ---------------------------------------------------------------------------
// Sum of 3 conv2 tap-partials + bias, mask, residual + LayerNorm (ln2).
// ---------------------------------------------------------------------------
__global__ __launch_bounds__(256)
void ln_residual_p3(float* __restrict__ xres, const bf16_t* __restrict__ part,
                    bf16_t* __restrict__ xbf, const float* __restrict__ g,
                    const float* __restrict__ bvec, const float* __restrict__ bias,
                    const float* __restrict__ mask)
{
    int gw = blockIdx.x * 4 + (threadIdx.x >> 6);
    int lane = threadIdx.x & 63;
    long base = (long)gw * 512 + lane * 8;
    bf16x8 pa = *(const bf16x8*)(part + base);
    bf16x8 pbv = *(const bf16x8*)(part + base + (1l << 22));
    bf16x8 pc = *(const bf16x8*)(part + base + (2l << 22));
    f32x4 x0 = *(const f32x4*)(xres + base);
    f32x4 x1 = *(const f32x4*)(xres + base + 4);
    f32x4 bi0 = *(const f32x4*)(bias + lane * 8);
    f32x4 bi1 = *(const f32x4*)(bias + lane * 8 + 4);
    float mk = mask[gw];
    float s[8];
    #pragma unroll
    for (int e = 0; e < 4; ++e) {
        float y0 = ((float)pa[e] + (float)pbv[e] + (float)pc[e] + bi0[e]) * mk;
        float y1 = ((float)pa[4 + e] + (float)pbv[4 + e] + (float)pc[4 + e] + bi1[e]) * mk;
        s[e] = x0[e] + y0; s[4 + e] = x1[e] + y1;
    }
    float sum = 0.f, sq = 0.f;
    #pragma unroll
    for (int e = 0; e < 8; ++e) { sum += s[e]; sq += s[e] * s[e]; }
    #pragma unroll
    for (int o = 1; o < 64; o <<= 1) { sum += __shfl_xor(sum, o); sq += __shfl_xor(sq, o); }
    float mean = sum * (1.f / 512.f);
    float var  = sq * (1.f / 512.f) - mean * mean;
    float rstd = rsqrtf(var + 1e-5f);
    f32x4 g0 = *(const f32x4*)(g + lane * 8);
    f32x4 g1 = *(const f32x4*)(g + lane * 8 + 4);
    f32x4 b0 = *(const f32x4*)(bvec + lane * 8);
    f32x4 b1 = *(const f32x4*)(bvec + lane * 8 + 4);
    f32x4 o0, o1; bf16x8 ob;
    #pragma unroll
    for (int e = 0; e < 4; ++e) {
        float v0 = (s[e] - mean) * rstd * g0[e] + b0[e];
        float v1 = (s[4 + e] - mean) * rstd * g1[e] + b1[e];
        o0[e] = v0; o1[e] = v1;
        ob[e] = (bf16_t)v0; ob[4 + e] = (bf16_t)v1;
    }
    *(f32x4*)(xres + base) = o0;
    *(f32x4*)(xres + base + 4) = o1;
    *(bf16x8*)(xbf + base) = ob;
}

// ---------------------------------------------------------------------------
// Transposes: x[B,C,T] <-> act[B*T, C]
// ---------------------------------------------------------------------------
__global__ __launch_bounds__(256)
void transpose_in_k(const float* __restrict__ x, const float* __restrict__ mask,
                    float* __restrict__ xres, bf16_t* __restrict__ xbf)
{
    __shared__ float tile[32][33];
    int b = blockIdx.z, c0 = blockIdx.y * 32, t0 = blockIdx.x * 32;
    int tx = threadIdx.x & 31, ty = threadIdx.x >> 5;
    #pragma unroll
    for (int r = 0; r < 4; ++r) {
        int cl = ty + r * 8;
        tile[cl][tx] = x[((long)b * 512 + c0 + cl) * 1024 + t0 + tx];
    }
    __syncthreads();
    #pragma unroll
    for (int r = 0; r < 4; ++r) {
        int tl = ty + r * 8;
        int n = b * 1024 + t0 + tl;
        float v = tile[tx][tl] * mask[n];
        xres[(long)n * 512 + c0 + tx] = v;
        xbf[(long)n * 512 + c0 + tx] = (bf16_t)v;
    }
}

__global__ __launch_bounds__(256)
void transpose_out_k(const float* __restrict__ xres, const float* __restrict__ mask,
                     float* __restrict__ out)
{
    __shared__ float tile[32][33];
    int b = blockIdx.z, c0 = blockIdx.y * 32, t0 = blockIdx.x * 32;
    int tx = threadIdx.x & 31, ty = threadIdx.x >> 5;
    #pragma unroll
    for (int r = 0; r < 4; ++r) {
        int tl = ty + r * 8;
        int n = b * 1024 + t0 + tl;
        tile[tl][tx] = xres[(long)n * 512 + c0 + tx] * mask[n];
    }
    __syncthreads();
    #pragma unroll
    for (int r = 0; r < 4; ++r) {
        int cl = ty + r * 8;
        out[((long)b * 512 + c0 + cl) * 1024 + t0 + tx] = tile[tx][cl];
    }
}

// ---------------------------------------------------------------------------
// Per-layer weight packing (fp32 -> bf16, q-scale fold, conv k-major repack)
// ---------------------------------------------------------------------------
__global__ __launch_bounds__(256)
void pack_attn_w(const float* __restrict__ w, bf16_t* __restrict__ Wqk,
                 bf16_t* __restrict__ Wv, bf16_t* __restrict__ Wo)
{
    int idx = blockIdx.x * 256 + threadIdx.x;      // < 4*512*512
    if (idx >= 4 * 512 * 512) return;
    int c = idx & 511;
    int o = (idx >> 9) & 511;
    int which = idx >> 18;
    float v = w[idx];
    if (which == 0) v *= 0.125f;
    if (which <= 1)      Wqk[(which * 512 + o) * 512 + c] = (bf16_t)v;
    else if (which == 2) Wv[o * 512 + c] = (bf16_t)v;
    else                 Wo[o * 512 + c] = (bf16_t)v;
}

__global__ __launch_bounds__(256)
void pack_attn_b(const float* __restrict__ bsrc, float* __restrict__ bqk)
{
    int idx = blockIdx.x * 256 + threadIdx.x;
    if (idx >= 6 * 2 * 512) return;     // only q,k need packing (q scaled)
    int c = idx & 511, which = (idx >> 9) & 1, i = idx >> 10;
    float v = bsrc[(i * 4 + which) * 512 + c];
    if (which == 0) v *= 0.125f;
    bqk[i * 1024 + which * 512 + c] = v;
}

__global__ __launch_bounds__(256)
void pack_w1k(const float* __restrict__ w, bf16_t* __restrict__ Wp)
{
    int idx = blockIdx.x * 256 + threadIdx.x;      // < 2048*1536
    if (idx >= 2048 * 1536) return;
    int c = idx & 511;
    int k = (idx >> 9) % 3;
    int f = idx / 1536;
    Wp[idx] = (bf16_t)w[(f * 512 + c) * 3 + k];    // w1[f][c][k] -> Wp[f][k][c]
}

__global__ __launch_bounds__(256)
void pack_w2k(const float* __restrict__ w, bf16_t* __restrict__ Wp)
{
    int idx = blockIdx.x * 256 + threadIdx.x;      // < 512*6144
    if (idx >= 512 * 6144) return;
    int f = idx & 2047;
    int k = (idx >> 11) % 3;
    int ci = idx / 6144;
    Wp[idx] = (bf16_t)w[ci * 6144 + f * 3 + k];    // w2[c][f][k] -> Wp[c][k][f]
}

// ---------------------------------------------------------------------------
extern "C" void kernel_launch(void* const* d_in, const int* in_sizes, int n_in,
                              void* d_out, int out_size, void* d_ws, size_t ws_size,
                              hipStream_t stream)
{
    const float* x      = (const float*)d_in[0];
    const float* xmask  = (const float*)d_in[1];
    const float* attn_w = (const float*)d_in[2];
    const float* attn_b = (const float*)d_in[3];
    const float* erk    = (const float*)d_in[4];
    const float* erv    = (const float*)d_in[5];
    const float* ln1g   = (const float*)d_in[6];
    const float* ln1b   = (const float*)d_in[7];
    const float* w1     = (const float*)d_in[8];
    const float* b1in   = (const float*)d_in[9];
    const float* w2     = (const float*)d_in[10];
    const float* b2in   = (const float*)d_in[11];
    const float* ln2g   = (const float*)d_in[12];
    const float* ln2b   = (const float*)d_in[13];
    float* out = (float*)d_out;

    char* p = (char*)d_ws;
    auto alloc = [&](size_t bytes) {
        char* r = p;
        p += (bytes + 255) & ~(size_t)255;
        return r;
    };
    // total ws usage ~110 MB (r9 layout, stats removed)
    bf16_t* zpage = (bf16_t*)alloc(1024);
    bf16_t* Wqk_l = (bf16_t*)alloc(1024l * 512 * 2);
    bf16_t* Wv_l  = (bf16_t*)alloc(512l * 512 * 2);
    bf16_t* Wo_l  = (bf16_t*)alloc(512l * 512 * 2);
    bf16_t* W1p_l = (bf16_t*)alloc(2048l * 1536 * 2);
    bf16_t* W2p_l = (bf16_t*)alloc(512l * 6144 * 2);
    float*  bqk   = (float*)alloc(6l * 1024 * 4);
    float*  xres  = (float*)alloc(8192l * 512 * 4);
    bf16_t* xbf   = (bf16_t*)alloc(8192l * 512 * 2);
    bf16_t* big   = (bf16_t*)alloc(8192l * 2048 * 2);   // qk|vt|attn_out, aliased by hbuf
    bf16_t* ybuf  = (bf16_t*)alloc(8192l * 512 * 2);
    bf16_t* part  = (bf16_t*)alloc(3l * 8192 * 512 * 2); // conv2 tap partials
    float*  R     = (float*)alloc(64l * 1024 * 9 * 4);
    float*  kb    = (float*)alloc(8192l * 4);            // key-side mask bias
    (void)in_sizes; (void)n_in; (void)out_size; (void)ws_size;

    bf16_t* qk       = big;                    // [8192][1024]
    bf16_t* vt       = big + 8192l * 1024;     // [512][8192]
    bf16_t* attn_out = vt + 512l * 8192;       // [8192][512]
    bf16_t* hbuf     = big;                    // [8192][2048], aliases all three

    hipMemsetAsync(zpage, 0, 1024, stream);
    pack_attn_b<<<24, 256, 0, stream>>>(attn_b, bqk);
    mask_bias<<<32, 256, 0, stream>>>(xmask, kb);
    transpose_in_k<<<dim3(32, 16, 8), 256, 0, stream>>>(x, xmask, xres, xbf);

    for (int i = 0; i < 6; ++i) {
        pack_attn_w<<<4096, 256, 0, stream>>>(attn_w + (long)i * 4 * 512 * 512,
                                              Wqk_l, Wv_l, Wo_l);
        pack_w1k<<<12288, 256, 0, stream>>>(w1 + (long)i * 2048 * 512 * 3, W1p_l);
        pack_w2k<<<12288, 256, 0, stream>>>(w2 + (long)i * 512 * 2048 * 3, W2p_l);

        // QK projection (q pre-scaled): [1024,512] x [8192,512]^T -> qk[n][m]
        gemm_nt<128, 128, 0, 0, 1, 0, 0><<<dim3(64, 8, 1), 256, 0, stream>>>(
            Wqk_l, xbf, qk, bqk + i * 1024, nullptr, zpage,
            512, 512, 512, 1024, 0, 0, 0, 0, 0, 0, 0);
        // V projection -> channel-major vt[c][n]  (BM=64: 512 blocks, 2/CU)
        gemm_nt<64, 128, 1, 0, 1, 0, 0><<<dim3(64, 8, 1), 256, 0, stream>>>(
            Wv_l, xbf, vt, attn_b + (i * 4 + 2) * 512, nullptr, zpage,
            512, 512, 512, 8192, 0, 0, 0, 0, 0, 0, 0);
        // R table for banded rel-k logits
        rel_qk<<<16384, 256, 0, stream>>>(qk, erk + i * 576, R);
        // fused flash attention (static-max, in-register band rel-v; fully
        // finished output -- band_finish eliminated)
        flash_attn<<<dim3(64, 16), 256, 0, stream>>>(qk, vt, R, kb,
                                                     erv + i * 576, attn_out);
        // O projection (BM=64: 512 blocks)
        gemm_nt<64, 128, 0, 0, 1, 0, 0><<<dim3(64, 8, 1), 256, 0, stream>>>(
            Wo_l, attn_out, ybuf, attn_b + (i * 4 + 3) * 512, nullptr, zpage,
            512, 512, 512, 512, 0, 0, 0, 0, 0, 0, 0);
        // LN1 (xbf masked for conv1 input)
        ln_residual<1><<<2048, 256, 0, stream>>>(xres, ybuf, xbf,
                                                 ln1g + i * 512, ln1b + i * 512, xmask);
        // conv1 (K=3*512) + bias + relu + mask
        gemm_nt<128, 128, 0, 1, 1, 1, 1><<<dim3(64, 16, 1), 256, 0, stream>>>(
            W1p_l, xbf, hbuf, b1in + i * 2048, xmask, zpage,
            1536, 1536, 512, 2048, 512, 0, 0, 0, 0, 0, 0);
        // conv2 split-K by tap: partials [3][8192][512] bf16 (BM=64: 1536 blocks)
        gemm_nt<64, 128, 0, 2, 0, 0, 0><<<dim3(64, 8, 3), 256, 0, stream>>>(
            W2p_l, hbuf, part, nullptr, nullptr, zpage,
            2048, 6144, 2048, 512, 2048, 0, 0, 0, 0, 0, 0);
        // LN2 fused with partial reduce + bias + mask
        ln_residual_p3<<<2048, 256, 0, stream>>>(xres, part, xbf,
                                                 ln2g + i * 512, ln2b + i * 512,
                                                 b2in + i * 512, xmask);
    }

    transpose_out_k<<<dim3(32, 16, 8), 256, 0, stream>>>(xres, xmask, out);
}

// Round 14
// 2819.613 us; speedup vs baseline: 1.3078x; 1.3078x over previous
//
#include <hip/hip_runtime.h>

typedef __bf16 bf16_t;
typedef __bf16 bf16x8 __attribute__((ext_vector_type(8)));
typedef __bf16 bf16x4 __attribute__((ext_vector_type(4)));
typedef float  f32x4  __attribute__((ext_vector_type(4)));

#define AS1 __attribute__((address_space(1)))
#define AS3 __attribute__((address_space(3)))

#define CMAX 16.0f   // static softmax max bound (true scores |s| ~ 1)

// ---------------------------------------------------------------------------
// Unified NT GEMM:  D[m][n] = sum_k A[m][k] * Bt[n][k]   (both K-contiguous)
// OUTMN=0: store C[n][m] (activation layout), OUTMN=1: store C[m][n].
// CONV=1: K = 3*CIN fused tap loop. CONV=2: split-K, blockIdx.z = tap,
//         K = CIN, writes bf16 partial at C + (tap<<22) + n*512 + m.
// ---------------------------------------------------------------------------
template<int BM, int BN, int OUTMN, int CONV, int BIAS, int RELU, int MASK>
__global__ __launch_bounds__(256)
void gemm_nt(const bf16_t* __restrict__ A, const bf16_t* __restrict__ B,
             bf16_t* __restrict__ C, const float* __restrict__ bias,
             const float* __restrict__ mask, const bf16_t* __restrict__ zpage,
             int K, int lda, int ldb, int ldc, int CIN,
             long sAb, long sAh, long sBb, long sBh, long sCb, long sCh)
{
    constexpr int BK = 32;
    __shared__ bf16_t As[BM * BK];
    __shared__ bf16_t Bs[BN * BK];
    const int z = blockIdx.z;
    int tap0 = 0;
    if constexpr (CONV == 2) {
        tap0 = z;
        A += (long)tap0 * CIN;             // tap's K-slice of the weight
    } else {
        A += (long)(z >> 3) * sAb + (long)(z & 7) * sAh;
        B += (long)(z >> 3) * sBb + (long)(z & 7) * sBh;
        C += (long)(z >> 3) * sCb + (long)(z & 7) * sCh;
    }
    const int m0 = blockIdx.y * BM;
    const int n0 = blockIdx.x * BN;
    const int tid = threadIdx.x;
    const int wid = tid >> 6, lane = tid & 63;
    constexpr int WM = BM / 2, WN = BN / 2;
    constexpr int FM = WM / 16, FN = WN / 16;
    const int wm = wid >> 1, wn = wid & 1;

    f32x4 acc[FM][FN] = {};

    constexpr int ACH = BM / 64;   // A chunks (16 rows = 1KB) per wave
    constexpr int BCH = BN / 64;
    const int rquad = lane >> 2;          // row within 16-row chunk
    const int koff  = (lane & 3) * 8;     // element offset along K

    int tap = 0, cc0 = 0;
    for (int k0 = 0; k0 < K; k0 += BK) {
        #pragma unroll
        for (int q = 0; q < ACH; ++q) {
            int ch  = wid * ACH + q;
            int row = ch * 16 + rquad;
            const bf16_t* src = A + (long)(m0 + row) * lda + (k0 + koff);
            __builtin_amdgcn_global_load_lds((const AS1 void*)src,
                                             (AS3 void*)(As + ch * 512), 16, 0, 0);
        }
        #pragma unroll
        for (int q = 0; q < BCH; ++q) {
            int ch  = wid * BCH + q;
            int row = ch * 16 + rquad;
            const bf16_t* src;
            if constexpr (CONV == 1) {
                int tl = (n0 & 1023) + row + tap - 1;
                src = ((unsigned)tl < 1024u)
                    ? B + (long)(n0 + row + tap - 1) * ldb + (cc0 + koff)
                    : zpage + koff;
            } else if constexpr (CONV == 2) {
                int tl = (n0 & 1023) + row + tap0 - 1;
                src = ((unsigned)tl < 1024u)
                    ? B + (long)(n0 + row + tap0 - 1) * ldb + (k0 + koff)
                    : zpage + koff;
            } else {
                src = B + (long)(n0 + row) * ldb + (k0 + koff);
            }
            __builtin_amdgcn_global_load_lds((const AS1 void*)src,
                                             (AS3 void*)(Bs + ch * 512), 16, 0, 0);
        }
        if constexpr (CONV == 1) { cc0 += BK; if (cc0 == CIN) { cc0 = 0; ++tap; } }
        __syncthreads();

        const bf16_t* Ab = As + (wm * WM + (lane & 15)) * BK + ((lane >> 4) * 8);
        const bf16_t* Bb = Bs + (wn * WN + (lane & 15)) * BK + ((lane >> 4) * 8);
        bf16x8 af[FM], bv[FN];
        #pragma unroll
        for (int i = 0; i < FM; ++i) af[i] = *(const bf16x8*)(Ab + i * 16 * BK);
        #pragma unroll
        for (int j = 0; j < FN; ++j) bv[j] = *(const bf16x8*)(Bb + j * 16 * BK);
        #pragma unroll
        for (int i = 0; i < FM; ++i)
            #pragma unroll
            for (int j = 0; j < FN; ++j)
                acc[i][j] = __builtin_amdgcn_mfma_f32_16x16x32_bf16(af[i], bv[j], acc[i][j], 0, 0, 0);
        __syncthreads();
    }

    const int mw = m0 + wm * WM, nw = n0 + wn * WN;
    #pragma unroll
    for (int i = 0; i < FM; ++i) {
        const int mb = mw + i * 16 + (lane >> 4) * 4;
        f32x4 bvv = {};
        if constexpr (BIAS) bvv = *(const f32x4*)(bias + mb);
        #pragma unroll
        for (int j = 0; j < FN; ++j) {
            const int nn = nw + j * 16 + (lane & 15);
            f32x4 v = acc[i][j];
            if constexpr (BIAS) v += bvv;
            if constexpr (RELU) {
                #pragma unroll
                for (int r = 0; r < 4; ++r) v[r] = fmaxf(v[r], 0.f);
            }
            if constexpr (MASK) v *= mask[nn];
            bf16x4 o;
            #pragma unroll
            for (int r = 0; r < 4; ++r) o[r] = (bf16_t)v[r];
            if constexpr (CONV == 2) {
                *(bf16x4*)(C + ((long)tap0 << 22) + (long)nn * 512 + mb) = o;
            } else if constexpr (OUTMN) {
                #pragma unroll
                for (int r = 0; r < 4; ++r) C[(long)(mb + r) * ldc + nn] = (bf16_t)v[r];
            } else {
                *(bf16x4*)(C + (long)nn * ldc + mb) = o;
            }
        }
    }
}

// ---------------------------------------------------------------------------
// R[bh,t,j] = sum_d q_scaled[b*1024+t][h*64+d] * erk[j][d]   (wave per (bh,t))
// ---------------------------------------------------------------------------
__global__ __launch_bounds__(256)
void rel_qk(const bf16_t* __restrict__ qk, const float* __restrict__ erk_l,
            float* __restrict__ R)
{
    int gw = blockIdx.x * 4 + (threadIdx.x >> 6);
    int z = gw >> 10, t = gw & 1023;
    int b = z >> 3, h = z & 7;
    int lane = threadIdx.x & 63;
    float qv = (float)qk[(long)(b * 1024 + t) * 1024 + h * 64 + lane];
    float r[9];
    #pragma unroll
    for (int j = 0; j < 9; ++j) r[j] = qv * erk_l[j * 64 + lane];
    #pragma unroll
    for (int o = 1; o < 64; o <<= 1)
        #pragma unroll
        for (int j = 0; j < 9; ++j) r[j] += __shfl_xor(r[j], o);
    if (lane == 0) {
        #pragma unroll
        for (int j = 0; j < 9; ++j) R[(long)gw * 9 + j] = r[j];
    }
}

// ---------------------------------------------------------------------------
// kb[n] = -1e4 if mask[n]==0 else 0   (additive key-side mask bias)
// ---------------------------------------------------------------------------
__global__ __launch_bounds__(256)
void mask_bias(const float* __restrict__ mask, float* __restrict__ kb)
{
    int i = blockIdx.x * 256 + threadIdx.x;
    if (i < 8192) kb[i] = (mask[i] == 0.f) ? -1e4f : 0.f;
}

// ---------------------------------------------------------------------------
// Fused flash attention with static-max softmax (p = exp(s - CMAX)), row-sum
// via ones-MFMA. Grid (64 bh, 16 qtiles), 4 waves, wave owns 16 q-rows.
// (r13 lesson: do NOT fuse the band rel-v accumulator here -- its 36-float
// loop-carried state spills to scratch; band_finish stays separate.)
// ---------------------------------------------------------------------------
__global__ __launch_bounds__(256)
void flash_attn(const bf16_t* __restrict__ qk, const bf16_t* __restrict__ vt,
                const float* __restrict__ R, const float* __restrict__ kb,
                bf16_t* __restrict__ out, float* __restrict__ stats)
{
    __shared__ bf16_t P_lds[4 * 1024];             // 2KB per wave
    const int w = threadIdx.x >> 6, lane = threadIdx.x & 63;
    const int hi = lane >> 4, li = lane & 15;
    const int bh = blockIdx.x, b = bh >> 3, h = bh & 7;
    const int q0 = blockIdx.y * 64 + w * 16;
    const long nbase = (long)b * 1024;
    char* pw = (char*)(P_lds + w * 1024);

    const bf16_t* qrow = qk + (nbase + q0 + li) * 1024 + h * 64 + hi * 8;
    bf16x8 aq0 = *(const bf16x8*)(qrow);
    bf16x8 aq1 = *(const bf16x8*)(qrow + 32);

    bf16x8 ones;
    #pragma unroll
    for (int e = 0; e < 8; ++e) ones[e] = (bf16_t)1.0f;

    f32x4 acc_o[4] = {};
    f32x4 acc_l = {};

    const bf16_t* kbase = qk + nbase * 1024 + 512 + h * 64 + hi * 8;
    const bf16_t* vbase = vt + (long)(h * 64 + li) * 8192 + nbase + hi * 8;
    const float* kbp = kb + b * 1024;

    bf16x8 kc[4][2], vv[4][2];
    #pragma unroll
    for (int j = 0; j < 4; ++j) {
        const bf16_t* kr = kbase + (long)(j * 16 + li) * 1024;
        kc[j][0] = *(const bf16x8*)kr;
        kc[j][1] = *(const bf16x8*)(kr + 32);
    }

    for (int it = 0; it < 16; ++it) {
        const int s0 = it * 64;
        #pragma unroll
        for (int j2 = 0; j2 < 4; ++j2) {
            const bf16_t* vr = vbase + (long)(j2 * 16) * 8192 + s0;
            vv[j2][0] = *(const bf16x8*)vr;
            vv[j2][1] = *(const bf16x8*)(vr + 32);
        }
        float kbv[4];
        #pragma unroll
        for (int j = 0; j < 4; ++j) kbv[j] = kbp[s0 + j * 16 + li];
        f32x4 sc[4];
        __builtin_amdgcn_s_setprio(1);
        #pragma unroll
        for (int j = 0; j < 4; ++j) {
            f32x4 a = {};
            a = __builtin_amdgcn_mfma_f32_16x16x32_bf16(aq0, kc[j][0], a, 0, 0, 0);
            a = __builtin_amdgcn_mfma_f32_16x16x32_bf16(aq1, kc[j][1], a, 0, 0, 0);
            sc[j] = a;
        }
        __builtin_amdgcn_s_setprio(0);
        const int s1 = (s0 + 64) & 1023;
        #pragma unroll
        for (int j = 0; j < 4; ++j) {
            const bf16_t* kr = kbase + (long)(s1 + j * 16 + li) * 1024;
            kc[j][0] = *(const bf16x8*)kr;
            kc[j][1] = *(const bf16x8*)(kr + 32);
        }
        #pragma unroll
        for (int j = 0; j < 4; ++j) {
            const int sb = s0 + j * 16;
            const bool near = (sb + 15 >= q0 - 4) && (sb <= q0 + 19);
            const int s_abs = sb + li;
            #pragma unroll
            for (int r = 0; r < 4; ++r) {
                const int q_abs = q0 + hi * 4 + r;
                float v = sc[j][r] + kbv[j];
                if (near) {
                    int jb = s_abs - q_abs + 4;
                    if ((unsigned)jb < 9u)
                        v += R[((long)bh * 1024 + q_abs) * 9 + jb];
                }
                sc[j][r] = __expf(v - CMAX);
            }
        }
        #pragma unroll
        for (int j = 0; j < 4; ++j)
            #pragma unroll
            for (int r = 0; r < 4; ++r) {
                int q = hi * 4 + r;
                int c = (j * 32 + li * 2) ^ ((q & 7) << 4);
                *(bf16_t*)(pw + q * 128 + c) = (bf16_t)sc[j][r];
            }
        asm volatile("s_waitcnt lgkmcnt(0)" ::: "memory");
        __builtin_amdgcn_s_setprio(1);
        #pragma unroll
        for (int half = 0; half < 2; ++half) {
            int cr = (half * 64 + hi * 16) ^ ((li & 7) << 4);
            bf16x8 pa = *(const bf16x8*)(pw + li * 128 + cr);
            #pragma unroll
            for (int j2 = 0; j2 < 4; ++j2)
                acc_o[j2] = __builtin_amdgcn_mfma_f32_16x16x32_bf16(pa, vv[j2][half], acc_o[j2], 0, 0, 0);
            acc_l = __builtin_amdgcn_mfma_f32_16x16x32_bf16(pa, ones, acc_l, 0, 0, 0);
        }
        __builtin_amdgcn_s_setprio(0);
    }

    #pragma unroll
    for (int r = 0; r < 4; ++r) {
        const float inv = 1.f / acc_l[r];
        const int q_abs = q0 + hi * 4 + r;
        #pragma unroll
        for (int j2 = 0; j2 < 4; ++j2) {
            const int d = j2 * 16 + li;
            out[(nbase + q_abs) * 512 + h * 64 + d] = (bf16_t)(acc_o[j2][r] * inv);
        }
        if (li == 0) {
            stats[2 * ((long)bh * 1024 + q_abs)]     = CMAX;
            stats[2 * ((long)bh * 1024 + q_abs) + 1] = acc_l[r];
        }
    }
}

// ---------------------------------------------------------------------------
// Banded rel-v finish: out[bh,t,d] += sum_j p_j * erv[j][d].
// ---------------------------------------------------------------------------
__global__ __launch_bounds__(256)
void band_finish(const bf16_t* __restrict__ qk, const float* __restrict__ R,
                 const float* __restrict__ stats, const float* __restrict__ erv_l,
                 const float* __restrict__ kb, bf16_t* __restrict__ out)
{
    int gw = blockIdx.x * 4 + (threadIdx.x >> 6);   // bh*1024 + t
    int bh = gw >> 10, t = gw & 1023;
    int b = bh >> 3, h = bh & 7;
    int lane = threadIdx.x & 63;
    const long nb = (long)b * 1024;
    float qv = (float)qk[(nb + t) * 1024 + h * 64 + lane];
    float p[9];
    #pragma unroll
    for (int j = 0; j < 9; ++j) {
        int s = t + j - 4;
        float dot = 0.f;
        if ((unsigned)s < 1024u)
            dot = qv * (float)qk[(nb + s) * 1024 + 512 + h * 64 + lane];
        p[j] = dot;
    }
    #pragma unroll
    for (int o = 1; o < 64; o <<= 1)
        #pragma unroll
        for (int j = 0; j < 9; ++j) p[j] += __shfl_xor(p[j], o);
    float m = stats[2 * (long)gw], invl = 1.f / stats[2 * (long)gw + 1];
    #pragma unroll
    for (int j = 0; j < 9; ++j) {
        int s = t + j - 4;
        if ((unsigned)s < 1024u) {
            float sc = p[j] + R[(long)gw * 9 + j] + kb[b * 1024 + s];
            p[j] = __expf(sc - m) * invl;
        } else p[j] = 0.f;
    }
    long oidx = (nb + t) * 512 + h * 64 + lane;
    float v = (float)out[oidx];
    #pragma unroll
    for (int j = 0; j < 9; ++j) v += p[j] * erv_l[j * 64 + lane];
    out[oidx] = (bf16_t)v;
}

// ---------------------------------------------------------------------------
// Residual + LayerNorm over C=512 (wave per row n).
// ---------------------------------------------------------------------------
template<int MASKOUT>
__global__ __launch_bounds__(256)
void ln_residual(float* __restrict__ xres, const bf16_t* __restrict__ y,
                 bf16_t* __restrict__ xbf, const float* __restrict__ g,
                 const float* __restrict__ bvec, const float* __restrict__ mask)
{
    int gw = blockIdx.x * 4 + (threadIdx.x >> 6);
    int lane = threadIdx.x & 63;
    long base = (long)gw * 512 + lane * 8;
    f32x4 x0 = *(const f32x4*)(xres + base);
    f32x4 x1 = *(const f32x4*)(xres + base + 4);
    bf16x8 yv = *(const bf16x8*)(y + base);
    float s[8];
    #pragma unroll
    for (int e = 0; e < 4; ++e) { s[e] = x0[e] + (float)yv[e]; s[4 + e] = x1[e] + (float)yv[4 + e]; }
    float sum = 0.f, sq = 0.f;
    #pragma unroll
    for (int e = 0; e < 8; ++e) { sum += s[e]; sq += s[e] * s[e]; }
    #pragma unroll
    for (int o = 1; o < 64; o <<= 1) { sum += __shfl_xor(sum, o); sq += __shfl_xor(sq, o); }
    float mean = sum * (1.f / 512.f);
    float var  = sq * (1.f / 512.f) - mean * mean;
    float rstd = rsqrtf(var + 1e-5f);
    f32x4 g0 = *(const f32x4*)(g + lane * 8);
    f32x4 g1 = *(const f32x4*)(g + lane * 8 + 4);
    f32x4 b0 = *(const f32x4*)(bvec + lane * 8);
    f32x4 b1 = *(const f32x4*)(bvec + lane * 8 + 4);
    float mk = MASKOUT ? mask[gw] : 1.f;
    f32x4 o0, o1; bf16x8 ob;
    #pragma unroll
    for (int e = 0; e < 4; ++e) {
        float v0 = (s[e] - mean) * rstd * g0[e] + b0[e];
        float v1 = (s[4 + e] - mean) * rstd * g1[e] + b1[e];
        o0[e] = v0; o1[e] = v1;
        ob[e] = (bf16_t)(v0 * mk); ob[4 + e] = (bf16_t)(v1 * mk);
    }
    *(f32x4*)(xres + base) = o0;
    *(f32x4*)(xres + base + 4) = o1;
    *(bf16x8*)(xbf + base) = ob;
}

// ---------------------------------------------------------------------------
// Sum of 3 conv2 tap-partials + bias, mask, residual + LayerNorm (ln2).
// ---------------------------------------------------------------------------
__global__ __launch_bounds__(256)
void ln_residual_p3(float* __restrict__ xres, const bf16_t* __restrict__ part,
                    bf16_t* __restrict__ xbf, const float* __restrict__ g,
                    const float* __restrict__ bvec, const float* __restrict__ bias,
                    const float* __restrict__ mask)
{
    int gw = blockIdx.x * 4 + (threadIdx.x >> 6);
    int lane = threadIdx.x & 63;
    long base = (long)gw * 512 + lane * 8;
    bf16x8 pa = *(const bf16x8*)(part + base);
    bf16x8 pbv = *(const bf16x8*)(part + base + (1l << 22));
    bf16x8 pc = *(const bf16x8*)(part + base + (2l << 22));
    f32x4 x0 = *(const f32x4*)(xres + base);
    f32x4 x1 = *(const f32x4*)(xres + base + 4);
    f32x4 bi0 = *(const f32x4*)(bias + lane * 8);
    f32x4 bi1 = *(const f32x4*)(bias + lane * 8 + 4);
    float mk = mask[gw];
    float s[8];
    #pragma unroll
    for (int e = 0; e < 4; ++e) {
        float y0 = ((float)pa[e] + (float)pbv[e] + (float)pc[e] + bi0[e]) * mk;
        float y1 = ((float)pa[4 + e] + (float)pbv[4 + e] + (float)pc[4 + e] + bi1[e]) * mk;
        s[e] = x0[e] + y0; s[4 + e] = x1[e] + y1;
    }
    float sum = 0.f, sq = 0.f;
    #pragma unroll
    for (int e = 0; e < 8; ++e) { sum += s[e]; sq += s[e] * s[e]; }
    #pragma unroll
    for (int o = 1; o < 64; o <<= 1) { sum += __shfl_xor(sum, o); sq += __shfl_xor(sq, o); }
    float mean = sum * (1.f / 512.f);
    float var  = sq * (1.f / 512.f) - mean * mean;
    float rstd = rsqrtf(var + 1e-5f);
    f32x4 g0 = *(const f32x4*)(g + lane * 8);
    f32x4 g1 = *(const f32x4*)(g + lane * 8 + 4);
    f32x4 b0 = *(const f32x4*)(bvec + lane * 8);
    f32x4 b1 = *(const f32x4*)(bvec + lane * 8 + 4);
    f32x4 o0, o1; bf16x8 ob;
    #pragma unroll
    for (int e = 0; e < 4; ++e) {
        float v0 = (s[e] - mean) * rstd * g0[e] + b0[e];
        float v1 = (s[4 + e] - mean) * rstd * g1[e] + b1[e];
        o0[e] = v0; o1[e] = v1;
        ob[e] = (bf16_t)v0; ob[4 + e] = (bf16_t)v1;
    }
    *(f32x4*)(xres + base) = o0;
    *(f32x4*)(xres + base + 4) = o1;
    *(bf16x8*)(xbf + base) = ob;
}

// ---------------------------------------------------------------------------
// Transposes: x[B,C,T] <-> act[B*T, C]
// ---------------------------------------------------------------------------
__global__ __launch_bounds__(256)
void transpose_in_k(const float* __restrict__ x, const float* __restrict__ mask,
                    float* __restrict__ xres, bf16_t* __restrict__ xbf)
{
    __shared__ float tile[32][33];
    int b = blockIdx.z, c0 = blockIdx.y * 32, t0 = blockIdx.x * 32;
    int tx = threadIdx.x & 31, ty = threadIdx.x >> 5;
    #pragma unroll
    for (int r = 0; r < 4; ++r) {
        int cl = ty + r * 8;
        tile[cl][tx] = x[((long)b * 512 + c0 + cl) * 1024 + t0 + tx];
    }
    __syncthreads();
    #pragma unroll
    for (int r = 0; r < 4; ++r) {
        int tl = ty + r * 8;
        int n = b * 1024 + t0 + tl;
        float v = tile[tx][tl] * mask[n];
        xres[(long)n * 512 + c0 + tx] = v;
        xbf[(long)n * 512 + c0 + tx] = (bf16_t)v;
    }
}

__global__ __launch_bounds__(256)
void transpose_out_k(const float* __restrict__ xres, const float* __restrict__ mask,
                     float* __restrict__ out)
{
    __shared__ float tile[32][33];
    int b = blockIdx.z, c0 = blockIdx.y * 32, t0 = blockIdx.x * 32;
    int tx = threadIdx.x & 31, ty = threadIdx.x >> 5;
    #pragma unroll
    for (int r = 0; r < 4; ++r) {
        int tl = ty + r * 8;
        int n = b * 1024 + t0 + tl;
        tile[tl][tx] = xres[(long)n * 512 + c0 + tx] * mask[n];
    }
    __syncthreads();
    #pragma unroll
    for (int r = 0; r < 4; ++r) {
        int cl = ty + r * 8;
        out[((long)b * 512 + c0 + cl) * 1024 + t0 + tx] = tile[tx][cl];
    }
}

// ---------------------------------------------------------------------------
// Per-layer weight packing (fp32 -> bf16, q-scale fold, conv k-major repack)
// ---------------------------------------------------------------------------
__global__ __launch_bounds__(256)
void pack_attn_w(const float* __restrict__ w, bf16_t* __restrict__ Wqk,
                 bf16_t* __restrict__ Wv, bf16_t* __restrict__ Wo)
{
    int idx = blockIdx.x * 256 + threadIdx.x;      // < 4*512*512
    if (idx >= 4 * 512 * 512) return;
    int c = idx & 511;
    int o = (idx >> 9) & 511;
    int which = idx >> 18;
    float v = w[idx];
    if (which == 0) v *= 0.125f;
    if (which <= 1)      Wqk[(which * 512 + o) * 512 + c] = (bf16_t)v;
    else if (which == 2) Wv[o * 512 + c] = (bf16_t)v;
    else                 Wo[o * 512 + c] = (bf16_t)v;
}

__global__ __launch_bounds__(256)
void pack_attn_b(const float* __restrict__ bsrc, float* __restrict__ bqk)
{
    int idx = blockIdx.x * 256 + threadIdx.x;
    if (idx >= 6 * 2 * 512) return;     // only q,k need packing (q scaled)
    int c = idx & 511, which = (idx >> 9) & 1, i = idx >> 10;
    float v = bsrc[(i * 4 + which) * 512 + c];
    if (which == 0) v *= 0.125f;
    bqk[i * 1024 + which * 512 + c] = v;
}

__global__ __launch_bounds__(256)
void pack_w1k(const float* __restrict__ w, bf16_t* __restrict__ Wp)
{
    int idx = blockIdx.x * 256 + threadIdx.x;      // < 2048*1536
    if (idx >= 2048 * 1536) return;
    int c = idx & 511;
    int k = (idx >> 9) % 3;
    int f = idx / 1536;
    Wp[idx] = (bf16_t)w[(f * 512 + c) * 3 + k];    // w1[f][c][k] -> Wp[f][k][c]
}

__global__ __launch_bounds__(256)
void pack_w2k(const float* __restrict__ w, bf16_t* __restrict__ Wp)
{
    int idx = blockIdx.x * 256 + threadIdx.x;      // < 512*6144
    if (idx >= 512 * 6144) return;
    int f = idx & 2047;
    int k = (idx >> 11) % 3;
    int ci = idx / 6144;
    Wp[idx] = (bf16_t)w[ci * 6144 + f * 3 + k];    // w2[c][f][k] -> Wp[c][k][f]
}

// ---------------------------------------------------------------------------
extern "C" void kernel_launch(void* const* d_in, const int* in_sizes, int n_in,
                              void* d_out, int out_size, void* d_ws, size_t ws_size,
                              hipStream_t stream)
{
    const float* x      = (const float*)d_in[0];
    const float* xmask  = (const float*)d_in[1];
    const float* attn_w = (const float*)d_in[2];
    const float* attn_b = (const float*)d_in[3];
    const float* erk    = (const float*)d_in[4];
    const float* erv    = (const float*)d_in[5];
    const float* ln1g   = (const float*)d_in[6];
    const float* ln1b   = (const float*)d_in[7];
    const float* w1     = (const float*)d_in[8];
    const float* b1in   = (const float*)d_in[9];
    const float* w2     = (const float*)d_in[10];
    const float* b2in   = (const float*)d_in[11];
    const float* ln2g   = (const float*)d_in[12];
    const float* ln2b   = (const float*)d_in[13];
    float* out = (float*)d_out;

    char* p = (char*)d_ws;
    auto alloc = [&](size_t bytes) {
        char* r = p;
        p += (bytes + 255) & ~(size_t)255;
        return r;
    };
    // total ws usage ~110 MB (r9 layout)
    bf16_t* zpage = (bf16_t*)alloc(1024);
    bf16_t* Wqk_l = (bf16_t*)alloc(1024l * 512 * 2);
    bf16_t* Wv_l  = (bf16_t*)alloc(512l * 512 * 2);
    bf16_t* Wo_l  = (bf16_t*)alloc(512l * 512 * 2);
    bf16_t* W1p_l = (bf16_t*)alloc(2048l * 1536 * 2);
    bf16_t* W2p_l = (bf16_t*)alloc(512l * 6144 * 2);
    float*  bqk   = (float*)alloc(6l * 1024 * 4);
    float*  xres  = (float*)alloc(8192l * 512 * 4);
    bf16_t* xbf   = (bf16_t*)alloc(8192l * 512 * 2);
    bf16_t* big   = (bf16_t*)alloc(8192l * 2048 * 2);   // qk|vt|attn_out, aliased by hbuf
    bf16_t* ybuf  = (bf16_t*)alloc(8192l * 512 * 2);
    bf16_t* part  = (bf16_t*)alloc(3l * 8192 * 512 * 2); // conv2 tap partials
    float*  R     = (float*)alloc(64l * 1024 * 9 * 4);
    float*  stats = (float*)alloc(64l * 1024 * 2 * 4);   // (m, l) per row
    float*  kb    = (float*)alloc(8192l * 4);            // key-side mask bias
    (void)in_sizes; (void)n_in; (void)out_size; (void)ws_size;

    bf16_t* qk       = big;                    // [8192][1024]
    bf16_t* vt       = big + 8192l * 1024;     // [512][8192]
    bf16_t* attn_out = vt + 512l * 8192;       // [8192][512]
    bf16_t* hbuf     = big;                    // [8192][2048], aliases all three

    hipMemsetAsync(zpage, 0, 1024, stream);
    pack_attn_b<<<24, 256, 0, stream>>>(attn_b, bqk);
    mask_bias<<<32, 256, 0, stream>>>(xmask, kb);
    transpose_in_k<<<dim3(32, 16, 8), 256, 0, stream>>>(x, xmask, xres, xbf);

    for (int i = 0; i < 6; ++i) {
        pack_attn_w<<<4096, 256, 0, stream>>>(attn_w + (long)i * 4 * 512 * 512,
                                              Wqk_l, Wv_l, Wo_l);
        pack_w1k<<<12288, 256, 0, stream>>>(w1 + (long)i * 2048 * 512 * 3, W1p_l);
        pack_w2k<<<12288, 256, 0, stream>>>(w2 + (long)i * 512 * 2048 * 3, W2p_l);

        // QK projection (q pre-scaled): [1024,512] x [8192,512]^T -> qk[n][m]
        gemm_nt<128, 128, 0, 0, 1, 0, 0><<<dim3(64, 8, 1), 256, 0, stream>>>(
            Wqk_l, xbf, qk, bqk + i * 1024, nullptr, zpage,
            512, 512, 512, 1024, 0, 0, 0, 0, 0, 0, 0);
        // V projection -> channel-major vt[c][n]  (BM=64: 512 blocks, 2/CU)
        gemm_nt<64, 128, 1, 0, 1, 0, 0><<<dim3(64, 8, 1), 256, 0, stream>>>(
            Wv_l, xbf, vt, attn_b + (i * 4 + 2) * 512, nullptr, zpage,
            512, 512, 512, 8192, 0, 0, 0, 0, 0, 0, 0);
        // R table for banded rel-k logits
        rel_qk<<<16384, 256, 0, stream>>>(qk, erk + i * 576, R);
        // fused flash attention (static-max softmax, shuffle-free)
        flash_attn<<<dim3(64, 16), 256, 0, stream>>>(qk, vt, R, kb,
                                                     attn_out, stats);
        // banded rel-v finish (reconstruct band P from stats)
        band_finish<<<16384, 256, 0, stream>>>(qk, R, stats, erv + i * 576,
                                               kb, attn_out);
        // O projection (BM=64: 512 blocks)
        gemm_nt<64, 128, 0, 0, 1, 0, 0><<<dim3(64, 8, 1), 256, 0, stream>>>(
            Wo_l, attn_out, ybuf, attn_b + (i * 4 + 3) * 512, nullptr, zpage,
            512, 512, 512, 512, 0, 0, 0, 0, 0, 0, 0);
        // LN1 (xbf masked for conv1 input)
        ln_residual<1><<<2048, 256, 0, stream>>>(xres, ybuf, xbf,
                                                 ln1g + i * 512, ln1b + i * 512, xmask);
        // conv1 (K=3*512) + bias + relu + mask  -- BM=64: 2048 blocks, 8/CU
        gemm_nt<64, 128, 0, 1, 1, 1, 1><<<dim3(64, 32, 1), 256, 0, stream>>>(
            W1p_l, xbf, hbuf, b1in + i * 2048, xmask, zpage,
            1536, 1536, 512, 2048, 512, 0, 0, 0, 0, 0, 0);
        // conv2 split-K by tap: partials [3][8192][512] bf16 (BM=64: 1536 blocks)
        gemm_nt<64, 128, 0, 2, 0, 0, 0><<<dim3(64, 8, 3), 256, 0, stream>>>(
            W2p_l, hbuf, part, nullptr, nullptr, zpage,
            2048, 6144, 2048, 512, 2048, 0, 0, 0, 0, 0, 0);
        // LN2 fused with partial reduce + bias + mask
        ln_residual_p3<<<2048, 256, 0, stream>>>(xres, part, xbf,
                                                 ln2g + i * 512, ln2b + i * 512,
                                                 b2in + i * 512, xmask);
    }

    transpose_out_k<<<dim3(32, 16, 8), 256, 0, stream>>>(xres, xmask, out);
}

// Round 15
// 2801.530 us; speedup vs baseline: 1.3162x; 1.0065x over previous
//
#include <hip/hip_runtime.h>

typedef __bf16 bf16_t;
typedef __bf16 bf16x8 __attribute__((ext_vector_type(8)));
typedef __bf16 bf16x4 __attribute__((ext_vector_type(4)));
typedef float  f32x4  __attribute__((ext_vector_type(4)));

#define AS1 __attribute__((address_space(1)))
#define AS3 __attribute__((address_space(3)))

#define CMAX 16.0f   // static softmax max bound (true scores |s| ~ 1)

// ---------------------------------------------------------------------------
// Unified NT GEMM:  D[m][n] = sum_k A[m][k] * Bt[n][k]   (both K-contiguous)
// OUTMN=0: store C[n][m] (activation layout), OUTMN=1: store C[m][n].
// CONV=1: K = 3*CIN fused tap loop. CONV=2: split-K, blockIdx.z = tap,
//         K = CIN, writes bf16 partial at C + (tap<<22) + n*512 + m.
// ---------------------------------------------------------------------------
template<int BM, int BN, int OUTMN, int CONV, int BIAS, int RELU, int MASK>
__global__ __launch_bounds__(256)
void gemm_nt(const bf16_t* __restrict__ A, const bf16_t* __restrict__ B,
             bf16_t* __restrict__ C, const float* __restrict__ bias,
             const float* __restrict__ mask, const bf16_t* __restrict__ zpage,
             int K, int lda, int ldb, int ldc, int CIN,
             long sAb, long sAh, long sBb, long sBh, long sCb, long sCh)
{
    constexpr int BK = 32;
    __shared__ bf16_t As[BM * BK];
    __shared__ bf16_t Bs[BN * BK];
    const int z = blockIdx.z;
    int tap0 = 0;
    if constexpr (CONV == 2) {
        tap0 = z;
        A += (long)tap0 * CIN;             // tap's K-slice of the weight
    } else {
        A += (long)(z >> 3) * sAb + (long)(z & 7) * sAh;
        B += (long)(z >> 3) * sBb + (long)(z & 7) * sBh;
        C += (long)(z >> 3) * sCb + (long)(z & 7) * sCh;
    }
    const int m0 = blockIdx.y * BM;
    const int n0 = blockIdx.x * BN;
    const int tid = threadIdx.x;
    const int wid = tid >> 6, lane = tid & 63;
    constexpr int WM = BM / 2, WN = BN / 2;
    constexpr int FM = WM / 16, FN = WN / 16;
    const int wm = wid >> 1, wn = wid & 1;

    f32x4 acc[FM][FN] = {};

    constexpr int ACH = BM / 64;   // A chunks (16 rows = 1KB) per wave
    constexpr int BCH = BN / 64;
    const int rquad = lane >> 2;          // row within 16-row chunk
    const int koff  = (lane & 3) * 8;     // element offset along K

    int tap = 0, cc0 = 0;
    for (int k0 = 0; k0 < K; k0 += BK) {
        #pragma unroll
        for (int q = 0; q < ACH; ++q) {
            int ch  = wid * ACH + q;
            int row = ch * 16 + rquad;
            const bf16_t* src = A + (long)(m0 + row) * lda + (k0 + koff);
            __builtin_amdgcn_global_load_lds((const AS1 void*)src,
                                             (AS3 void*)(As + ch * 512), 16, 0, 0);
        }
        #pragma unroll
        for (int q = 0; q < BCH; ++q) {
            int ch  = wid * BCH + q;
            int row = ch * 16 + rquad;
            const bf16_t* src;
            if constexpr (CONV == 1) {
                int tl = (n0 & 1023) + row + tap - 1;
                src = ((unsigned)tl < 1024u)
                    ? B + (long)(n0 + row + tap - 1) * ldb + (cc0 + koff)
                    : zpage + koff;
            } else if constexpr (CONV == 2) {
                int tl = (n0 & 1023) + row + tap0 - 1;
                src = ((unsigned)tl < 1024u)
                    ? B + (long)(n0 + row + tap0 - 1) * ldb + (k0 + koff)
                    : zpage + koff;
            } else {
                src = B + (long)(n0 + row) * ldb + (k0 + koff);
            }
            __builtin_amdgcn_global_load_lds((const AS1 void*)src,
                                             (AS3 void*)(Bs + ch * 512), 16, 0, 0);
        }
        if constexpr (CONV == 1) { cc0 += BK; if (cc0 == CIN) { cc0 = 0; ++tap; } }
        __syncthreads();

        const bf16_t* Ab = As + (wm * WM + (lane & 15)) * BK + ((lane >> 4) * 8);
        const bf16_t* Bb = Bs + (wn * WN + (lane & 15)) * BK + ((lane >> 4) * 8);
        bf16x8 af[FM], bv[FN];
        #pragma unroll
        for (int i = 0; i < FM; ++i) af[i] = *(const bf16x8*)(Ab + i * 16 * BK);
        #pragma unroll
        for (int j = 0; j < FN; ++j) bv[j] = *(const bf16x8*)(Bb + j * 16 * BK);
        #pragma unroll
        for (int i = 0; i < FM; ++i)
            #pragma unroll
            for (int j = 0; j < FN; ++j)
                acc[i][j] = __builtin_amdgcn_mfma_f32_16x16x32_bf16(af[i], bv[j], acc[i][j], 0, 0, 0);
        __syncthreads();
    }

    const int mw = m0 + wm * WM, nw = n0 + wn * WN;
    #pragma unroll
    for (int i = 0; i < FM; ++i) {
        const int mb = mw + i * 16 + (lane >> 4) * 4;
        f32x4 bvv = {};
        if constexpr (BIAS) bvv = *(const f32x4*)(bias + mb);
        #pragma unroll
        for (int j = 0; j < FN; ++j) {
            const int nn = nw + j * 16 + (lane & 15);
            f32x4 v = acc[i][j];
            if constexpr (BIAS) v += bvv;
            if constexpr (RELU) {
                #pragma unroll
                for (int r = 0; r < 4; ++r) v[r] = fmaxf(v[r], 0.f);
            }
            if constexpr (MASK) v *= mask[nn];
            bf16x4 o;
            #pragma unroll
            for (int r = 0; r < 4; ++r) o[r] = (bf16_t)v[r];
            if constexpr (CONV == 2) {
                *(bf16x4*)(C + ((long)tap0 << 22) + (long)nn * 512 + mb) = o;
            } else if constexpr (OUTMN) {
                #pragma unroll
                for (int r = 0; r < 4; ++r) C[(long)(mb + r) * ldc + nn] = (bf16_t)v[r];
            } else {
                *(bf16x4*)(C + (long)nn * ldc + mb) = o;
            }
        }
    }
}

// ---------------------------------------------------------------------------
// R[bh,t,j] = sum_d q_scaled[b*1024+t][h*64+d] * erk[j][d]   (wave per (bh,t))
// ---------------------------------------------------------------------------
__global__ __launch_bounds__(256)
void rel_qk(const bf16_t* __restrict__ qk, const float* __restrict__ erk_l,
            float* __restrict__ R)
{
    int gw = blockIdx.x * 4 + (threadIdx.x >> 6);
    int z = gw >> 10, t = gw & 1023;
    int b = z >> 3, h = z & 7;
    int lane = threadIdx.x & 63;
    float qv = (float)qk[(long)(b * 1024 + t) * 1024 + h * 64 + lane];
    float r[9];
    #pragma unroll
    for (int j = 0; j < 9; ++j) r[j] = qv * erk_l[j * 64 + lane];
    #pragma unroll
    for (int o = 1; o < 64; o <<= 1)
        #pragma unroll
        for (int j = 0; j < 9; ++j) r[j] += __shfl_xor(r[j], o);
    if (lane == 0) {
        #pragma unroll
        for (int j = 0; j < 9; ++j) R[(long)gw * 9 + j] = r[j];
    }
}

// ---------------------------------------------------------------------------
// kb[n] = -1e4 if mask[n]==0 else 0   (additive key-side mask bias)
// ---------------------------------------------------------------------------
__global__ __launch_bounds__(256)
void mask_bias(const float* __restrict__ mask, float* __restrict__ kb)
{
    int i = blockIdx.x * 256 + threadIdx.x;
    if (i < 8192) kb[i] = (mask[i] == 0.f) ? -1e4f : 0.f;
}

// ---------------------------------------------------------------------------
// Fused flash attention with static-max softmax (p = exp(s - CMAX)), row-sum
// via ones-MFMA. Grid (64 bh, 16 qtiles), 4 waves, wave owns 16 q-rows.
// (r13 lesson: do NOT fuse the band rel-v accumulator here -- its 36-float
// loop-carried state spills to scratch; band_finish stays separate.)
// ---------------------------------------------------------------------------
__global__ __launch_bounds__(256)
void flash_attn(const bf16_t* __restrict__ qk, const bf16_t* __restrict__ vt,
                const float* __restrict__ R, const float* __restrict__ kb,
                bf16_t* __restrict__ out, float* __restrict__ stats)
{
    __shared__ bf16_t P_lds[4 * 1024];             // 2KB per wave
    const int w = threadIdx.x >> 6, lane = threadIdx.x & 63;
    const int hi = lane >> 4, li = lane & 15;
    const int bh = blockIdx.x, b = bh >> 3, h = bh & 7;
    const int q0 = blockIdx.y * 64 + w * 16;
    const long nbase = (long)b * 1024;
    char* pw = (char*)(P_lds + w * 1024);

    const bf16_t* qrow = qk + (nbase + q0 + li) * 1024 + h * 64 + hi * 8;
    bf16x8 aq0 = *(const bf16x8*)(qrow);
    bf16x8 aq1 = *(const bf16x8*)(qrow + 32);

    bf16x8 ones;
    #pragma unroll
    for (int e = 0; e < 8; ++e) ones[e] = (bf16_t)1.0f;

    f32x4 acc_o[4] = {};
    f32x4 acc_l = {};

    const bf16_t* kbase = qk + nbase * 1024 + 512 + h * 64 + hi * 8;
    const bf16_t* vbase = vt + (long)(h * 64 + li) * 8192 + nbase + hi * 8;
    const float* kbp = kb + b * 1024;

    bf16x8 kc[4][2], vv[4][2];
    #pragma unroll
    for (int j = 0; j < 4; ++j) {
        const bf16_t* kr = kbase + (long)(j * 16 + li) * 1024;
        kc[j][0] = *(const bf16x8*)kr;
        kc[j][1] = *(const bf16x8*)(kr + 32);
    }

    for (int it = 0; it < 16; ++it) {
        const int s0 = it * 64;
        #pragma unroll
        for (int j2 = 0; j2 < 4; ++j2) {
            const bf16_t* vr = vbase + (long)(j2 * 16) * 8192 + s0;
            vv[j2][0] = *(const bf16x8*)vr;
            vv[j2][1] = *(const bf16x8*)(vr + 32);
        }
        float kbv[4];
        #pragma unroll
        for (int j = 0; j < 4; ++j) kbv[j] = kbp[s0 + j * 16 + li];
        f32x4 sc[4];
        __builtin_amdgcn_s_setprio(1);
        #pragma unroll
        for (int j = 0; j < 4; ++j) {
            f32x4 a = {};
            a = __builtin_amdgcn_mfma_f32_16x16x32_bf16(aq0, kc[j][0], a, 0, 0, 0);
            a = __builtin_amdgcn_mfma_f32_16x16x32_bf16(aq1, kc[j][1], a, 0, 0, 0);
            sc[j] = a;
        }
        __builtin_amdgcn_s_setprio(0);
        const int s1 = (s0 + 64) & 1023;
        #pragma unroll
        for (int j = 0; j < 4; ++j) {
            const bf16_t* kr = kbase + (long)(s1 + j * 16 + li) * 1024;
            kc[j][0] = *(const bf16x8*)kr;
            kc[j][1] = *(const bf16x8*)(kr + 32);
        }
        #pragma unroll
        for (int j = 0; j < 4; ++j) {
            const int sb = s0 + j * 16;
            const bool near = (sb + 15 >= q0 - 4) && (sb <= q0 + 19);
            const int s_abs = sb + li;
            #pragma unroll
            for (int r = 0; r < 4; ++r) {
                const int q_abs = q0 + hi * 4 + r;
                float v = sc[j][r] + kbv[j];
                if (near) {
                    int jb = s_abs - q_abs + 4;
                    if ((unsigned)jb < 9u)
                        v += R[((long)bh * 1024 + q_abs) * 9 + jb];
                }
                sc[j][r] = __expf(v - CMAX);
            }
        }
        #pragma unroll
        for (int j = 0; j < 4; ++j)
            #pragma unroll
            for (int r = 0; r < 4; ++r) {
                int q = hi * 4 + r;
                int c = (j * 32 + li * 2) ^ ((q & 7) << 4);
                *(bf16_t*)(pw + q * 128 + c) = (bf16_t)sc[j][r];
            }
        asm volatile("s_waitcnt lgkmcnt(0)" ::: "memory");
        __builtin_amdgcn_s_setprio(1);
        #pragma unroll
        for (int half = 0; half < 2; ++half) {
            int cr = (half * 64 + hi * 16) ^ ((li & 7) << 4);
            bf16x8 pa = *(const bf16x8*)(pw + li * 128 + cr);
            #pragma unroll
            for (int j2 = 0; j2 < 4; ++j2)
                acc_o[j2] = __builtin_amdgcn_mfma_f32_16x16x32_bf16(pa, vv[j2][half], acc_o[j2], 0, 0, 0);
            acc_l = __builtin_amdgcn_mfma_f32_16x16x32_bf16(pa, ones, acc_l, 0, 0, 0);
        }
        __builtin_amdgcn_s_setprio(0);
    }

    #pragma unroll
    for (int r = 0; r < 4; ++r) {
        const float inv = 1.f / acc_l[r];
        const int q_abs = q0 + hi * 4 + r;
        #pragma unroll
        for (int j2 = 0; j2 < 4; ++j2) {
            const int d = j2 * 16 + li;
            out[(nbase + q_abs) * 512 + h * 64 + d] = (bf16_t)(acc_o[j2][r] * inv);
        }
        if (li == 0) {
            stats[2 * ((long)bh * 1024 + q_abs)]     = CMAX;
            stats[2 * ((long)bh * 1024 + q_abs) + 1] = acc_l[r];
        }
    }
}

// ---------------------------------------------------------------------------
// Banded rel-v finish: out[bh,t,d] += sum_j p_j * erv[j][d].
// ---------------------------------------------------------------------------
__global__ __launch_bounds__(256)
void band_finish(const bf16_t* __restrict__ qk, const float* __restrict__ R,
                 const float* __restrict__ stats, const float* __restrict__ erv_l,
                 const float* __restrict__ kb, bf16_t* __restrict__ out)
{
    int gw = blockIdx.x * 4 + (threadIdx.x >> 6);   // bh*1024 + t
    int bh = gw >> 10, t = gw & 1023;
    int b = bh >> 3, h = bh & 7;
    int lane = threadIdx.x & 63;
    const long nb = (long)b * 1024;
    float qv = (float)qk[(nb + t) * 1024 + h * 64 + lane];
    float p[9];
    #pragma unroll
    for (int j = 0; j < 9; ++j) {
        int s = t + j - 4;
        float dot = 0.f;
        if ((unsigned)s < 1024u)
            dot = qv * (float)qk[(nb + s) * 1024 + 512 + h * 64 + lane];
        p[j] = dot;
    }
    #pragma unroll
    for (int o = 1; o < 64; o <<= 1)
        #pragma unroll
        for (int j = 0; j < 9; ++j) p[j] += __shfl_xor(p[j], o);
    float m = stats[2 * (long)gw], invl = 1.f / stats[2 * (long)gw + 1];
    #pragma unroll
    for (int j = 0; j < 9; ++j) {
        int s = t + j - 4;
        if ((unsigned)s < 1024u) {
            float sc = p[j] + R[(long)gw * 9 + j] + kb[b * 1024 + s];
            p[j] = __expf(sc - m) * invl;
        } else p[j] = 0.f;
    }
    long oidx = (nb + t) * 512 + h * 64 + lane;
    float v = (float)out[oidx];
    #pragma unroll
    for (int j = 0; j < 9; ++j) v += p[j] * erv_l[j * 64 + lane];
    out[oidx] = (bf16_t)v;
}

// ---------------------------------------------------------------------------
// Residual + LayerNorm over C=512 (wave per row n).
// ---------------------------------------------------------------------------
template<int MASKOUT>
__global__ __launch_bounds__(256)
void ln_residual(float* __restrict__ xres, const bf16_t* __restrict__ y,
                 bf16_t* __restrict__ xbf, const float* __restrict__ g,
                 const float* __restrict__ bvec, const float* __restrict__ mask)
{
    int gw = blockIdx.x * 4 + (threadIdx.x >> 6);
    int lane = threadIdx.x & 63;
    long base = (long)gw * 512 + lane * 8;
    f32x4 x0 = *(const f32x4*)(xres + base);
    f32x4 x1 = *(const f32x4*)(xres + base + 4);
    bf16x8 yv = *(const bf16x8*)(y + base);
    float s[8];
    #pragma unroll
    for (int e = 0; e < 4; ++e) { s[e] = x0[e] + (float)yv[e]; s[4 + e] = x1[e] + (float)yv[4 + e]; }
    float sum = 0.f, sq = 0.f;
    #pragma unroll
    for (int e = 0; e < 8; ++e) { sum += s[e]; sq += s[e] * s[e]; }
    #pragma unroll
    for (int o = 1; o < 64; o <<= 1) { sum += __shfl_xor(sum, o); sq += __shfl_xor(sq, o); }
    float mean = sum * (1.f / 512.f);
    float var  = sq * (1.f / 512.f) - mean * mean;
    float rstd = rsqrtf(var + 1e-5f);
    f32x4 g0 = *(const f32x4*)(g + lane * 8);
    f32x4 g1 = *(const f32x4*)(g + lane * 8 + 4);
    f32x4 b0 = *(const f32x4*)(bvec + lane * 8);
    f32x4 b1 = *(const f32x4*)(bvec + lane * 8 + 4);
    float mk = MASKOUT ? mask[gw] : 1.f;
    f32x4 o0, o1; bf16x8 ob;
    #pragma unroll
    for (int e = 0; e < 4; ++e) {
        float v0 = (s[e] - mean) * rstd * g0[e] + b0[e];
        float v1 = (s[4 + e] - mean) * rstd * g1[e] + b1[e];
        o0[e] = v0; o1[e] = v1;
        ob[e] = (bf16_t)(v0 * mk); ob[4 + e] = (bf16_t)(v1 * mk);
    }
    *(f32x4*)(xres + base) = o0;
    *(f32x4*)(xres + base + 4) = o1;
    *(bf16x8*)(xbf + base) = ob;
}

// ---------------------------------------------------------------------------
// Sum of 3 conv2 tap-partials + bias, mask, residual + LayerNorm (ln2).
// ---------------------------------------------------------------------------
__global__ __launch_bounds__(256)
void ln_residual_p3(float* __restrict__ xres, const bf16_t* __restrict__ part,
                    bf16_t* __restrict__ xbf, const float* __restrict__ g,
                    const float* __restrict__ bvec, const float* __restrict__ bias,
                    const float* __restrict__ mask)
{
    int gw = blockIdx.x * 4 + (threadIdx.x >> 6);
    int lane = threadIdx.x & 63;
    long base = (long)gw * 512 + lane * 8;
    bf16x8 pa = *(const bf16x8*)(part + base);
    bf16x8 pbv = *(const bf16x8*)(part + base + (1l << 22));
    bf16x8 pc = *(const bf16x8*)(part + base + (2l << 22));
    f32x4 x0 = *(const f32x4*)(xres + base);
    f32x4 x1 = *(const f32x4*)(xres + base + 4);
    f32x4 bi0 = *(const f32x4*)(bias + lane * 8);
    f32x4 bi1 = *(const f32x4*)(bias + lane * 8 + 4);
    float mk = mask[gw];
    float s[8];
    #pragma unroll
    for (int e = 0; e < 4; ++e) {
        float y0 = ((float)pa[e] + (float)pbv[e] + (float)pc[e] + bi0[e]) * mk;
        float y1 = ((float)pa[4 + e] + (float)pbv[4 + e] + (float)pc[4 + e] + bi1[e]) * mk;
        s[e] = x0[e] + y0; s[4 + e] = x1[e] + y1;
    }
    float sum = 0.f, sq = 0.f;
    #pragma unroll
    for (int e = 0; e < 8; ++e) { sum += s[e]; sq += s[e] * s[e]; }
    #pragma unroll
    for (int o = 1; o < 64; o <<= 1) { sum += __shfl_xor(sum, o); sq += __shfl_xor(sq, o); }
    float mean = sum * (1.f / 512.f);
    float var  = sq * (1.f / 512.f) - mean * mean;
    float rstd = rsqrtf(var + 1e-5f);
    f32x4 g0 = *(const f32x4*)(g + lane * 8);
    f32x4 g1 = *(const f32x4*)(g + lane * 8 + 4);
    f32x4 b0 = *(const f32x4*)(bvec + lane * 8);
    f32x4 b1 = *(const f32x4*)(bvec + lane * 8 + 4);
    f32x4 o0, o1; bf16x8 ob;
    #pragma unroll
    for (int e = 0; e < 4; ++e) {
        float v0 = (s[e] - mean) * rstd * g0[e] + b0[e];
        float v1 = (s[4 + e] - mean) * rstd * g1[e] + b1[e];
        o0[e] = v0; o1[e] = v1;
        ob[e] = (bf16_t)v0; ob[4 + e] = (bf16_t)v1;
    }
    *(f32x4*)(xres + base) = o0;
    *(f32x4*)(xres + base + 4) = o1;
    *(bf16x8*)(xbf + base) = ob;
}

// ---------------------------------------------------------------------------
// Transposes: x[B,C,T] <-> act[B*T, C]
// ---------------------------------------------------------------------------
__global__ __launch_bounds__(256)
void transpose_in_k(const float* __restrict__ x, const float* __restrict__ mask,
                    float* __restrict__ xres, bf16_t* __restrict__ xbf)
{
    __shared__ float tile[32][33];
    int b = blockIdx.z, c0 = blockIdx.y * 32, t0 = blockIdx.x * 32;
    int tx = threadIdx.x & 31, ty = threadIdx.x >> 5;
    #pragma unroll
    for (int r = 0; r < 4; ++r) {
        int cl = ty + r * 8;
        tile[cl][tx] = x[((long)b * 512 + c0 + cl) * 1024 + t0 + tx];
    }
    __syncthreads();
    #pragma unroll
    for (int r = 0; r < 4; ++r) {
        int tl = ty + r * 8;
        int n = b * 1024 + t0 + tl;
        float v = tile[tx][tl] * mask[n];
        xres[(long)n * 512 + c0 + tx] = v;
        xbf[(long)n * 512 + c0 + tx] = (bf16_t)v;
    }
}

__global__ __launch_bounds__(256)
void transpose_out_k(const float* __restrict__ xres, const float* __restrict__ mask,
                     float* __restrict__ out)
{
    __shared__ float tile[32][33];
    int b = blockIdx.z, c0 = blockIdx.y * 32, t0 = blockIdx.x * 32;
    int tx = threadIdx.x & 31, ty = threadIdx.x >> 5;
    #pragma unroll
    for (int r = 0; r < 4; ++r) {
        int tl = ty + r * 8;
        int n = b * 1024 + t0 + tl;
        tile[tl][tx] = xres[(long)n * 512 + c0 + tx] * mask[n];
    }
    __syncthreads();
    #pragma unroll
    for (int r = 0; r < 4; ++r) {
        int cl = ty + r * 8;
        out[((long)b * 512 + c0 + cl) * 1024 + t0 + tx] = tile[tx][cl];
    }
}

// ---------------------------------------------------------------------------
// Per-layer weight packing (fp32 -> bf16, q-scale fold, conv k-major repack)
// ---------------------------------------------------------------------------
__global__ __launch_bounds__(256)
void pack_attn_w(const float* __restrict__ w, bf16_t* __restrict__ Wqk,
                 bf16_t* __restrict__ Wv, bf16_t* __restrict__ Wo)
{
    int idx = blockIdx.x * 256 + threadIdx.x;      // < 4*512*512
    if (idx >= 4 * 512 * 512) return;
    int c = idx & 511;
    int o = (idx >> 9) & 511;
    int which = idx >> 18;
    float v = w[idx];
    if (which == 0) v *= 0.125f;
    if (which <= 1)      Wqk[(which * 512 + o) * 512 + c] = (bf16_t)v;
    else if (which == 2) Wv[o * 512 + c] = (bf16_t)v;
    else                 Wo[o * 512 + c] = (bf16_t)v;
}

__global__ __launch_bounds__(256)
void pack_attn_b(const float* __restrict__ bsrc, float* __restrict__ bqk)
{
    int idx = blockIdx.x * 256 + threadIdx.x;
    if (idx >= 6 * 2 * 512) return;     // only q,k need packing (q scaled)
    int c = idx & 511, which = (idx >> 9) & 1, i = idx >> 10;
    float v = bsrc[(i * 4 + which) * 512 + c];
    if (which == 0) v *= 0.125f;
    bqk[i * 1024 + which * 512 + c] = v;
}

__global__ __launch_bounds__(256)
void pack_w1k(const float* __restrict__ w, bf16_t* __restrict__ Wp)
{
    int idx = blockIdx.x * 256 + threadIdx.x;      // < 2048*1536
    if (idx >= 2048 * 1536) return;
    int c = idx & 511;
    int k = (idx >> 9) % 3;
    int f = idx / 1536;
    Wp[idx] = (bf16_t)w[(f * 512 + c) * 3 + k];    // w1[f][c][k] -> Wp[f][k][c]
}

__global__ __launch_bounds__(256)
void pack_w2k(const float* __restrict__ w, bf16_t* __restrict__ Wp)
{
    int idx = blockIdx.x * 256 + threadIdx.x;      // < 512*6144
    if (idx >= 512 * 6144) return;
    int f = idx & 2047;
    int k = (idx >> 11) % 3;
    int ci = idx / 6144;
    Wp[idx] = (bf16_t)w[ci * 6144 + f * 3 + k];    // w2[c][f][k] -> Wp[c][k][f]
}

// ---------------------------------------------------------------------------
extern "C" void kernel_launch(void* const* d_in, const int* in_sizes, int n_in,
                              void* d_out, int out_size, void* d_ws, size_t ws_size,
                              hipStream_t stream)
{
    const float* x      = (const float*)d_in[0];
    const float* xmask  = (const float*)d_in[1];
    const float* attn_w = (const float*)d_in[2];
    const float* attn_b = (const float*)d_in[3];
    const float* erk    = (const float*)d_in[4];
    const float* erv    = (const float*)d_in[5];
    const float* ln1g   = (const float*)d_in[6];
    const float* ln1b   = (const float*)d_in[7];
    const float* w1     = (const float*)d_in[8];
    const float* b1in   = (const float*)d_in[9];
    const float* w2     = (const float*)d_in[10];
    const float* b2in   = (const float*)d_in[11];
    const float* ln2g   = (const float*)d_in[12];
    const float* ln2b   = (const float*)d_in[13];
    float* out = (float*)d_out;

    char* p = (char*)d_ws;
    auto alloc = [&](size_t bytes) {
        char* r = p;
        p += (bytes + 255) & ~(size_t)255;
        return r;
    };
    // total ws usage ~110 MB (r9 layout)
    bf16_t* zpage = (bf16_t*)alloc(1024);
    bf16_t* Wqk_l = (bf16_t*)alloc(1024l * 512 * 2);
    bf16_t* Wv_l  = (bf16_t*)alloc(512l * 512 * 2);
    bf16_t* Wo_l  = (bf16_t*)alloc(512l * 512 * 2);
    bf16_t* W1p_l = (bf16_t*)alloc(2048l * 1536 * 2);
    bf16_t* W2p_l = (bf16_t*)alloc(512l * 6144 * 2);
    float*  bqk   = (float*)alloc(6l * 1024 * 4);
    float*  xres  = (float*)alloc(8192l * 512 * 4);
    bf16_t* xbf   = (bf16_t*)alloc(8192l * 512 * 2);
    bf16_t* big   = (bf16_t*)alloc(8192l * 2048 * 2);   // qk|vt|attn_out, aliased by hbuf
    bf16_t* ybuf  = (bf16_t*)alloc(8192l * 512 * 2);
    bf16_t* part  = (bf16_t*)alloc(3l * 8192 * 512 * 2); // conv2 tap partials
    float*  R     = (float*)alloc(64l * 1024 * 9 * 4);
    float*  stats = (float*)alloc(64l * 1024 * 2 * 4);   // (m, l) per row
    float*  kb    = (float*)alloc(8192l * 4);            // key-side mask bias
    (void)in_sizes; (void)n_in; (void)out_size; (void)ws_size;

    bf16_t* qk       = big;                    // [8192][1024]
    bf16_t* vt       = big + 8192l * 1024;     // [512][8192]
    bf16_t* attn_out = vt + 512l * 8192;       // [8192][512]
    bf16_t* hbuf     = big;                    // [8192][2048], aliases all three

    hipMemsetAsync(zpage, 0, 1024, stream);
    pack_attn_b<<<24, 256, 0, stream>>>(attn_b, bqk);
    mask_bias<<<32, 256, 0, stream>>>(xmask, kb);
    transpose_in_k<<<dim3(32, 16, 8), 256, 0, stream>>>(x, xmask, xres, xbf);

    for (int i = 0; i < 6; ++i) {
        pack_attn_w<<<4096, 256, 0, stream>>>(attn_w + (long)i * 4 * 512 * 512,
                                              Wqk_l, Wv_l, Wo_l);
        pack_w1k<<<12288, 256, 0, stream>>>(w1 + (long)i * 2048 * 512 * 3, W1p_l);
        pack_w2k<<<12288, 256, 0, stream>>>(w2 + (long)i * 512 * 2048 * 3, W2p_l);

        // QK projection (q pre-scaled) -- BM=64: 1024 blocks, 4/CU
        gemm_nt<64, 128, 0, 0, 1, 0, 0><<<dim3(64, 16, 1), 256, 0, stream>>>(
            Wqk_l, xbf, qk, bqk + i * 1024, nullptr, zpage,
            512, 512, 512, 1024, 0, 0, 0, 0, 0, 0, 0);
        // V projection -> channel-major vt[c][n] -- BN=64: 1024 blocks
        gemm_nt<64, 64, 1, 0, 1, 0, 0><<<dim3(128, 8, 1), 256, 0, stream>>>(
            Wv_l, xbf, vt, attn_b + (i * 4 + 2) * 512, nullptr, zpage,
            512, 512, 512, 8192, 0, 0, 0, 0, 0, 0, 0);
        // R table for banded rel-k logits
        rel_qk<<<16384, 256, 0, stream>>>(qk, erk + i * 576, R);
        // fused flash attention (static-max softmax, shuffle-free)
        flash_attn<<<dim3(64, 16), 256, 0, stream>>>(qk, vt, R, kb,
                                                     attn_out, stats);
        // banded rel-v finish (reconstruct band P from stats)
        band_finish<<<16384, 256, 0, stream>>>(qk, R, stats, erv + i * 576,
                                               kb, attn_out);
        // O projection -- BN=64: 1024 blocks
        gemm_nt<64, 64, 0, 0, 1, 0, 0><<<dim3(128, 8, 1), 256, 0, stream>>>(
            Wo_l, attn_out, ybuf, attn_b + (i * 4 + 3) * 512, nullptr, zpage,
            512, 512, 512, 512, 0, 0, 0, 0, 0, 0, 0);
        // LN1 (xbf masked for conv1 input)
        ln_residual<1><<<2048, 256, 0, stream>>>(xres, ybuf, xbf,
                                                 ln1g + i * 512, ln1b + i * 512, xmask);
        // conv1 (K=3*512) + bias + relu + mask  -- BM=64: 2048 blocks, 8/CU
        gemm_nt<64, 128, 0, 1, 1, 1, 1><<<dim3(64, 32, 1), 256, 0, stream>>>(
            W1p_l, xbf, hbuf, b1in + i * 2048, xmask, zpage,
            1536, 1536, 512, 2048, 512, 0, 0, 0, 0, 0, 0);
        // conv2 split-K by tap: partials [3][8192][512] bf16 (1536 blocks)
        gemm_nt<64, 128, 0, 2, 0, 0, 0><<<dim3(64, 8, 3), 256, 0, stream>>>(
            W2p_l, hbuf, part, nullptr, nullptr, zpage,
            2048, 6144, 2048, 512, 2048, 0, 0, 0, 0, 0, 0);
        // LN2 fused with partial reduce + bias + mask
        ln_residual_p3<<<2048, 256, 0, stream>>>(xres, part, xbf,
                                                 ln2g + i * 512, ln2b + i * 512,
                                                 b2in + i * 512, xmask);
    }

    transpose_out_k<<<dim3(32, 16, 8), 256, 0, stream>>>(xres, xmask, out);
}

// Round 16
// 2616.907 us; speedup vs baseline: 1.4090x; 1.0706x over previous
//
#include <hip/hip_runtime.h>

typedef __bf16 bf16_t;
typedef __bf16 bf16x8 __attribute__((ext_vector_type(8)));
typedef __bf16 bf16x4 __attribute__((ext_vector_type(4)));
typedef float  f32x4  __attribute__((ext_vector_type(4)));

#define AS1 __attribute__((address_space(1)))
#define AS3 __attribute__((address_space(3)))

#define CMAX 16.0f   // static softmax max bound (true scores |s| ~ 1)

// ---------------------------------------------------------------------------
// Unified NT GEMM:  D[m][n] = sum_k A[m][k] * Bt[n][k]   (both K-contiguous)
// OUTMN=0: store C[n][m] (activation layout), OUTMN=1: store C[m][n].
// CONV=1: K = 3*CIN fused tap loop. CONV=2: split-K, blockIdx.z = tap,
//         K = CIN, writes bf16 partial at C + (tap<<22) + n*512 + m.
// ---------------------------------------------------------------------------
template<int BM, int BN, int OUTMN, int CONV, int BIAS, int RELU, int MASK>
__global__ __launch_bounds__(256)
void gemm_nt(const bf16_t* __restrict__ A, const bf16_t* __restrict__ B,
             bf16_t* __restrict__ C, const float* __restrict__ bias,
             const float* __restrict__ mask, const bf16_t* __restrict__ zpage,
             int K, int lda, int ldb, int ldc, int CIN,
             long sAb, long sAh, long sBb, long sBh, long sCb, long sCh)
{
    constexpr int BK = 32;
    __shared__ bf16_t As[BM * BK];
    __shared__ bf16_t Bs[BN * BK];
    const int z = blockIdx.z;
    int tap0 = 0;
    if constexpr (CONV == 2) {
        tap0 = z;
        A += (long)tap0 * CIN;             // tap's K-slice of the weight
    } else {
        A += (long)(z >> 3) * sAb + (long)(z & 7) * sAh;
        B += (long)(z >> 3) * sBb + (long)(z & 7) * sBh;
        C += (long)(z >> 3) * sCb + (long)(z & 7) * sCh;
    }
    const int m0 = blockIdx.y * BM;
    const int n0 = blockIdx.x * BN;
    const int tid = threadIdx.x;
    const int wid = tid >> 6, lane = tid & 63;
    constexpr int WM = BM / 2, WN = BN / 2;
    constexpr int FM = WM / 16, FN = WN / 16;
    const int wm = wid >> 1, wn = wid & 1;

    f32x4 acc[FM][FN] = {};

    constexpr int ACH = BM / 64;   // A chunks (16 rows = 1KB) per wave
    constexpr int BCH = BN / 64;
    const int rquad = lane >> 2;          // row within 16-row chunk
    const int koff  = (lane & 3) * 8;     // element offset along K

    int tap = 0, cc0 = 0;
    for (int k0 = 0; k0 < K; k0 += BK) {
        #pragma unroll
        for (int q = 0; q < ACH; ++q) {
            int ch  = wid * ACH + q;
            int row = ch * 16 + rquad;
            const bf16_t* src = A + (long)(m0 + row) * lda + (k0 + koff);
            __builtin_amdgcn_global_load_lds((const AS1 void*)src,
                                             (AS3 void*)(As + ch * 512), 16, 0, 0);
        }
        #pragma unroll
        for (int q = 0; q < BCH; ++q) {
            int ch  = wid * BCH + q;
            int row = ch * 16 + rquad;
            const bf16_t* src;
            if constexpr (CONV == 1) {
                int tl = (n0 & 1023) + row + tap - 1;
                src = ((unsigned)tl < 1024u)
                    ? B + (long)(n0 + row + tap - 1) * ldb + (cc0 + koff)
                    : zpage + koff;
            } else if constexpr (CONV == 2) {
                int tl = (n0 & 1023) + row + tap0 - 1;
                src = ((unsigned)tl < 1024u)
                    ? B + (long)(n0 + row + tap0 - 1) * ldb + (k0 + koff)
                    : zpage + koff;
            } else {
                src = B + (long)(n0 + row) * ldb + (k0 + koff);
            }
            __builtin_amdgcn_global_load_lds((const AS1 void*)src,
                                             (AS3 void*)(Bs + ch * 512), 16, 0, 0);
        }
        if constexpr (CONV == 1) { cc0 += BK; if (cc0 == CIN) { cc0 = 0; ++tap; } }
        __syncthreads();

        const bf16_t* Ab = As + (wm * WM + (lane & 15)) * BK + ((lane >> 4) * 8);
        const bf16_t* Bb = Bs + (wn * WN + (lane & 15)) * BK + ((lane >> 4) * 8);
        bf16x8 af[FM], bv[FN];
        #pragma unroll
        for (int i = 0; i < FM; ++i) af[i] = *(const bf16x8*)(Ab + i * 16 * BK);
        #pragma unroll
        for (int j = 0; j < FN; ++j) bv[j] = *(const bf16x8*)(Bb + j * 16 * BK);
        #pragma unroll
        for (int i = 0; i < FM; ++i)
            #pragma unroll
            for (int j = 0; j < FN; ++j)
                acc[i][j] = __builtin_amdgcn_mfma_f32_16x16x32_bf16(af[i], bv[j], acc[i][j], 0, 0, 0);
        __syncthreads();
    }

    const int mw = m0 + wm * WM, nw = n0 + wn * WN;
    #pragma unroll
    for (int i = 0; i < FM; ++i) {
        const int mb = mw + i * 16 + (lane >> 4) * 4;
        f32x4 bvv = {};
        if constexpr (BIAS) bvv = *(const f32x4*)(bias + mb);
        #pragma unroll
        for (int j = 0; j < FN; ++j) {
            const int nn = nw + j * 16 + (lane & 15);
            f32x4 v = acc[i][j];
            if constexpr (BIAS) v += bvv;
            if constexpr (RELU) {
                #pragma unroll
                for (int r = 0; r < 4; ++r) v[r] = fmaxf(v[r], 0.f);
            }
            if constexpr (MASK) v *= mask[nn];
            bf16x4 o;
            #pragma unroll
            for (int r = 0; r < 4; ++r) o[r] = (bf16_t)v[r];
            if constexpr (CONV == 2) {
                *(bf16x4*)(C + ((long)tap0 << 22) + (long)nn * 512 + mb) = o;
            } else if constexpr (OUTMN) {
                #pragma unroll
                for (int r = 0; r < 4; ++r) C[(long)(mb + r) * ldc + nn] = (bf16_t)v[r];
            } else {
                *(bf16x4*)(C + (long)nn * ldc + mb) = o;
            }
        }
    }
}

// ---------------------------------------------------------------------------
// R[bh,t,j] = sum_d q_scaled[t][h*64+d] * erk[j][d] via MFMA (16x16x32).
// Grid (64 bh, 16 t-tiles), 4 waves; wave computes a 16t x 16j tile (9 j
// valid). Replaces the 54-shuffle wave-reduce version (~4x faster).
// ---------------------------------------------------------------------------
__global__ __launch_bounds__(256)
void rel_qk_mfma(const bf16_t* __restrict__ qk, const float* __restrict__ erk_l,
                 float* __restrict__ R)
{
    const int w = threadIdx.x >> 6, lane = threadIdx.x & 63;
    const int hi = lane >> 4, li = lane & 15;
    const int bh = blockIdx.x, b = bh >> 3, h = bh & 7;
    const int t0 = blockIdx.y * 64 + w * 16;
    const long nb = (long)b * 1024;

    const bf16_t* qrow = qk + (nb + t0 + li) * 1024 + h * 64 + hi * 8;
    bf16x8 aq0 = *(const bf16x8*)(qrow);
    bf16x8 aq1 = *(const bf16x8*)(qrow + 32);

    bf16x8 be0, be1;
    #pragma unroll
    for (int e = 0; e < 8; ++e) {
        float v0 = (li < 9) ? erk_l[li * 64 + hi * 8 + e] : 0.f;
        float v1 = (li < 9) ? erk_l[li * 64 + 32 + hi * 8 + e] : 0.f;
        be0[e] = (bf16_t)v0; be1[e] = (bf16_t)v1;
    }
    f32x4 acc = {};
    acc = __builtin_amdgcn_mfma_f32_16x16x32_bf16(aq0, be0, acc, 0, 0, 0);
    acc = __builtin_amdgcn_mfma_f32_16x16x32_bf16(aq1, be1, acc, 0, 0, 0);
    if (li < 9) {
        #pragma unroll
        for (int r = 0; r < 4; ++r) {
            int t = t0 + hi * 4 + r;
            R[((long)bh * 1024 + t) * 9 + li] = acc[r];
        }
    }
}

// ---------------------------------------------------------------------------
// kb[n] = -1e4 if mask[n]==0 else 0   (additive key-side mask bias)
// ---------------------------------------------------------------------------
__global__ __launch_bounds__(256)
void mask_bias(const float* __restrict__ mask, float* __restrict__ kb)
{
    int i = blockIdx.x * 256 + threadIdx.x;
    if (i < 8192) kb[i] = (mask[i] == 0.f) ? -1e4f : 0.f;
}

// ---------------------------------------------------------------------------
// Fused flash attention with static-max softmax (p = exp(s - CMAX)), row-sum
// via ones-MFMA. Grid (64 bh, 16 qtiles), 4 waves, wave owns 16 q-rows.
// (r13 lesson: do NOT fuse the band rel-v accumulator here -- its 36-float
// loop-carried state spills to scratch; band_finish stays separate.)
// ---------------------------------------------------------------------------
__global__ __launch_bounds__(256)
void flash_attn(const bf16_t* __restrict__ qk, const bf16_t* __restrict__ vt,
                const float* __restrict__ R, const float* __restrict__ kb,
                bf16_t* __restrict__ out, float* __restrict__ stats)
{
    __shared__ bf16_t P_lds[4 * 1024];             // 2KB per wave
    const int w = threadIdx.x >> 6, lane = threadIdx.x & 63;
    const int hi = lane >> 4, li = lane & 15;
    const int bh = blockIdx.x, b = bh >> 3, h = bh & 7;
    const int q0 = blockIdx.y * 64 + w * 16;
    const long nbase = (long)b * 1024;
    char* pw = (char*)(P_lds + w * 1024);

    const bf16_t* qrow = qk + (nbase + q0 + li) * 1024 + h * 64 + hi * 8;
    bf16x8 aq0 = *(const bf16x8*)(qrow);
    bf16x8 aq1 = *(const bf16x8*)(qrow + 32);

    bf16x8 ones;
    #pragma unroll
    for (int e = 0; e < 8; ++e) ones[e] = (bf16_t)1.0f;

    f32x4 acc_o[4] = {};
    f32x4 acc_l = {};

    const bf16_t* kbase = qk + nbase * 1024 + 512 + h * 64 + hi * 8;
    const bf16_t* vbase = vt + (long)(h * 64 + li) * 8192 + nbase + hi * 8;
    const float* kbp = kb + b * 1024;

    bf16x8 kc[4][2], vv[4][2];
    #pragma unroll
    for (int j = 0; j < 4; ++j) {
        const bf16_t* kr = kbase + (long)(j * 16 + li) * 1024;
        kc[j][0] = *(const bf16x8*)kr;
        kc[j][1] = *(const bf16x8*)(kr + 32);
    }

    for (int it = 0; it < 16; ++it) {
        const int s0 = it * 64;
        #pragma unroll
        for (int j2 = 0; j2 < 4; ++j2) {
            const bf16_t* vr = vbase + (long)(j2 * 16) * 8192 + s0;
            vv[j2][0] = *(const bf16x8*)vr;
            vv[j2][1] = *(const bf16x8*)(vr + 32);
        }
        float kbv[4];
        #pragma unroll
        for (int j = 0; j < 4; ++j) kbv[j] = kbp[s0 + j * 16 + li];
        f32x4 sc[4];
        __builtin_amdgcn_s_setprio(1);
        #pragma unroll
        for (int j = 0; j < 4; ++j) {
            f32x4 a = {};
            a = __builtin_amdgcn_mfma_f32_16x16x32_bf16(aq0, kc[j][0], a, 0, 0, 0);
            a = __builtin_amdgcn_mfma_f32_16x16x32_bf16(aq1, kc[j][1], a, 0, 0, 0);
            sc[j] = a;
        }
        __builtin_amdgcn_s_setprio(0);
        const int s1 = (s0 + 64) & 1023;
        #pragma unroll
        for (int j = 0; j < 4; ++j) {
            const bf16_t* kr = kbase + (long)(s1 + j * 16 + li) * 1024;
            kc[j][0] = *(const bf16x8*)kr;
            kc[j][1] = *(const bf16x8*)(kr + 32);
        }
        #pragma unroll
        for (int j = 0; j < 4; ++j) {
            const int sb = s0 + j * 16;
            const bool near = (sb + 15 >= q0 - 4) && (sb <= q0 + 19);
            const int s_abs = sb + li;
            #pragma unroll
            for (int r = 0; r < 4; ++r) {
                const int q_abs = q0 + hi * 4 + r;
                float v = sc[j][r] + kbv[j];
                if (near) {
                    int jb = s_abs - q_abs + 4;
                    if ((unsigned)jb < 9u)
                        v += R[((long)bh * 1024 + q_abs) * 9 + jb];
                }
                sc[j][r] = __expf(v - CMAX);
            }
        }
        #pragma unroll
        for (int j = 0; j < 4; ++j)
            #pragma unroll
            for (int r = 0; r < 4; ++r) {
                int q = hi * 4 + r;
                int c = (j * 32 + li * 2) ^ ((q & 7) << 4);
                *(bf16_t*)(pw + q * 128 + c) = (bf16_t)sc[j][r];
            }
        asm volatile("s_waitcnt lgkmcnt(0)" ::: "memory");
        __builtin_amdgcn_s_setprio(1);
        #pragma unroll
        for (int half = 0; half < 2; ++half) {
            int cr = (half * 64 + hi * 16) ^ ((li & 7) << 4);
            bf16x8 pa = *(const bf16x8*)(pw + li * 128 + cr);
            #pragma unroll
            for (int j2 = 0; j2 < 4; ++j2)
                acc_o[j2] = __builtin_amdgcn_mfma_f32_16x16x32_bf16(pa, vv[j2][half], acc_o[j2], 0, 0, 0);
            acc_l = __builtin_amdgcn_mfma_f32_16x16x32_bf16(pa, ones, acc_l, 0, 0, 0);
        }
        __builtin_amdgcn_s_setprio(0);
    }

    #pragma unroll
    for (int r = 0; r < 4; ++r) {
        const float inv = 1.f / acc_l[r];
        const int q_abs = q0 + hi * 4 + r;
        #pragma unroll
        for (int j2 = 0; j2 < 4; ++j2) {
            const int d = j2 * 16 + li;
            out[(nbase + q_abs) * 512 + h * 64 + d] = (bf16_t)(acc_o[j2][r] * inv);
        }
        if (li == 0) {
            stats[2 * ((long)bh * 1024 + q_abs)]     = CMAX;
            stats[2 * ((long)bh * 1024 + q_abs) + 1] = acc_l[r];
        }
    }
}

// ---------------------------------------------------------------------------
// Banded rel-v finish: out[bh,t,d] += sum_j p_j * erv[j][d].
// ---------------------------------------------------------------------------
__global__ __launch_bounds__(256)
void band_finish(const bf16_t* __restrict__ qk, const float* __restrict__ R,
                 const float* __restrict__ stats, const float* __restrict__ erv_l,
                 const float* __restrict__ kb, bf16_t* __restrict__ out)
{
    int gw = blockIdx.x * 4 + (threadIdx.x >> 6);   // bh*1024 + t
    int bh = gw >> 10, t = gw & 1023;
    int b = bh >> 3, h = bh & 7;
    int lane = threadIdx.x & 63;
    const long nb = (long)b * 1024;
    float qv = (float)qk[(nb + t) * 1024 + h * 64 + lane];
    float p[9];
    #pragma unroll
    for (int j = 0; j < 9; ++j) {
        int s = t + j - 4;
        float dot = 0.f;
        if ((unsigned)s < 1024u)
            dot = qv * (float)qk[(nb + s) * 1024 + 512 + h * 64 + lane];
        p[j] = dot;
    }
    #pragma unroll
    for (int o = 1; o < 64; o <<= 1)
        #pragma unroll
        for (int j = 0; j < 9; ++j) p[j] += __shfl_xor(p[j], o);
    float m = stats[2 * (long)gw], invl = 1.f / stats[2 * (long)gw + 1];
    #pragma unroll
    for (int j = 0; j < 9; ++j) {
        int s = t + j - 4;
        if ((unsigned)s < 1024u) {
            float sc = p[j] + R[(long)gw * 9 + j] + kb[b * 1024 + s];
            p[j] = __expf(sc - m) * invl;
        } else p[j] = 0.f;
    }
    long oidx = (nb + t) * 512 + h * 64 + lane;
    float v = (float)out[oidx];
    #pragma unroll
    for (int j = 0; j < 9; ++j) v += p[j] * erv_l[j * 64 + lane];
    out[oidx] = (bf16_t)v;
}

// ---------------------------------------------------------------------------
// Residual + LayerNorm over C=512 (wave per row n).
// ---------------------------------------------------------------------------
template<int MASKOUT>
__global__ __launch_bounds__(256)
void ln_residual(float* __restrict__ xres, const bf16_t* __restrict__ y,
                 bf16_t* __restrict__ xbf, const float* __restrict__ g,
                 const float* __restrict__ bvec, const float* __restrict__ mask)
{
    int gw = blockIdx.x * 4 + (threadIdx.x >> 6);
    int lane = threadIdx.x & 63;
    long base = (long)gw * 512 + lane * 8;
    f32x4 x0 = *(const f32x4*)(xres + base);
    f32x4 x1 = *(const f32x4*)(xres + base + 4);
    bf16x8 yv = *(const bf16x8*)(y + base);
    float s[8];
    #pragma unroll
    for (int e = 0; e < 4; ++e) { s[e] = x0[e] + (float)yv[e]; s[4 + e] = x1[e] + (float)yv[4 + e]; }
    float sum = 0.f, sq = 0.f;
    #pragma unroll
    for (int e = 0; e < 8; ++e) { sum += s[e]; sq += s[e] * s[e]; }
    #pragma unroll
    for (int o = 1; o < 64; o <<= 1) { sum += __shfl_xor(sum, o); sq += __shfl_xor(sq, o); }
    float mean = sum * (1.f / 512.f);
    float var  = sq * (1.f / 512.f) - mean * mean;
    float rstd = rsqrtf(var + 1e-5f);
    f32x4 g0 = *(const f32x4*)(g + lane * 8);
    f32x4 g1 = *(const f32x4*)(g + lane * 8 + 4);
    f32x4 b0 = *(const f32x4*)(bvec + lane * 8);
    f32x4 b1 = *(const f32x4*)(bvec + lane * 8 + 4);
    float mk = MASKOUT ? mask[gw] : 1.f;
    f32x4 o0, o1; bf16x8 ob;
    #pragma unroll
    for (int e = 0; e < 4; ++e) {
        float v0 = (s[e] - mean) * rstd * g0[e] + b0[e];
        float v1 = (s[4 + e] - mean) * rstd * g1[e] + b1[e];
        o0[e] = v0; o1[e] = v1;
        ob[e] = (bf16_t)(v0 * mk); ob[4 + e] = (bf16_t)(v1 * mk);
    }
    *(f32x4*)(xres + base) = o0;
    *(f32x4*)(xres + base + 4) = o1;
    *(bf16x8*)(xbf + base) = ob;
}

// ---------------------------------------------------------------------------
// Sum of 3 conv2 tap-partials + bias, mask, residual + LayerNorm (ln2).
// ---------------------------------------------------------------------------
__global__ __launch_bounds__(256)
void ln_residual_p3(float* __restrict__ xres, const bf16_t* __restrict__ part,
                    bf16_t* __restrict__ xbf, const float* __restrict__ g,
                    const float* __restrict__ bvec, const float* __restrict__ bias,
                    const float* __restrict__ mask)
{
    int gw = blockIdx.x * 4 + (threadIdx.x >> 6);
    int lane = threadIdx.x & 63;
    long base = (long)gw * 512 + lane * 8;
    bf16x8 pa = *(const bf16x8*)(part + base);
    bf16x8 pbv = *(const bf16x8*)(part + base + (1l << 22));
    bf16x8 pc = *(const bf16x8*)(part + base + (2l << 22));
    f32x4 x0 = *(const f32x4*)(xres + base);
    f32x4 x1 = *(const f32x4*)(xres + base + 4);
    f32x4 bi0 = *(const f32x4*)(bias + lane * 8);
    f32x4 bi1 = *(const f32x4*)(bias + lane * 8 + 4);
    float mk = mask[gw];
    float s[8];
    #pragma unroll
    for (int e = 0; e < 4; ++e) {
        float y0 = ((float)pa[e] + (float)pbv[e] + (float)pc[e] + bi0[e]) * mk;
        float y1 = ((float)pa[4 + e] + (float)pbv[4 + e] + (float)pc[4 + e] + bi1[e]) * mk;
        s[e] = x0[e] + y0; s[4 + e] = x1[e] + y1;
    }
    float sum = 0.f, sq = 0.f;
    #pragma unroll
    for (int e = 0; e < 8; ++e) { sum += s[e]; sq += s[e] * s[e]; }
    #pragma unroll
    for (int o = 1; o < 64; o <<= 1) { sum += __shfl_xor(sum, o); sq += __shfl_xor(sq, o); }
    float mean = sum * (1.f / 512.f);
    float var  = sq * (1.f / 512.f) - mean * mean;
    float rstd = rsqrtf(var + 1e-5f);
    f32x4 g0 = *(const f32x4*)(g + lane * 8);
    f32x4 g1 = *(const f32x4*)(g + lane * 8 + 4);
    f32x4 b0 = *(const f32x4*)(bvec + lane * 8);
    f32x4 b1 = *(const f32x4*)(bvec + lane * 8 + 4);
    f32x4 o0, o1; bf16x8 ob;
    #pragma unroll
    for (int e = 0; e < 4; ++e) {
        float v0 = (s[e] - mean) * rstd * g0[e] + b0[e];
        float v1 = (s[4 + e] - mean) * rstd * g1[e] + b1[e];
        o0[e] = v0; o1[e] = v1;
        ob[e] = (bf16_t)v0; ob[4 + e] = (bf16_t)v1;
    }
    *(f32x4*)(xres + base) = o0;
    *(f32x4*)(xres + base + 4) = o1;
    *(bf16x8*)(xbf + base) = ob;
}

// ---------------------------------------------------------------------------
// Transposes: x[B,C,T] <-> act[B*T, C]
// ---------------------------------------------------------------------------
__global__ __launch_bounds__(256)
void transpose_in_k(const float* __restrict__ x, const float* __restrict__ mask,
                    float* __restrict__ xres, bf16_t* __restrict__ xbf)
{
    __shared__ float tile[32][33];
    int b = blockIdx.z, c0 = blockIdx.y * 32, t0 = blockIdx.x * 32;
    int tx = threadIdx.x & 31, ty = threadIdx.x >> 5;
    #pragma unroll
    for (int r = 0; r < 4; ++r) {
        int cl = ty + r * 8;
        tile[cl][tx] = x[((long)b * 512 + c0 + cl) * 1024 + t0 + tx];
    }
    __syncthreads();
    #pragma unroll
    for (int r = 0; r < 4; ++r) {
        int tl = ty + r * 8;
        int n = b * 1024 + t0 + tl;
        float v = tile[tx][tl] * mask[n];
        xres[(long)n * 512 + c0 + tx] = v;
        xbf[(long)n * 512 + c0 + tx] = (bf16_t)v;
    }
}

__global__ __launch_bounds__(256)
void transpose_out_k(const float* __restrict__ xres, const float* __restrict__ mask,
                     float* __restrict__ out)
{
    __shared__ float tile[32][33];
    int b = blockIdx.z, c0 = blockIdx.y * 32, t0 = blockIdx.x * 32;
    int tx = threadIdx.x & 31, ty = threadIdx.x >> 5;
    #pragma unroll
    for (int r = 0; r < 4; ++r) {
        int tl = ty + r * 8;
        int n = b * 1024 + t0 + tl;
        tile[tl][tx] = xres[(long)n * 512 + c0 + tx] * mask[n];
    }
    __syncthreads();
    #pragma unroll
    for (int r = 0; r < 4; ++r) {
        int cl = ty + r * 8;
        out[((long)b * 512 + c0 + cl) * 1024 + t0 + tx] = tile[tx][cl];
    }
}

// ---------------------------------------------------------------------------
// Per-layer weight packing (fp32 -> bf16, q-scale fold, conv k-major repack)
// ---------------------------------------------------------------------------
__global__ __launch_bounds__(256)
void pack_attn_w(const float* __restrict__ w, bf16_t* __restrict__ Wqk,
                 bf16_t* __restrict__ Wv, bf16_t* __restrict__ Wo)
{
    int idx = blockIdx.x * 256 + threadIdx.x;      // < 4*512*512
    if (idx >= 4 * 512 * 512) return;
    int c = idx & 511;
    int o = (idx >> 9) & 511;
    int which = idx >> 18;
    float v = w[idx];
    if (which == 0) v *= 0.125f;
    if (which <= 1)      Wqk[(which * 512 + o) * 512 + c] = (bf16_t)v;
    else if (which == 2) Wv[o * 512 + c] = (bf16_t)v;
    else                 Wo[o * 512 + c] = (bf16_t)v;
}

__global__ __launch_bounds__(256)
void pack_attn_b(const float* __restrict__ bsrc, float* __restrict__ bqk)
{
    int idx = blockIdx.x * 256 + threadIdx.x;
    if (idx >= 6 * 2 * 512) return;     // only q,k need packing (q scaled)
    int c = idx & 511, which = (idx >> 9) & 1, i = idx >> 10;
    float v = bsrc[(i * 4 + which) * 512 + c];
    if (which == 0) v *= 0.125f;
    bqk[i * 1024 + which * 512 + c] = v;
}

// ---------------------------------------------------------------------------
// Merged conv weight pack: w1[f][c][k] -> W1p[f][k][c], w2[c][f][k] ->
// W2p[c][k][f].  idx < 2048*1536 handles w1, rest handles w2.
// ---------------------------------------------------------------------------
__global__ __launch_bounds__(256)
void pack_conv_w(const float* __restrict__ w1, const float* __restrict__ w2,
                 bf16_t* __restrict__ W1p, bf16_t* __restrict__ W2p)
{
    int idx = blockIdx.x * 256 + threadIdx.x;      // < 2048*1536 + 512*6144
    if (idx < 2048 * 1536) {
        int c = idx & 511;
        int k = (idx >> 9) % 3;
        int f = idx / 1536;
        W1p[idx] = (bf16_t)w1[(f * 512 + c) * 3 + k];
    } else {
        int j = idx - 2048 * 1536;                 // < 512*6144
        int f = j & 2047;
        int k = (j >> 11) % 3;
        int ci = j / 6144;
        W2p[j] = (bf16_t)w2[ci * 6144 + f * 3 + k];
    }
}

// ---------------------------------------------------------------------------
extern "C" void kernel_launch(void* const* d_in, const int* in_sizes, int n_in,
                              void* d_out, int out_size, void* d_ws, size_t ws_size,
                              hipStream_t stream)
{
    const float* x      = (const float*)d_in[0];
    const float* xmask  = (const float*)d_in[1];
    const float* attn_w = (const float*)d_in[2];
    const float* attn_b = (const float*)d_in[3];
    const float* erk    = (const float*)d_in[4];
    const float* erv    = (const float*)d_in[5];
    const float* ln1g   = (const float*)d_in[6];
    const float* ln1b   = (const float*)d_in[7];
    const float* w1     = (const float*)d_in[8];
    const float* b1in   = (const float*)d_in[9];
    const float* w2     = (const float*)d_in[10];
    const float* b2in   = (const float*)d_in[11];
    const float* ln2g   = (const float*)d_in[12];
    const float* ln2b   = (const float*)d_in[13];
    float* out = (float*)d_out;

    char* p = (char*)d_ws;
    auto alloc = [&](size_t bytes) {
        char* r = p;
        p += (bytes + 255) & ~(size_t)255;
        return r;
    };
    // total ws usage ~110 MB (r9 layout)
    bf16_t* zpage = (bf16_t*)alloc(1024);
    bf16_t* Wqk_l = (bf16_t*)alloc(1024l * 512 * 2);
    bf16_t* Wv_l  = (bf16_t*)alloc(512l * 512 * 2);
    bf16_t* Wo_l  = (bf16_t*)alloc(512l * 512 * 2);
    bf16_t* W1p_l = (bf16_t*)alloc(2048l * 1536 * 2);
    bf16_t* W2p_l = (bf16_t*)alloc(512l * 6144 * 2);
    float*  bqk   = (float*)alloc(6l * 1024 * 4);
    float*  xres  = (float*)alloc(8192l * 512 * 4);
    bf16_t* xbf   = (bf16_t*)alloc(8192l * 512 * 2);
    bf16_t* big   = (bf16_t*)alloc(8192l * 2048 * 2);   // qk|vt|attn_out, aliased by hbuf
    bf16_t* ybuf  = (bf16_t*)alloc(8192l * 512 * 2);
    bf16_t* part  = (bf16_t*)alloc(3l * 8192 * 512 * 2); // conv2 tap partials
    float*  R     = (float*)alloc(64l * 1024 * 9 * 4);
    float*  stats = (float*)alloc(64l * 1024 * 2 * 4);   // (m, l) per row
    float*  kb    = (float*)alloc(8192l * 4);            // key-side mask bias
    (void)in_sizes; (void)n_in; (void)out_size; (void)ws_size;

    bf16_t* qk       = big;                    // [8192][1024]
    bf16_t* vt       = big + 8192l * 1024;     // [512][8192]
    bf16_t* attn_out = vt + 512l * 8192;       // [8192][512]
    bf16_t* hbuf     = big;                    // [8192][2048], aliases all three

    hipMemsetAsync(zpage, 0, 1024, stream);
    pack_attn_b<<<24, 256, 0, stream>>>(attn_b, bqk);
    mask_bias<<<32, 256, 0, stream>>>(xmask, kb);
    transpose_in_k<<<dim3(32, 16, 8), 256, 0, stream>>>(x, xmask, xres, xbf);

    for (int i = 0; i < 6; ++i) {
        pack_attn_w<<<4096, 256, 0, stream>>>(attn_w + (long)i * 4 * 512 * 512,
                                              Wqk_l, Wv_l, Wo_l);
        pack_conv_w<<<24576, 256, 0, stream>>>(w1 + (long)i * 2048 * 512 * 3,
                                               w2 + (long)i * 512 * 2048 * 3,
                                               W1p_l, W2p_l);

        // QK projection (q pre-scaled) -- BM=64: 1024 blocks, 4/CU
        gemm_nt<64, 128, 0, 0, 1, 0, 0><<<dim3(64, 16, 1), 256, 0, stream>>>(
            Wqk_l, xbf, qk, bqk + i * 1024, nullptr, zpage,
            512, 512, 512, 1024, 0, 0, 0, 0, 0, 0, 0);
        // V projection -> channel-major vt[c][n] -- BN=64: 1024 blocks
        gemm_nt<64, 64, 1, 0, 1, 0, 0><<<dim3(128, 8, 1), 256, 0, stream>>>(
            Wv_l, xbf, vt, attn_b + (i * 4 + 2) * 512, nullptr, zpage,
            512, 512, 512, 8192, 0, 0, 0, 0, 0, 0, 0);
        // R table via MFMA (1024 blocks, no shuffles)
        rel_qk_mfma<<<dim3(64, 16), 256, 0, stream>>>(qk, erk + i * 576, R);
        // fused flash attention (static-max softmax, shuffle-free)
        flash_attn<<<dim3(64, 16), 256, 0, stream>>>(qk, vt, R, kb,
                                                     attn_out, stats);
        // banded rel-v finish (reconstruct band P from stats)
        band_finish<<<16384, 256, 0, stream>>>(qk, R, stats, erv + i * 576,
                                               kb, attn_out);
        // O projection -- BN=64: 1024 blocks
        gemm_nt<64, 64, 0, 0, 1, 0, 0><<<dim3(128, 8, 1), 256, 0, stream>>>(
            Wo_l, attn_out, ybuf, attn_b + (i * 4 + 3) * 512, nullptr, zpage,
            512, 512, 512, 512, 0, 0, 0, 0, 0, 0, 0);
        // LN1 (xbf masked for conv1 input)
        ln_residual<1><<<2048, 256, 0, stream>>>(xres, ybuf, xbf,
                                                 ln1g + i * 512, ln1b + i * 512, xmask);
        // conv1 (K=3*512) + bias + relu + mask  -- BM=64: 2048 blocks, 8/CU
        gemm_nt<64, 128, 0, 1, 1, 1, 1><<<dim3(64, 32, 1), 256, 0, stream>>>(
            W1p_l, xbf, hbuf, b1in + i * 2048, xmask, zpage,
            1536, 1536, 512, 2048, 512, 0, 0, 0, 0, 0, 0);
        // conv2 split-K by tap: partials [3][8192][512] bf16 (1536 blocks)
        gemm_nt<64, 128, 0, 2, 0, 0, 0><<<dim3(64, 8, 3), 256, 0, stream>>>(
            W2p_l, hbuf, part, nullptr, nullptr, zpage,
            2048, 6144, 2048, 512, 2048, 0, 0, 0, 0, 0, 0);
        // LN2 fused with partial reduce + bias + mask
        ln_residual_p3<<<2048, 256, 0, stream>>>(xres, part, xbf,
                                                 ln2g + i * 512, ln2b + i * 512,
                                                 b2in + i * 512, xmask);
    }

    transpose_out_k<<<dim3(32, 16, 8), 256, 0, stream>>>(xres, xmask, out);
}

// Round 17
// 2428.875 us; speedup vs baseline: 1.5181x; 1.0774x over previous
//
#include <hip/hip_runtime.h>

typedef __bf16 bf16_t;
typedef __bf16 bf16x8 __attribute__((ext_vector_type(8)));
typedef __bf16 bf16x4 __attribute__((ext_vector_type(4)));
typedef float  f32x4  __attribute__((ext_vector_type(4)));

#define AS1 __attribute__((address_space(1)))
#define AS3 __attribute__((address_space(3)))

#define CMAX 16.0f   // static softmax max bound (true scores |s| ~ 1)

// ---------------------------------------------------------------------------
// Unified NT GEMM:  D[m][n] = sum_k A[m][k] * Bt[n][k]   (both K-contiguous)
// OUTMN=0: store C[n][m] (activation layout), OUTMN=1: store C[m][n].
// CONV=1: K = 3*CIN fused tap loop. CONV=2: split-K, blockIdx.z = tap,
//         K = CIN, writes bf16 partial at C + (tap<<22) + n*512 + m.
// ---------------------------------------------------------------------------
template<int BM, int BN, int OUTMN, int CONV, int BIAS, int RELU, int MASK>
__global__ __launch_bounds__(256)
void gemm_nt(const bf16_t* __restrict__ A, const bf16_t* __restrict__ B,
             bf16_t* __restrict__ C, const float* __restrict__ bias,
             const float* __restrict__ mask, const bf16_t* __restrict__ zpage,
             int K, int lda, int ldb, int ldc, int CIN,
             long sAb, long sAh, long sBb, long sBh, long sCb, long sCh)
{
    constexpr int BK = 32;
    __shared__ bf16_t As[BM * BK];
    __shared__ bf16_t Bs[BN * BK];
    const int z = blockIdx.z;
    int tap0 = 0;
    if constexpr (CONV == 2) {
        tap0 = z;
        A += (long)tap0 * CIN;             // tap's K-slice of the weight
    } else {
        A += (long)(z >> 3) * sAb + (long)(z & 7) * sAh;
        B += (long)(z >> 3) * sBb + (long)(z & 7) * sBh;
        C += (long)(z >> 3) * sCb + (long)(z & 7) * sCh;
    }
    const int m0 = blockIdx.y * BM;
    const int n0 = blockIdx.x * BN;
    const int tid = threadIdx.x;
    const int wid = tid >> 6, lane = tid & 63;
    constexpr int WM = BM / 2, WN = BN / 2;
    constexpr int FM = WM / 16, FN = WN / 16;
    const int wm = wid >> 1, wn = wid & 1;

    f32x4 acc[FM][FN] = {};

    constexpr int ACH = BM / 64;   // A chunks (16 rows = 1KB) per wave
    constexpr int BCH = BN / 64;
    const int rquad = lane >> 2;          // row within 16-row chunk
    const int koff  = (lane & 3) * 8;     // element offset along K

    int tap = 0, cc0 = 0;
    for (int k0 = 0; k0 < K; k0 += BK) {
        #pragma unroll
        for (int q = 0; q < ACH; ++q) {
            int ch  = wid * ACH + q;
            int row = ch * 16 + rquad;
            const bf16_t* src = A + (long)(m0 + row) * lda + (k0 + koff);
            __builtin_amdgcn_global_load_lds((const AS1 void*)src,
                                             (AS3 void*)(As + ch * 512), 16, 0, 0);
        }
        #pragma unroll
        for (int q = 0; q < BCH; ++q) {
            int ch  = wid * BCH + q;
            int row = ch * 16 + rquad;
            const bf16_t* src;
            if constexpr (CONV == 1) {
                int tl = (n0 & 1023) + row + tap - 1;
                src = ((unsigned)tl < 1024u)
                    ? B + (long)(n0 + row + tap - 1) * ldb + (cc0 + koff)
                    : zpage + koff;
            } else if constexpr (CONV == 2) {
                int tl = (n0 & 1023) + row + tap0 - 1;
                src = ((unsigned)tl < 1024u)
                    ? B + (long)(n0 + row + tap0 - 1) * ldb + (k0 + koff)
                    : zpage + koff;
            } else {
                src = B + (long)(n0 + row) * ldb + (k0 + koff);
            }
            __builtin_amdgcn_global_load_lds((const AS1 void*)src,
                                             (AS3 void*)(Bs + ch * 512), 16, 0, 0);
        }
        if constexpr (CONV == 1) { cc0 += BK; if (cc0 == CIN) { cc0 = 0; ++tap; } }
        __syncthreads();

        const bf16_t* Ab = As + (wm * WM + (lane & 15)) * BK + ((lane >> 4) * 8);
        const bf16_t* Bb = Bs + (wn * WN + (lane & 15)) * BK + ((lane >> 4) * 8);
        bf16x8 af[FM], bv[FN];
        #pragma unroll
        for (int i = 0; i < FM; ++i) af[i] = *(const bf16x8*)(Ab + i * 16 * BK);
        #pragma unroll
        for (int j = 0; j < FN; ++j) bv[j] = *(const bf16x8*)(Bb + j * 16 * BK);
        #pragma unroll
        for (int i = 0; i < FM; ++i)
            #pragma unroll
            for (int j = 0; j < FN; ++j)
                acc[i][j] = __builtin_amdgcn_mfma_f32_16x16x32_bf16(af[i], bv[j], acc[i][j], 0, 0, 0);
        __syncthreads();
    }

    const int mw = m0 + wm * WM, nw = n0 + wn * WN;
    #pragma unroll
    for (int i = 0; i < FM; ++i) {
        const int mb = mw + i * 16 + (lane >> 4) * 4;
        f32x4 bvv = {};
        if constexpr (BIAS) bvv = *(const f32x4*)(bias + mb);
        #pragma unroll
        for (int j = 0; j < FN; ++j) {
            const int nn = nw + j * 16 + (lane & 15);
            f32x4 v = acc[i][j];
            if constexpr (BIAS) v += bvv;
            if constexpr (RELU) {
                #pragma unroll
                for (int r = 0; r < 4; ++r) v[r] = fmaxf(v[r], 0.f);
            }
            if constexpr (MASK) v *= mask[nn];
            bf16x4 o;
            #pragma unroll
            for (int r = 0; r < 4; ++r) o[r] = (bf16_t)v[r];
            if constexpr (CONV == 2) {
                *(bf16x4*)(C + ((long)tap0 << 22) + (long)nn * 512 + mb) = o;
            } else if constexpr (OUTMN) {
                #pragma unroll
                for (int r = 0; r < 4; ++r) C[(long)(mb + r) * ldc + nn] = (bf16_t)v[r];
            } else {
                *(bf16x4*)(C + (long)nn * ldc + mb) = o;
            }
        }
    }
}

// ---------------------------------------------------------------------------
// R[bh,t,j] = sum_d q_scaled[t][h*64+d] * erk[j][d] via MFMA (16x16x32).
// Grid (64 bh, 16 t-tiles), 4 waves; wave computes a 16t x 16j tile (9 j
// valid).
// ---------------------------------------------------------------------------
__global__ __launch_bounds__(256)
void rel_qk_mfma(const bf16_t* __restrict__ qk, const float* __restrict__ erk_l,
                 float* __restrict__ R)
{
    const int w = threadIdx.x >> 6, lane = threadIdx.x & 63;
    const int hi = lane >> 4, li = lane & 15;
    const int bh = blockIdx.x, b = bh >> 3, h = bh & 7;
    const int t0 = blockIdx.y * 64 + w * 16;
    const long nb = (long)b * 1024;

    const bf16_t* qrow = qk + (nb + t0 + li) * 1024 + h * 64 + hi * 8;
    bf16x8 aq0 = *(const bf16x8*)(qrow);
    bf16x8 aq1 = *(const bf16x8*)(qrow + 32);

    bf16x8 be0, be1;
    #pragma unroll
    for (int e = 0; e < 8; ++e) {
        float v0 = (li < 9) ? erk_l[li * 64 + hi * 8 + e] : 0.f;
        float v1 = (li < 9) ? erk_l[li * 64 + 32 + hi * 8 + e] : 0.f;
        be0[e] = (bf16_t)v0; be1[e] = (bf16_t)v1;
    }
    f32x4 acc = {};
    acc = __builtin_amdgcn_mfma_f32_16x16x32_bf16(aq0, be0, acc, 0, 0, 0);
    acc = __builtin_amdgcn_mfma_f32_16x16x32_bf16(aq1, be1, acc, 0, 0, 0);
    if (li < 9) {
        #pragma unroll
        for (int r = 0; r < 4; ++r) {
            int t = t0 + hi * 4 + r;
            R[((long)bh * 1024 + t) * 9 + li] = acc[r];
        }
    }
}

// ---------------------------------------------------------------------------
// kb[n] = -1e4 if mask[n]==0 else 0   (additive key-side mask bias)
// ---------------------------------------------------------------------------
__global__ __launch_bounds__(256)
void mask_bias(const float* __restrict__ mask, float* __restrict__ kb)
{
    int i = blockIdx.x * 256 + threadIdx.x;
    if (i < 8192) kb[i] = (mask[i] == 0.f) ? -1e4f : 0.f;
}

// ---------------------------------------------------------------------------
// Fused flash attention with static-max softmax (p = exp(s - CMAX)), row-sum
// via ones-MFMA. Grid (64 bh, 16 qtiles), 4 waves, wave owns 16 q-rows.
// NEW: in the "near" sub-tiles, stores the 9 band P values per row to pband
// (one 4B scattered store per (row, jb) across the whole s-loop -- no
// loop-carried state, so no r13 spill hazard). band_apply consumes them.
// ---------------------------------------------------------------------------
__global__ __launch_bounds__(256)
void flash_attn(const bf16_t* __restrict__ qk, const bf16_t* __restrict__ vt,
                const float* __restrict__ R, const float* __restrict__ kb,
                bf16_t* __restrict__ out, float* __restrict__ lsum,
                float* __restrict__ pband)
{
    __shared__ bf16_t P_lds[4 * 1024];             // 2KB per wave
    const int w = threadIdx.x >> 6, lane = threadIdx.x & 63;
    const int hi = lane >> 4, li = lane & 15;
    const int bh = blockIdx.x, b = bh >> 3, h = bh & 7;
    const int q0 = blockIdx.y * 64 + w * 16;
    const long nbase = (long)b * 1024;
    char* pw = (char*)(P_lds + w * 1024);

    const bf16_t* qrow = qk + (nbase + q0 + li) * 1024 + h * 64 + hi * 8;
    bf16x8 aq0 = *(const bf16x8*)(qrow);
    bf16x8 aq1 = *(const bf16x8*)(qrow + 32);

    bf16x8 ones;
    #pragma unroll
    for (int e = 0; e < 8; ++e) ones[e] = (bf16_t)1.0f;

    f32x4 acc_o[4] = {};
    f32x4 acc_l = {};

    const bf16_t* kbase = qk + nbase * 1024 + 512 + h * 64 + hi * 8;
    const bf16_t* vbase = vt + (long)(h * 64 + li) * 8192 + nbase + hi * 8;
    const float* kbp = kb + b * 1024;

    bf16x8 kc[4][2], vv[4][2];
    #pragma unroll
    for (int j = 0; j < 4; ++j) {
        const bf16_t* kr = kbase + (long)(j * 16 + li) * 1024;
        kc[j][0] = *(const bf16x8*)kr;
        kc[j][1] = *(const bf16x8*)(kr + 32);
    }

    for (int it = 0; it < 16; ++it) {
        const int s0 = it * 64;
        #pragma unroll
        for (int j2 = 0; j2 < 4; ++j2) {
            const bf16_t* vr = vbase + (long)(j2 * 16) * 8192 + s0;
            vv[j2][0] = *(const bf16x8*)vr;
            vv[j2][1] = *(const bf16x8*)(vr + 32);
        }
        float kbv[4];
        #pragma unroll
        for (int j = 0; j < 4; ++j) kbv[j] = kbp[s0 + j * 16 + li];
        f32x4 sc[4];
        __builtin_amdgcn_s_setprio(1);
        #pragma unroll
        for (int j = 0; j < 4; ++j) {
            f32x4 a = {};
            a = __builtin_amdgcn_mfma_f32_16x16x32_bf16(aq0, kc[j][0], a, 0, 0, 0);
            a = __builtin_amdgcn_mfma_f32_16x16x32_bf16(aq1, kc[j][1], a, 0, 0, 0);
            sc[j] = a;
        }
        __builtin_amdgcn_s_setprio(0);
        const int s1 = (s0 + 64) & 1023;
        #pragma unroll
        for (int j = 0; j < 4; ++j) {
            const bf16_t* kr = kbase + (long)(s1 + j * 16 + li) * 1024;
            kc[j][0] = *(const bf16x8*)kr;
            kc[j][1] = *(const bf16x8*)(kr + 32);
        }
        #pragma unroll
        for (int j = 0; j < 4; ++j) {
            const int sb = s0 + j * 16;
            const bool near = (sb + 15 >= q0 - 4) && (sb <= q0 + 19);
            const int s_abs = sb + li;
            #pragma unroll
            for (int r = 0; r < 4; ++r) {
                const int q_abs = q0 + hi * 4 + r;
                float v = sc[j][r] + kbv[j];
                if (near) {
                    int jb = s_abs - q_abs + 4;
                    if ((unsigned)jb < 9u)
                        v += R[((long)bh * 1024 + q_abs) * 9 + jb];
                }
                float pex = __expf(v - CMAX);
                sc[j][r] = pex;
                if (near) {
                    int jb = s_abs - q_abs + 4;
                    if ((unsigned)jb < 9u)
                        pband[((long)bh * 1024 + q_abs) * 9 + jb] = pex;
                }
            }
        }
        #pragma unroll
        for (int j = 0; j < 4; ++j)
            #pragma unroll
            for (int r = 0; r < 4; ++r) {
                int q = hi * 4 + r;
                int c = (j * 32 + li * 2) ^ ((q & 7) << 4);
                *(bf16_t*)(pw + q * 128 + c) = (bf16_t)sc[j][r];
            }
        asm volatile("s_waitcnt lgkmcnt(0)" ::: "memory");
        __builtin_amdgcn_s_setprio(1);
        #pragma unroll
        for (int half = 0; half < 2; ++half) {
            int cr = (half * 64 + hi * 16) ^ ((li & 7) << 4);
            bf16x8 pa = *(const bf16x8*)(pw + li * 128 + cr);
            #pragma unroll
            for (int j2 = 0; j2 < 4; ++j2)
                acc_o[j2] = __builtin_amdgcn_mfma_f32_16x16x32_bf16(pa, vv[j2][half], acc_o[j2], 0, 0, 0);
            acc_l = __builtin_amdgcn_mfma_f32_16x16x32_bf16(pa, ones, acc_l, 0, 0, 0);
        }
        __builtin_amdgcn_s_setprio(0);
    }

    #pragma unroll
    for (int r = 0; r < 4; ++r) {
        const float inv = 1.f / acc_l[r];
        const int q_abs = q0 + hi * 4 + r;
        #pragma unroll
        for (int j2 = 0; j2 < 4; ++j2) {
            const int d = j2 * 16 + li;
            out[(nbase + q_abs) * 512 + h * 64 + d] = (bf16_t)(acc_o[j2][r] * inv);
        }
        if (li == 0) lsum[(long)bh * 1024 + q_abs] = acc_l[r];
    }
}

// ---------------------------------------------------------------------------
// Band apply: out[bh,t,d] += (sum_j pband[t][j] * erv[j][d]) / l.
// Wave per (bh,t), lane = d. No qk re-reads, no shuffles (r16's band_finish
// recomputed 9 dots + 54-shuffle reduce per row).
// ---------------------------------------------------------------------------
__global__ __launch_bounds__(256)
void band_apply(const float* __restrict__ pband, const float* __restrict__ lsum,
                const float* __restrict__ erv_l, bf16_t* __restrict__ out)
{
    int gw = blockIdx.x * 4 + (threadIdx.x >> 6);   // bh*1024 + t
    int bh = gw >> 10, t = gw & 1023;
    int b = bh >> 3, h = bh & 7;
    int lane = threadIdx.x & 63;
    float invl = 1.f / lsum[gw];
    const float* pb = pband + (long)gw * 9;
    float acc = 0.f;
    #pragma unroll
    for (int j = 0; j < 9; ++j) {
        int s = t + j - 4;
        if ((unsigned)s < 1024u)            // unwritten slots never read
            acc += pb[j] * erv_l[j * 64 + lane];
    }
    long oidx = ((long)b * 1024 + t) * 512 + h * 64 + lane;
    out[oidx] = (bf16_t)((float)out[oidx] + acc * invl);
}

// ---------------------------------------------------------------------------
// Residual + LayerNorm over C=512 (wave per row n).
// ---------------------------------------------------------------------------
template<int MASKOUT>
__global__ __launch_bounds__(256)
void ln_residual(float* __restrict__ xres, const bf16_t* __restrict__ y,
                 bf16_t* __restrict__ xbf, const float* __restrict__ g,
                 const float* __restrict__ bvec, const float* __restrict__ mask)
{
    int gw = blockIdx.x * 4 + (threadIdx.x >> 6);
    int lane = threadIdx.x & 63;
    long base = (long)gw * 512 + lane * 8;
    f32x4 x0 = *(const f32x4*)(xres + base);
    f32x4 x1 = *(const f32x4*)(xres + base + 4);
    bf16x8 yv = *(const bf16x8*)(y + base);
    float s[8];
    #pragma unroll
    for (int e = 0; e < 4; ++e) { s[e] = x0[e] + (float)yv[e]; s[4 + e] = x1[e] + (float)yv[4 + e]; }
    float sum = 0.f, sq = 0.f;
    #pragma unroll
    for (int e = 0; e < 8; ++e) { sum += s[e]; sq += s[e] * s[e]; }
    #pragma unroll
    for (int o = 1; o < 64; o <<= 1) { sum += __shfl_xor(sum, o); sq += __shfl_xor(sq, o); }
    float mean = sum * (1.f / 512.f);
    float var  = sq * (1.f / 512.f) - mean * mean;
    float rstd = rsqrtf(var + 1e-5f);
    f32x4 g0 = *(const f32x4*)(g + lane * 8);
    f32x4 g1 = *(const f32x4*)(g + lane * 8 + 4);
    f32x4 b0 = *(const f32x4*)(bvec + lane * 8);
    f32x4 b1 = *(const f32x4*)(bvec + lane * 8 + 4);
    float mk = MASKOUT ? mask[gw] : 1.f;
    f32x4 o0, o1; bf16x8 ob;
    #pragma unroll
    for (int e = 0; e < 4; ++e) {
        float v0 = (s[e] - mean) * rstd * g0[e] + b0[e];
        float v1 = (s[4 + e] - mean) * rstd * g1[e] + b1[e];
        o0[e] = v0; o1[e] = v1;
        ob[e] = (bf16_t)(v0 * mk); ob[4 + e] = (bf16_t)(v1 * mk);
    }
    *(f32x4*)(xres + base) = o0;
    *(f32x4*)(xres + base + 4) = o1;
    *(bf16x8*)(xbf + base) = ob;
}

// ---------------------------------------------------------------------------
// Sum of 3 conv2 tap-partials + bias, mask, residual + LayerNorm (ln2).
// ---------------------------------------------------------------------------
__global__ __launch_bounds__(256)
void ln_residual_p3(float* __restrict__ xres, const bf16_t* __restrict__ part,
                    bf16_t* __restrict__ xbf, const float* __restrict__ g,
                    const float* __restrict__ bvec, const float* __restrict__ bias,
                    const float* __restrict__ mask)
{
    int gw = blockIdx.x * 4 + (threadIdx.x >> 6);
    int lane = threadIdx.x & 63;
    long base = (long)gw * 512 + lane * 8;
    bf16x8 pa = *(const bf16x8*)(part + base);
    bf16x8 pbv = *(const bf16x8*)(part + base + (1l << 22));
    bf16x8 pc = *(const bf16x8*)(part + base + (2l << 22));
    f32x4 x0 = *(const f32x4*)(xres + base);
    f32x4 x1 = *(const f32x4*)(xres + base + 4);
    f32x4 bi0 = *(const f32x4*)(bias + lane * 8);
    f32x4 bi1 = *(const f32x4*)(bias + lane * 8 + 4);
    float mk = mask[gw];
    float s[8];
    #pragma unroll
    for (int e = 0; e < 4; ++e) {
        float y0 = ((float)pa[e] + (float)pbv[e] + (float)pc[e] + bi0[e]) * mk;
        float y1 = ((float)pa[4 + e] + (float)pbv[4 + e] + (float)pc[4 + e] + bi1[e]) * mk;
        s[e] = x0[e] + y0; s[4 + e] = x1[e] + y1;
    }
    float sum = 0.f, sq = 0.f;
    #pragma unroll
    for (int e = 0; e < 8; ++e) { sum += s[e]; sq += s[e] * s[e]; }
    #pragma unroll
    for (int o = 1; o < 64; o <<= 1) { sum += __shfl_xor(sum, o); sq += __shfl_xor(sq, o); }
    float mean = sum * (1.f / 512.f);
    float var  = sq * (1.f / 512.f) - mean * mean;
    float rstd = rsqrtf(var + 1e-5f);
    f32x4 g0 = *(const f32x4*)(g + lane * 8);
    f32x4 g1 = *(const f32x4*)(g + lane * 8 + 4);
    f32x4 b0 = *(const f32x4*)(bvec + lane * 8);
    f32x4 b1 = *(const f32x4*)(bvec + lane * 8 + 4);
    f32x4 o0, o1; bf16x8 ob;
    #pragma unroll
    for (int e = 0; e < 4; ++e) {
        float v0 = (s[e] - mean) * rstd * g0[e] + b0[e];
        float v1 = (s[4 + e] - mean) * rstd * g1[e] + b1[e];
        o0[e] = v0; o1[e] = v1;
        ob[e] = (bf16_t)v0; ob[4 + e] = (bf16_t)v1;
    }
    *(f32x4*)(xres + base) = o0;
    *(f32x4*)(xres + base + 4) = o1;
    *(bf16x8*)(xbf + base) = ob;
}

// ---------------------------------------------------------------------------
// Transposes: x[B,C,T] <-> act[B*T, C]
// ---------------------------------------------------------------------------
__global__ __launch_bounds__(256)
void transpose_in_k(const float* __restrict__ x, const float* __restrict__ mask,
                    float* __restrict__ xres, bf16_t* __restrict__ xbf)
{
    __shared__ float tile[32][33];
    int b = blockIdx.z, c0 = blockIdx.y * 32, t0 = blockIdx.x * 32;
    int tx = threadIdx.x & 31, ty = threadIdx.x >> 5;
    #pragma unroll
    for (int r = 0; r < 4; ++r) {
        int cl = ty + r * 8;
        tile[cl][tx] = x[((long)b * 512 + c0 + cl) * 1024 + t0 + tx];
    }
    __syncthreads();
    #pragma unroll
    for (int r = 0; r < 4; ++r) {
        int tl = ty + r * 8;
        int n = b * 1024 + t0 + tl;
        float v = tile[tx][tl] * mask[n];
        xres[(long)n * 512 + c0 + tx] = v;
        xbf[(long)n * 512 + c0 + tx] = (bf16_t)v;
    }
}

__global__ __launch_bounds__(256)
void transpose_out_k(const float* __restrict__ xres, const float* __restrict__ mask,
                     float* __restrict__ out)
{
    __shared__ float tile[32][33];
    int b = blockIdx.z, c0 = blockIdx.y * 32, t0 = blockIdx.x * 32;
    int tx = threadIdx.x & 31, ty = threadIdx.x >> 5;
    #pragma unroll
    for (int r = 0; r < 4; ++r) {
        int tl = ty + r * 8;
        int n = b * 1024 + t0 + tl;
        tile[tl][tx] = xres[(long)n * 512 + c0 + tx] * mask[n];
    }
    __syncthreads();
    #pragma unroll
    for (int r = 0; r < 4; ++r) {
        int cl = ty + r * 8;
        out[((long)b * 512 + c0 + cl) * 1024 + t0 + tx] = tile[tx][cl];
    }
}

// ---------------------------------------------------------------------------
// Per-layer weight packing (fp32 -> bf16, q-scale fold, conv k-major repack)
// ---------------------------------------------------------------------------
__global__ __launch_bounds__(256)
void pack_attn_w(const float* __restrict__ w, bf16_t* __restrict__ Wqk,
                 bf16_t* __restrict__ Wv, bf16_t* __restrict__ Wo)
{
    int idx = blockIdx.x * 256 + threadIdx.x;      // < 4*512*512
    if (idx >= 4 * 512 * 512) return;
    int c = idx & 511;
    int o = (idx >> 9) & 511;
    int which = idx >> 18;
    float v = w[idx];
    if (which == 0) v *= 0.125f;
    if (which <= 1)      Wqk[(which * 512 + o) * 512 + c] = (bf16_t)v;
    else if (which == 2) Wv[o * 512 + c] = (bf16_t)v;
    else                 Wo[o * 512 + c] = (bf16_t)v;
}

__global__ __launch_bounds__(256)
void pack_attn_b(const float* __restrict__ bsrc, float* __restrict__ bqk)
{
    int idx = blockIdx.x * 256 + threadIdx.x;
    if (idx >= 6 * 2 * 512) return;     // only q,k need packing (q scaled)
    int c = idx & 511, which = (idx >> 9) & 1, i = idx >> 10;
    float v = bsrc[(i * 4 + which) * 512 + c];
    if (which == 0) v *= 0.125f;
    bqk[i * 1024 + which * 512 + c] = v;
}

// ---------------------------------------------------------------------------
// Merged conv weight pack: w1[f][c][k] -> W1p[f][k][c], w2[c][f][k] ->
// W2p[c][k][f].
// ---------------------------------------------------------------------------
__global__ __launch_bounds__(256)
void pack_conv_w(const float* __restrict__ w1, const float* __restrict__ w2,
                 bf16_t* __restrict__ W1p, bf16_t* __restrict__ W2p)
{
    int idx = blockIdx.x * 256 + threadIdx.x;      // < 2048*1536 + 512*6144
    if (idx < 2048 * 1536) {
        int c = idx & 511;
        int k = (idx >> 9) % 3;
        int f = idx / 1536;
        W1p[idx] = (bf16_t)w1[(f * 512 + c) * 3 + k];
    } else {
        int j = idx - 2048 * 1536;                 // < 512*6144
        int f = j & 2047;
        int k = (j >> 11) % 3;
        int ci = j / 6144;
        W2p[j] = (bf16_t)w2[ci * 6144 + f * 3 + k];
    }
}

// ---------------------------------------------------------------------------
extern "C" void kernel_launch(void* const* d_in, const int* in_sizes, int n_in,
                              void* d_out, int out_size, void* d_ws, size_t ws_size,
                              hipStream_t stream)
{
    const float* x      = (const float*)d_in[0];
    const float* xmask  = (const float*)d_in[1];
    const float* attn_w = (const float*)d_in[2];
    const float* attn_b = (const float*)d_in[3];
    const float* erk    = (const float*)d_in[4];
    const float* erv    = (const float*)d_in[5];
    const float* ln1g   = (const float*)d_in[6];
    const float* ln1b   = (const float*)d_in[7];
    const float* w1     = (const float*)d_in[8];
    const float* b1in   = (const float*)d_in[9];
    const float* w2     = (const float*)d_in[10];
    const float* b2in   = (const float*)d_in[11];
    const float* ln2g   = (const float*)d_in[12];
    const float* ln2b   = (const float*)d_in[13];
    float* out = (float*)d_out;

    char* p = (char*)d_ws;
    auto alloc = [&](size_t bytes) {
        char* r = p;
        p += (bytes + 255) & ~(size_t)255;
        return r;
    };
    // total ws usage ~112 MB
    bf16_t* zpage = (bf16_t*)alloc(1024);
    bf16_t* Wqk_l = (bf16_t*)alloc(1024l * 512 * 2);
    bf16_t* Wv_l  = (bf16_t*)alloc(512l * 512 * 2);
    bf16_t* Wo_l  = (bf16_t*)alloc(512l * 512 * 2);
    bf16_t* W1p_l = (bf16_t*)alloc(2048l * 1536 * 2);
    bf16_t* W2p_l = (bf16_t*)alloc(512l * 6144 * 2);
    float*  bqk   = (float*)alloc(6l * 1024 * 4);
    float*  xres  = (float*)alloc(8192l * 512 * 4);
    bf16_t* xbf   = (bf16_t*)alloc(8192l * 512 * 2);
    bf16_t* big   = (bf16_t*)alloc(8192l * 2048 * 2);   // qk|vt|attn_out, aliased by hbuf
    bf16_t* ybuf  = (bf16_t*)alloc(8192l * 512 * 2);
    bf16_t* part  = (bf16_t*)alloc(3l * 8192 * 512 * 2); // conv2 tap partials
    float*  R     = (float*)alloc(64l * 1024 * 9 * 4);
    float*  lsum  = (float*)alloc(64l * 1024 * 4);       // row sums
    float*  pband = (float*)alloc(64l * 1024 * 9 * 4);   // band P values
    float*  kb    = (float*)alloc(8192l * 4);            // key-side mask bias
    (void)in_sizes; (void)n_in; (void)out_size; (void)ws_size;

    bf16_t* qk       = big;                    // [8192][1024]
    bf16_t* vt       = big + 8192l * 1024;     // [512][8192]
    bf16_t* attn_out = vt + 512l * 8192;       // [8192][512]
    bf16_t* hbuf     = big;                    // [8192][2048], aliases all three

    hipMemsetAsync(zpage, 0, 1024, stream);
    pack_attn_b<<<24, 256, 0, stream>>>(attn_b, bqk);
    mask_bias<<<32, 256, 0, stream>>>(xmask, kb);
    transpose_in_k<<<dim3(32, 16, 8), 256, 0, stream>>>(x, xmask, xres, xbf);

    for (int i = 0; i < 6; ++i) {
        pack_attn_w<<<4096, 256, 0, stream>>>(attn_w + (long)i * 4 * 512 * 512,
                                              Wqk_l, Wv_l, Wo_l);
        pack_conv_w<<<24576, 256, 0, stream>>>(w1 + (long)i * 2048 * 512 * 3,
                                               w2 + (long)i * 512 * 2048 * 3,
                                               W1p_l, W2p_l);

        // QK projection (q pre-scaled) -- BM=64: 1024 blocks, 4/CU
        gemm_nt<64, 128, 0, 0, 1, 0, 0><<<dim3(64, 16, 1), 256, 0, stream>>>(
            Wqk_l, xbf, qk, bqk + i * 1024, nullptr, zpage,
            512, 512, 512, 1024, 0, 0, 0, 0, 0, 0, 0);
        // V projection -> channel-major vt[c][n] -- BN=64: 1024 blocks
        gemm_nt<64, 64, 1, 0, 1, 0, 0><<<dim3(128, 8, 1), 256, 0, stream>>>(
            Wv_l, xbf, vt, attn_b + (i * 4 + 2) * 512, nullptr, zpage,
            512, 512, 512, 8192, 0, 0, 0, 0, 0, 0, 0);
        // R table via MFMA (1024 blocks, no shuffles)
        rel_qk_mfma<<<dim3(64, 16), 256, 0, stream>>>(qk, erk + i * 576, R);
        // fused flash attention (stores band P + row sums)
        flash_attn<<<dim3(64, 16), 256, 0, stream>>>(qk, vt, R, kb,
                                                     attn_out, lsum, pband);
        // band apply (tiny: 9 FMAs/lane, no recomputation)
        band_apply<<<16384, 256, 0, stream>>>(pband, lsum, erv + i * 576,
                                              attn_out);
        // O projection -- BN=64: 1024 blocks
        gemm_nt<64, 64, 0, 0, 1, 0, 0><<<dim3(128, 8, 1), 256, 0, stream>>>(
            Wo_l, attn_out, ybuf, attn_b + (i * 4 + 3) * 512, nullptr, zpage,
            512, 512, 512, 512, 0, 0, 0, 0, 0, 0, 0);
        // LN1 (xbf masked for conv1 input)
        ln_residual<1><<<2048, 256, 0, stream>>>(xres, ybuf, xbf,
                                                 ln1g + i * 512, ln1b + i * 512, xmask);
        // conv1 (K=3*512) + bias + relu + mask  -- BM=64: 2048 blocks, 8/CU
        gemm_nt<64, 128, 0, 1, 1, 1, 1><<<dim3(64, 32, 1), 256, 0, stream>>>(
            W1p_l, xbf, hbuf, b1in + i * 2048, xmask, zpage,
            1536, 1536, 512, 2048, 512, 0, 0, 0, 0, 0, 0);
        // conv2 split-K by tap: partials [3][8192][512] bf16 (1536 blocks)
        gemm_nt<64, 128, 0, 2, 0, 0, 0><<<dim3(64, 8, 3), 256, 0, stream>>>(
            W2p_l, hbuf, part, nullptr, nullptr, zpage,
            2048, 6144, 2048, 512, 2048, 0, 0, 0, 0, 0, 0);
        // LN2 fused with partial reduce + bias + mask
        ln_residual_p3<<<2048, 256, 0, stream>>>(xres, part, xbf,
                                                 ln2g + i * 512, ln2b + i * 512,
                                                 b2in + i * 512, xmask);
    }

    transpose_out_k<<<dim3(32, 16, 8), 256, 0, stream>>>(xres, xmask, out);
}

// Round 18
// 2395.274 us; speedup vs baseline: 1.5394x; 1.0140x over previous
//
#include <hip/hip_runtime.h>

typedef __bf16 bf16_t;
typedef __bf16 bf16x8 __attribute__((ext_vector_type(8)));
typedef __bf16 bf16x4 __attribute__((ext_vector_type(4)));
typedef float  f32x4  __attribute__((ext_vector_type(4)));

#define AS1 __attribute__((address_space(1)))
#define AS3 __attribute__((address_space(3)))

#define CMAX 16.0f   // static softmax max bound (true scores |s| ~ 1)

// ---------------------------------------------------------------------------
// Unified NT GEMM:  D[m][n] = sum_k A[m][k] * Bt[n][k]   (both K-contiguous)
// OUTMN=0: store C[n][m] (activation layout), OUTMN=1: store C[m][n].
// CONV=1: K = 3*CIN fused tap loop. CONV=2: split-K, blockIdx.z = tap,
//         K = CIN, writes bf16 partial at C + (tap<<22) + n*512 + m.
// ---------------------------------------------------------------------------
template<int BM, int BN, int OUTMN, int CONV, int BIAS, int RELU, int MASK>
__global__ __launch_bounds__(256)
void gemm_nt(const bf16_t* __restrict__ A, const bf16_t* __restrict__ B,
             bf16_t* __restrict__ C, const float* __restrict__ bias,
             const float* __restrict__ mask, const bf16_t* __restrict__ zpage,
             int K, int lda, int ldb, int ldc, int CIN,
             long sAb, long sAh, long sBb, long sBh, long sCb, long sCh)
{
    constexpr int BK = 32;
    __shared__ bf16_t As[BM * BK];
    __shared__ bf16_t Bs[BN * BK];
    const int z = blockIdx.z;
    int tap0 = 0;
    if constexpr (CONV == 2) {
        tap0 = z;
        A += (long)tap0 * CIN;             // tap's K-slice of the weight
    } else {
        A += (long)(z >> 3) * sAb + (long)(z & 7) * sAh;
        B += (long)(z >> 3) * sBb + (long)(z & 7) * sBh;
        C += (long)(z >> 3) * sCb + (long)(z & 7) * sCh;
    }
    const int m0 = blockIdx.y * BM;
    const int n0 = blockIdx.x * BN;
    const int tid = threadIdx.x;
    const int wid = tid >> 6, lane = tid & 63;
    constexpr int WM = BM / 2, WN = BN / 2;
    constexpr int FM = WM / 16, FN = WN / 16;
    const int wm = wid >> 1, wn = wid & 1;

    f32x4 acc[FM][FN] = {};

    constexpr int ACH = BM / 64;   // A chunks (16 rows = 1KB) per wave
    constexpr int BCH = BN / 64;
    const int rquad = lane >> 2;          // row within 16-row chunk
    const int koff  = (lane & 3) * 8;     // element offset along K

    int tap = 0, cc0 = 0;
    for (int k0 = 0; k0 < K; k0 += BK) {
        #pragma unroll
        for (int q = 0; q < ACH; ++q) {
            int ch  = wid * ACH + q;
            int row = ch * 16 + rquad;
            const bf16_t* src = A + (long)(m0 + row) * lda + (k0 + koff);
            __builtin_amdgcn_global_load_lds((const AS1 void*)src,
                                             (AS3 void*)(As + ch * 512), 16, 0, 0);
        }
        #pragma unroll
        for (int q = 0; q < BCH; ++q) {
            int ch  = wid * BCH + q;
            int row = ch * 16 + rquad;
            const bf16_t* src;
            if constexpr (CONV == 1) {
                int tl = (n0 & 1023) + row + tap - 1;
                src = ((unsigned)tl < 1024u)
                    ? B + (long)(n0 + row + tap - 1) * ldb + (cc0 + koff)
                    : zpage + koff;
            } else if constexpr (CONV == 2) {
                int tl = (n0 & 1023) + row + tap0 - 1;
                src = ((unsigned)tl < 1024u)
                    ? B + (long)(n0 + row + tap0 - 1) * ldb + (k0 + koff)
                    : zpage + koff;
            } else {
                src = B + (long)(n0 + row) * ldb + (k0 + koff);
            }
            __builtin_amdgcn_global_load_lds((const AS1 void*)src,
                                             (AS3 void*)(Bs + ch * 512), 16, 0, 0);
        }
        if constexpr (CONV == 1) { cc0 += BK; if (cc0 == CIN) { cc0 = 0; ++tap; } }
        __syncthreads();

        const bf16_t* Ab = As + (wm * WM + (lane & 15)) * BK + ((lane >> 4) * 8);
        const bf16_t* Bb = Bs + (wn * WN + (lane & 15)) * BK + ((lane >> 4) * 8);
        bf16x8 af[FM], bv[FN];
        #pragma unroll
        for (int i = 0; i < FM; ++i) af[i] = *(const bf16x8*)(Ab + i * 16 * BK);
        #pragma unroll
        for (int j = 0; j < FN; ++j) bv[j] = *(const bf16x8*)(Bb + j * 16 * BK);
        #pragma unroll
        for (int i = 0; i < FM; ++i)
            #pragma unroll
            for (int j = 0; j < FN; ++j)
                acc[i][j] = __builtin_amdgcn_mfma_f32_16x16x32_bf16(af[i], bv[j], acc[i][j], 0, 0, 0);
        __syncthreads();
    }

    const int mw = m0 + wm * WM, nw = n0 + wn * WN;
    #pragma unroll
    for (int i = 0; i < FM; ++i) {
        const int mb = mw + i * 16 + (lane >> 4) * 4;
        f32x4 bvv = {};
        if constexpr (BIAS) bvv = *(const f32x4*)(bias + mb);
        #pragma unroll
        for (int j = 0; j < FN; ++j) {
            const int nn = nw + j * 16 + (lane & 15);
            f32x4 v = acc[i][j];
            if constexpr (BIAS) v += bvv;
            if constexpr (RELU) {
                #pragma unroll
                for (int r = 0; r < 4; ++r) v[r] = fmaxf(v[r], 0.f);
            }
            if constexpr (MASK) v *= mask[nn];
            bf16x4 o;
            #pragma unroll
            for (int r = 0; r < 4; ++r) o[r] = (bf16_t)v[r];
            if constexpr (CONV == 2) {
                *(bf16x4*)(C + ((long)tap0 << 22) + (long)nn * 512 + mb) = o;
            } else if constexpr (OUTMN) {
                #pragma unroll
                for (int r = 0; r < 4; ++r) C[(long)(mb + r) * ldc + nn] = (bf16_t)v[r];
            } else {
                *(bf16x4*)(C + (long)nn * ldc + mb) = o;
            }
        }
    }
}

// ---------------------------------------------------------------------------
// kb[n] = -1e4 if mask[n]==0 else 0   (additive key-side mask bias)
// ---------------------------------------------------------------------------
__global__ __launch_bounds__(256)
void mask_bias(const float* __restrict__ mask, float* __restrict__ kb)
{
    int i = blockIdx.x * 256 + threadIdx.x;
    if (i < 8192) kb[i] = (mask[i] == 0.f) ? -1e4f : 0.f;
}

// ---------------------------------------------------------------------------
// Fully-fused flash attention: static-max softmax (p = exp(s-CMAX)), row-sum
// via ones-MFMA, R table computed in-prologue via 2 MFMAs (fused rel_qk),
// band P captured to LDS in "near" s-tiles (no loop-carried registers -- no
// r13 spill hazard), banded rel-v applied in the epilogue. One kernel does
// the entire attention step; outputs are final.
// Grid (64 bh, 16 qtiles), 4 waves, wave owns 16 q-rows, 16 s-iters of 64.
// ---------------------------------------------------------------------------
__global__ __launch_bounds__(256)
void flash_attn(const bf16_t* __restrict__ qk, const bf16_t* __restrict__ vt,
                const float* __restrict__ erk_l, const float* __restrict__ kb,
                const float* __restrict__ erv_l, bf16_t* __restrict__ out)
{
    __shared__ bf16_t P_lds[4 * 1024];             // 2KB per wave
    __shared__ float Rw[4][16 * 9];                // R tile per wave
    __shared__ float Pw[4][16 * 9];                // band P per wave
    const int w = threadIdx.x >> 6, lane = threadIdx.x & 63;
    const int hi = lane >> 4, li = lane & 15;
    const int bh = blockIdx.x, b = bh >> 3, h = bh & 7;
    const int q0 = blockIdx.y * 64 + w * 16;
    const long nbase = (long)b * 1024;
    char* pw = (char*)(P_lds + w * 1024);

    const bf16_t* qrow = qk + (nbase + q0 + li) * 1024 + h * 64 + hi * 8;
    bf16x8 aq0 = *(const bf16x8*)(qrow);
    bf16x8 aq1 = *(const bf16x8*)(qrow + 32);

    // ---- fused rel_qk: R[row][jb] = q . erk[jb], 16x9 tile via 2 MFMAs ----
    {
        bf16x8 be0, be1;
        #pragma unroll
        for (int e = 0; e < 8; ++e) {
            float v0 = (li < 9) ? erk_l[li * 64 + hi * 8 + e] : 0.f;
            float v1 = (li < 9) ? erk_l[li * 64 + 32 + hi * 8 + e] : 0.f;
            be0[e] = (bf16_t)v0; be1[e] = (bf16_t)v1;
        }
        f32x4 racc = {};
        racc = __builtin_amdgcn_mfma_f32_16x16x32_bf16(aq0, be0, racc, 0, 0, 0);
        racc = __builtin_amdgcn_mfma_f32_16x16x32_bf16(aq1, be1, racc, 0, 0, 0);
        if (li < 9) {
            #pragma unroll
            for (int r = 0; r < 4; ++r)
                Rw[w][(hi * 4 + r) * 9 + li] = racc[r];
        }
    }

    bf16x8 ones;
    #pragma unroll
    for (int e = 0; e < 8; ++e) ones[e] = (bf16_t)1.0f;

    f32x4 acc_o[4] = {};
    f32x4 acc_l = {};

    const bf16_t* kbase = qk + nbase * 1024 + 512 + h * 64 + hi * 8;
    const bf16_t* vbase = vt + (long)(h * 64 + li) * 8192 + nbase + hi * 8;
    const float* kbp = kb + b * 1024;

    bf16x8 kc[4][2], vv[4][2];
    #pragma unroll
    for (int j = 0; j < 4; ++j) {
        const bf16_t* kr = kbase + (long)(j * 16 + li) * 1024;
        kc[j][0] = *(const bf16x8*)kr;
        kc[j][1] = *(const bf16x8*)(kr + 32);
    }

    for (int it = 0; it < 16; ++it) {
        const int s0 = it * 64;
        #pragma unroll
        for (int j2 = 0; j2 < 4; ++j2) {
            const bf16_t* vr = vbase + (long)(j2 * 16) * 8192 + s0;
            vv[j2][0] = *(const bf16x8*)vr;
            vv[j2][1] = *(const bf16x8*)(vr + 32);
        }
        float kbv[4];
        #pragma unroll
        for (int j = 0; j < 4; ++j) kbv[j] = kbp[s0 + j * 16 + li];
        f32x4 sc[4];
        __builtin_amdgcn_s_setprio(1);
        #pragma unroll
        for (int j = 0; j < 4; ++j) {
            f32x4 a = {};
            a = __builtin_amdgcn_mfma_f32_16x16x32_bf16(aq0, kc[j][0], a, 0, 0, 0);
            a = __builtin_amdgcn_mfma_f32_16x16x32_bf16(aq1, kc[j][1], a, 0, 0, 0);
            sc[j] = a;
        }
        __builtin_amdgcn_s_setprio(0);
        const int s1 = (s0 + 64) & 1023;
        #pragma unroll
        for (int j = 0; j < 4; ++j) {
            const bf16_t* kr = kbase + (long)(s1 + j * 16 + li) * 1024;
            kc[j][0] = *(const bf16x8*)kr;
            kc[j][1] = *(const bf16x8*)(kr + 32);
        }
        #pragma unroll
        for (int j = 0; j < 4; ++j) {
            const int sb = s0 + j * 16;
            const bool near = (sb + 15 >= q0 - 4) && (sb <= q0 + 19);
            const int s_abs = sb + li;
            #pragma unroll
            for (int r = 0; r < 4; ++r) {
                const int row = hi * 4 + r;
                const int q_abs = q0 + row;
                float v = sc[j][r] + kbv[j];
                float pex;
                if (near) {
                    int jb = s_abs - q_abs + 4;
                    if ((unsigned)jb < 9u) v += Rw[w][row * 9 + jb];
                    pex = __expf(v - CMAX);
                    if ((unsigned)jb < 9u) Pw[w][row * 9 + jb] = pex;
                } else {
                    pex = __expf(v - CMAX);
                }
                sc[j][r] = pex;
            }
        }
        #pragma unroll
        for (int j = 0; j < 4; ++j)
            #pragma unroll
            for (int r = 0; r < 4; ++r) {
                int q = hi * 4 + r;
                int c = (j * 32 + li * 2) ^ ((q & 7) << 4);
                *(bf16_t*)(pw + q * 128 + c) = (bf16_t)sc[j][r];
            }
        asm volatile("s_waitcnt lgkmcnt(0)" ::: "memory");
        __builtin_amdgcn_s_setprio(1);
        #pragma unroll
        for (int half = 0; half < 2; ++half) {
            int cr = (half * 64 + hi * 16) ^ ((li & 7) << 4);
            bf16x8 pa = *(const bf16x8*)(pw + li * 128 + cr);
            #pragma unroll
            for (int j2 = 0; j2 < 4; ++j2)
                acc_o[j2] = __builtin_amdgcn_mfma_f32_16x16x32_bf16(pa, vv[j2][half], acc_o[j2], 0, 0, 0);
            acc_l = __builtin_amdgcn_mfma_f32_16x16x32_bf16(pa, ones, acc_l, 0, 0, 0);
        }
        __builtin_amdgcn_s_setprio(0);
    }

    // ---- epilogue: normalize + banded rel-v (Pw has all 9 values/row) ----
    #pragma unroll
    for (int r = 0; r < 4; ++r) {
        const int row = hi * 4 + r;
        const int q_abs = q0 + row;
        const float inv = 1.f / acc_l[r];
        #pragma unroll
        for (int j2 = 0; j2 < 4; ++j2) {
            const int d = j2 * 16 + li;
            float v = acc_o[j2][r];
            #pragma unroll
            for (int jb = 0; jb < 9; ++jb)
                if ((unsigned)(q_abs + jb - 4) < 1024u)   // unwritten never read
                    v += Pw[w][row * 9 + jb] * erv_l[jb * 64 + d];
            out[(nbase + q_abs) * 512 + h * 64 + d] = (bf16_t)(v * inv);
        }
    }
}

// ---------------------------------------------------------------------------
// Residual + LayerNorm over C=512 (wave per row n).
// ---------------------------------------------------------------------------
template<int MASKOUT>
__global__ __launch_bounds__(256)
void ln_residual(float* __restrict__ xres, const bf16_t* __restrict__ y,
                 bf16_t* __restrict__ xbf, const float* __restrict__ g,
                 const float* __restrict__ bvec, const float* __restrict__ mask)
{
    int gw = blockIdx.x * 4 + (threadIdx.x >> 6);
    int lane = threadIdx.x & 63;
    long base = (long)gw * 512 + lane * 8;
    f32x4 x0 = *(const f32x4*)(xres + base);
    f32x4 x1 = *(const f32x4*)(xres + base + 4);
    bf16x8 yv = *(const bf16x8*)(y + base);
    float s[8];
    #pragma unroll
    for (int e = 0; e < 4; ++e) { s[e] = x0[e] + (float)yv[e]; s[4 + e] = x1[e] + (float)yv[4 + e]; }
    float sum = 0.f, sq = 0.f;
    #pragma unroll
    for (int e = 0; e < 8; ++e) { sum += s[e]; sq += s[e] * s[e]; }
    #pragma unroll
    for (int o = 1; o < 64; o <<= 1) { sum += __shfl_xor(sum, o); sq += __shfl_xor(sq, o); }
    float mean = sum * (1.f / 512.f);
    float var  = sq * (1.f / 512.f) - mean * mean;
    float rstd = rsqrtf(var + 1e-5f);
    f32x4 g0 = *(const f32x4*)(g + lane * 8);
    f32x4 g1 = *(const f32x4*)(g + lane * 8 + 4);
    f32x4 b0 = *(const f32x4*)(bvec + lane * 8);
    f32x4 b1 = *(const f32x4*)(bvec + lane * 8 + 4);
    float mk = MASKOUT ? mask[gw] : 1.f;
    f32x4 o0, o1; bf16x8 ob;
    #pragma unroll
    for (int e = 0; e < 4; ++e) {
        float v0 = (s[e] - mean) * rstd * g0[e] + b0[e];
        float v1 = (s[4 + e] - mean) * rstd * g1[e] + b1[e];
        o0[e] = v0; o1[e] = v1;
        ob[e] = (bf16_t)(v0 * mk); ob[4 + e] = (bf16_t)(v1 * mk);
    }
    *(f32x4*)(xres + base) = o0;
    *(f32x4*)(xres + base + 4) = o1;
    *(bf16x8*)(xbf + base) = ob;
}

// ---------------------------------------------------------------------------
// Sum of 3 conv2 tap-partials + bias, mask, residual + LayerNorm (ln2).
// ---------------------------------------------------------------------------
__global__ __launch_bounds__(256)
void ln_residual_p3(float* __restrict__ xres, const bf16_t* __restrict__ part,
                    bf16_t* __restrict__ xbf, const float* __restrict__ g,
                    const float* __restrict__ bvec, const float* __restrict__ bias,
                    const float* __restrict__ mask)
{
    int gw = blockIdx.x * 4 + (threadIdx.x >> 6);
    int lane = threadIdx.x & 63;
    long base = (long)gw * 512 + lane * 8;
    bf16x8 pa = *(const bf16x8*)(part + base);
    bf16x8 pbv = *(const bf16x8*)(part + base + (1l << 22));
    bf16x8 pc = *(const bf16x8*)(part + base + (2l << 22));
    f32x4 x0 = *(const f32x4*)(xres + base);
    f32x4 x1 = *(const f32x4*)(xres + base + 4);
    f32x4 bi0 = *(const f32x4*)(bias + lane * 8);
    f32x4 bi1 = *(const f32x4*)(bias + lane * 8 + 4);
    float mk = mask[gw];
    float s[8];
    #pragma unroll
    for (int e = 0; e < 4; ++e) {
        float y0 = ((float)pa[e] + (float)pbv[e] + (float)pc[e] + bi0[e]) * mk;
        float y1 = ((float)pa[4 + e] + (float)pbv[4 + e] + (float)pc[4 + e] + bi1[e]) * mk;
        s[e] = x0[e] + y0; s[4 + e] = x1[e] + y1;
    }
    float sum = 0.f, sq = 0.f;
    #pragma unroll
    for (int e = 0; e < 8; ++e) { sum += s[e]; sq += s[e] * s[e]; }
    #pragma unroll
    for (int o = 1; o < 64; o <<= 1) { sum += __shfl_xor(sum, o); sq += __shfl_xor(sq, o); }
    float mean = sum * (1.f / 512.f);
    float var  = sq * (1.f / 512.f) - mean * mean;
    float rstd = rsqrtf(var + 1e-5f);
    f32x4 g0 = *(const f32x4*)(g + lane * 8);
    f32x4 g1 = *(const f32x4*)(g + lane * 8 + 4);
    f32x4 b0 = *(const f32x4*)(bvec + lane * 8);
    f32x4 b1 = *(const f32x4*)(bvec + lane * 8 + 4);
    f32x4 o0, o1; bf16x8 ob;
    #pragma unroll
    for (int e = 0; e < 4; ++e) {
        float v0 = (s[e] - mean) * rstd * g0[e] + b0[e];
        float v1 = (s[4 + e] - mean) * rstd * g1[e] + b1[e];
        o0[e] = v0; o1[e] = v1;
        ob[e] = (bf16_t)v0; ob[4 + e] = (bf16_t)v1;
    }
    *(f32x4*)(xres + base) = o0;
    *(f32x4*)(xres + base + 4) = o1;
    *(bf16x8*)(xbf + base) = ob;
}

// ---------------------------------------------------------------------------
// Transposes: x[B,C,T] <-> act[B*T, C]
// ---------------------------------------------------------------------------
__global__ __launch_bounds__(256)
void transpose_in_k(const float* __restrict__ x, const float* __restrict__ mask,
                    float* __restrict__ xres, bf16_t* __restrict__ xbf)
{
    __shared__ float tile[32][33];
    int b = blockIdx.z, c0 = blockIdx.y * 32, t0 = blockIdx.x * 32;
    int tx = threadIdx.x & 31, ty = threadIdx.x >> 5;
    #pragma unroll
    for (int r = 0; r < 4; ++r) {
        int cl = ty + r * 8;
        tile[cl][tx] = x[((long)b * 512 + c0 + cl) * 1024 + t0 + tx];
    }
    __syncthreads();
    #pragma unroll
    for (int r = 0; r < 4; ++r) {
        int tl = ty + r * 8;
        int n = b * 1024 + t0 + tl;
        float v = tile[tx][tl] * mask[n];
        xres[(long)n * 512 + c0 + tx] = v;
        xbf[(long)n * 512 + c0 + tx] = (bf16_t)v;
    }
}

__global__ __launch_bounds__(256)
void transpose_out_k(const float* __restrict__ xres, const float* __restrict__ mask,
                     float* __restrict__ out)
{
    __shared__ float tile[32][33];
    int b = blockIdx.z, c0 = blockIdx.y * 32, t0 = blockIdx.x * 32;
    int tx = threadIdx.x & 31, ty = threadIdx.x >> 5;
    #pragma unroll
    for (int r = 0; r < 4; ++r) {
        int tl = ty + r * 8;
        int n = b * 1024 + t0 + tl;
        tile[tl][tx] = xres[(long)n * 512 + c0 + tx] * mask[n];
    }
    __syncthreads();
    #pragma unroll
    for (int r = 0; r < 4; ++r) {
        int cl = ty + r * 8;
        out[((long)b * 512 + c0 + cl) * 1024 + t0 + tx] = tile[tx][cl];
    }
}

// ---------------------------------------------------------------------------
// Per-layer weight packing (fp32 -> bf16, q-scale fold, conv k-major repack)
// ---------------------------------------------------------------------------
__global__ __launch_bounds__(256)
void pack_attn_w(const float* __restrict__ w, bf16_t* __restrict__ Wqk,
                 bf16_t* __restrict__ Wv, bf16_t* __restrict__ Wo)
{
    int idx = blockIdx.x * 256 + threadIdx.x;      // < 4*512*512
    if (idx >= 4 * 512 * 512) return;
    int c = idx & 511;
    int o = (idx >> 9) & 511;
    int which = idx >> 18;
    float v = w[idx];
    if (which == 0) v *= 0.125f;
    if (which <= 1)      Wqk[(which * 512 + o) * 512 + c] = (bf16_t)v;
    else if (which == 2) Wv[o * 512 + c] = (bf16_t)v;
    else                 Wo[o * 512 + c] = (bf16_t)v;
}

__global__ __launch_bounds__(256)
void pack_attn_b(const float* __restrict__ bsrc, float* __restrict__ bqk)
{
    int idx = blockIdx.x * 256 + threadIdx.x;
    if (idx >= 6 * 2 * 512) return;     // only q,k need packing (q scaled)
    int c = idx & 511, which = (idx >> 9) & 1, i = idx >> 10;
    float v = bsrc[(i * 4 + which) * 512 + c];
    if (which == 0) v *= 0.125f;
    bqk[i * 1024 + which * 512 + c] = v;
}

// ---------------------------------------------------------------------------
// Merged conv weight pack: w1[f][c][k] -> W1p[f][k][c], w2[c][f][k] ->
// W2p[c][k][f].
// ---------------------------------------------------------------------------
__global__ __launch_bounds__(256)
void pack_conv_w(const float* __restrict__ w1, const float* __restrict__ w2,
                 bf16_t* __restrict__ W1p, bf16_t* __restrict__ W2p)
{
    int idx = blockIdx.x * 256 + threadIdx.x;      // < 2048*1536 + 512*6144
    if (idx < 2048 * 1536) {
        int c = idx & 511;
        int k = (idx >> 9) % 3;
        int f = idx / 1536;
        W1p[idx] = (bf16_t)w1[(f * 512 + c) * 3 + k];
    } else {
        int j = idx - 2048 * 1536;                 // < 512*6144
        int f = j & 2047;
        int k = (j >> 11) % 3;
        int ci = j / 6144;
        W2p[j] = (bf16_t)w2[ci * 6144 + f * 3 + k];
    }
}

// ---------------------------------------------------------------------------
extern "C" void kernel_launch(void* const* d_in, const int* in_sizes, int n_in,
                              void* d_out, int out_size, void* d_ws, size_t ws_size,
                              hipStream_t stream)
{
    const float* x      = (const float*)d_in[0];
    const float* xmask  = (const float*)d_in[1];
    const float* attn_w = (const float*)d_in[2];
    const float* attn_b = (const float*)d_in[3];
    const float* erk    = (const float*)d_in[4];
    const float* erv    = (const float*)d_in[5];
    const float* ln1g   = (const float*)d_in[6];
    const float* ln1b   = (const float*)d_in[7];
    const float* w1     = (const float*)d_in[8];
    const float* b1in   = (const float*)d_in[9];
    const float* w2     = (const float*)d_in[10];
    const float* b2in   = (const float*)d_in[11];
    const float* ln2g   = (const float*)d_in[12];
    const float* ln2b   = (const float*)d_in[13];
    float* out = (float*)d_out;

    char* p = (char*)d_ws;
    auto alloc = [&](size_t bytes) {
        char* r = p;
        p += (bytes + 255) & ~(size_t)255;
        return r;
    };
    // total ws usage ~110 MB
    bf16_t* zpage = (bf16_t*)alloc(1024);
    bf16_t* Wqk_l = (bf16_t*)alloc(1024l * 512 * 2);
    bf16_t* Wv_l  = (bf16_t*)alloc(512l * 512 * 2);
    bf16_t* Wo_l  = (bf16_t*)alloc(512l * 512 * 2);
    bf16_t* W1p_l = (bf16_t*)alloc(2048l * 1536 * 2);
    bf16_t* W2p_l = (bf16_t*)alloc(512l * 6144 * 2);
    float*  bqk   = (float*)alloc(6l * 1024 * 4);
    float*  xres  = (float*)alloc(8192l * 512 * 4);
    bf16_t* xbf   = (bf16_t*)alloc(8192l * 512 * 2);
    bf16_t* big   = (bf16_t*)alloc(8192l * 2048 * 2);   // qk|vt|attn_out, aliased by hbuf
    bf16_t* ybuf  = (bf16_t*)alloc(8192l * 512 * 2);
    bf16_t* part  = (bf16_t*)alloc(3l * 8192 * 512 * 2); // conv2 tap partials
    float*  kb    = (float*)alloc(8192l * 4);            // key-side mask bias
    (void)in_sizes; (void)n_in; (void)out_size; (void)ws_size;

    bf16_t* qk       = big;                    // [8192][1024]
    bf16_t* vt       = big + 8192l * 1024;     // [512][8192]
    bf16_t* attn_out = vt + 512l * 8192;       // [8192][512]
    bf16_t* hbuf     = big;                    // [8192][2048], aliases all three

    hipMemsetAsync(zpage, 0, 1024, stream);
    pack_attn_b<<<24, 256, 0, stream>>>(attn_b, bqk);
    mask_bias<<<32, 256, 0, stream>>>(xmask, kb);
    transpose_in_k<<<dim3(32, 16, 8), 256, 0, stream>>>(x, xmask, xres, xbf);

    for (int i = 0; i < 6; ++i) {
        pack_attn_w<<<4096, 256, 0, stream>>>(attn_w + (long)i * 4 * 512 * 512,
                                              Wqk_l, Wv_l, Wo_l);
        pack_conv_w<<<24576, 256, 0, stream>>>(w1 + (long)i * 2048 * 512 * 3,
                                               w2 + (long)i * 512 * 2048 * 3,
                                               W1p_l, W2p_l);

        // QK projection (q pre-scaled) -- BM=64: 1024 blocks, 4/CU
        gemm_nt<64, 128, 0, 0, 1, 0, 0><<<dim3(64, 16, 1), 256, 0, stream>>>(
            Wqk_l, xbf, qk, bqk + i * 1024, nullptr, zpage,
            512, 512, 512, 1024, 0, 0, 0, 0, 0, 0, 0);
        // V projection -> channel-major vt[c][n] -- BN=64: 1024 blocks
        gemm_nt<64, 64, 1, 0, 1, 0, 0><<<dim3(128, 8, 1), 256, 0, stream>>>(
            Wv_l, xbf, vt, attn_b + (i * 4 + 2) * 512, nullptr, zpage,
            512, 512, 512, 8192, 0, 0, 0, 0, 0, 0, 0);
        // fully-fused flash attention (R + softmax + PV + band rel-v)
        flash_attn<<<dim3(64, 16), 256, 0, stream>>>(qk, vt, erk + i * 576, kb,
                                                     erv + i * 576, attn_out);
        // O projection -- BN=64: 1024 blocks
        gemm_nt<64, 64, 0, 0, 1, 0, 0><<<dim3(128, 8, 1), 256, 0, stream>>>(
            Wo_l, attn_out, ybuf, attn_b + (i * 4 + 3) * 512, nullptr, zpage,
            512, 512, 512, 512, 0, 0, 0, 0, 0, 0, 0);
        // LN1 (xbf masked for conv1 input)
        ln_residual<1><<<2048, 256, 0, stream>>>(xres, ybuf, xbf,
                                                 ln1g + i * 512, ln1b + i * 512, xmask);
        // conv1 (K=3*512) + bias + relu + mask  -- BM=64: 2048 blocks, 8/CU
        gemm_nt<64, 128, 0, 1, 1, 1, 1><<<dim3(64, 32, 1), 256, 0, stream>>>(
            W1p_l, xbf, hbuf, b1in + i * 2048, xmask, zpage,
            1536, 1536, 512, 2048, 512, 0, 0, 0, 0, 0, 0);
        // conv2 split-K by tap: partials [3][8192][512] bf16 (1536 blocks)
        gemm_nt<64, 128, 0, 2, 0, 0, 0><<<dim3(64, 8, 3), 256, 0, stream>>>(
            W2p_l, hbuf, part, nullptr, nullptr, zpage,
            2048, 6144, 2048, 512, 2048, 0, 0, 0, 0, 0, 0);
        // LN2 fused with partial reduce + bias + mask
        ln_residual_p3<<<2048, 256, 0, stream>>>(xres, part, xbf,
                                                 ln2g + i * 512, ln2b + i * 512,
                                                 b2in + i * 512, xmask);
    }

    transpose_out_k<<<dim3(32, 16, 8), 256, 0, stream>>>(xres, xmask, out);
}

// Round 19
// 2346.330 us; speedup vs baseline: 1.5715x; 1.0209x over previous
//
#include <hip/hip_runtime.h>

typedef __bf16 bf16_t;
typedef __bf16 bf16x8 __attribute__((ext_vector_type(8)));
typedef __bf16 bf16x4 __attribute__((ext_vector_type(4)));
typedef float  f32x4  __attribute__((ext_vector_type(4)));

#define AS1 __attribute__((address_space(1)))
#define AS3 __attribute__((address_space(3)))

#define CMAX 16.0f   // static softmax max bound (true scores |s| ~ 1)

// ---------------------------------------------------------------------------
// Unified NT GEMM:  D[m][n] = sum_k A[m][k] * Bt[n][k]   (both K-contiguous)
// OUTMN=0: store C[n][m]. OUTMN=1: store C[m][n]. OUTMN=2: QKV fused --
//   m0<1024 -> qk[n][m] (ldc 1024); m0>=1024 -> vt[m-1024][n] (ld 8192),
//   vt located at C + 8192*1024.
// CONV=1: K = 3*CIN fused tap loop. CONV=2: split-K, blockIdx.z = tap,
//         K = CIN, writes bf16 partial at C + (tap<<22) + n*512 + m.
// ---------------------------------------------------------------------------
template<int BM, int BN, int OUTMN, int CONV, int BIAS, int RELU, int MASK>
__global__ __launch_bounds__(256)
void gemm_nt(const bf16_t* __restrict__ A, const bf16_t* __restrict__ B,
             bf16_t* __restrict__ C, const float* __restrict__ bias,
             const float* __restrict__ mask, const bf16_t* __restrict__ zpage,
             int K, int lda, int ldb, int ldc, int CIN,
             long sAb, long sAh, long sBb, long sBh, long sCb, long sCh)
{
    constexpr int BK = 32;
    __shared__ bf16_t As[BM * BK];
    __shared__ bf16_t Bs[BN * BK];
    const int z = blockIdx.z;
    int tap0 = 0;
    if constexpr (CONV == 2) {
        tap0 = z;
        A += (long)tap0 * CIN;             // tap's K-slice of the weight
    } else {
        A += (long)(z >> 3) * sAb + (long)(z & 7) * sAh;
        B += (long)(z >> 3) * sBb + (long)(z & 7) * sBh;
        C += (long)(z >> 3) * sCb + (long)(z & 7) * sCh;
    }
    const int m0 = blockIdx.y * BM;
    const int n0 = blockIdx.x * BN;
    const int tid = threadIdx.x;
    const int wid = tid >> 6, lane = tid & 63;
    constexpr int WM = BM / 2, WN = BN / 2;
    constexpr int FM = WM / 16, FN = WN / 16;
    const int wm = wid >> 1, wn = wid & 1;

    f32x4 acc[FM][FN] = {};

    constexpr int ACH = BM / 64;   // A chunks (16 rows = 1KB) per wave
    constexpr int BCH = BN / 64;
    const int rquad = lane >> 2;          // row within 16-row chunk
    const int koff  = (lane & 3) * 8;     // element offset along K

    int tap = 0, cc0 = 0;
    for (int k0 = 0; k0 < K; k0 += BK) {
        #pragma unroll
        for (int q = 0; q < ACH; ++q) {
            int ch  = wid * ACH + q;
            int row = ch * 16 + rquad;
            const bf16_t* src = A + (long)(m0 + row) * lda + (k0 + koff);
            __builtin_amdgcn_global_load_lds((const AS1 void*)src,
                                             (AS3 void*)(As + ch * 512), 16, 0, 0);
        }
        #pragma unroll
        for (int q = 0; q < BCH; ++q) {
            int ch  = wid * BCH + q;
            int row = ch * 16 + rquad;
            const bf16_t* src;
            if constexpr (CONV == 1) {
                int tl = (n0 & 1023) + row + tap - 1;
                src = ((unsigned)tl < 1024u)
                    ? B + (long)(n0 + row + tap - 1) * ldb + (cc0 + koff)
                    : zpage + koff;
            } else if constexpr (CONV == 2) {
                int tl = (n0 & 1023) + row + tap0 - 1;
                src = ((unsigned)tl < 1024u)
                    ? B + (long)(n0 + row + tap0 - 1) * ldb + (k0 + koff)
                    : zpage + koff;
            } else {
                src = B + (long)(n0 + row) * ldb + (k0 + koff);
            }
            __builtin_amdgcn_global_load_lds((const AS1 void*)src,
                                             (AS3 void*)(Bs + ch * 512), 16, 0, 0);
        }
        if constexpr (CONV == 1) { cc0 += BK; if (cc0 == CIN) { cc0 = 0; ++tap; } }
        __syncthreads();

        const bf16_t* Ab = As + (wm * WM + (lane & 15)) * BK + ((lane >> 4) * 8);
        const bf16_t* Bb = Bs + (wn * WN + (lane & 15)) * BK + ((lane >> 4) * 8);
        bf16x8 af[FM], bv[FN];
        #pragma unroll
        for (int i = 0; i < FM; ++i) af[i] = *(const bf16x8*)(Ab + i * 16 * BK);
        #pragma unroll
        for (int j = 0; j < FN; ++j) bv[j] = *(const bf16x8*)(Bb + j * 16 * BK);
        #pragma unroll
        for (int i = 0; i < FM; ++i)
            #pragma unroll
            for (int j = 0; j < FN; ++j)
                acc[i][j] = __builtin_amdgcn_mfma_f32_16x16x32_bf16(af[i], bv[j], acc[i][j], 0, 0, 0);
        __syncthreads();
    }

    const int mw = m0 + wm * WM, nw = n0 + wn * WN;
    #pragma unroll
    for (int i = 0; i < FM; ++i) {
        const int mb = mw + i * 16 + (lane >> 4) * 4;
        f32x4 bvv = {};
        if constexpr (BIAS) bvv = *(const f32x4*)(bias + mb);
        #pragma unroll
        for (int j = 0; j < FN; ++j) {
            const int nn = nw + j * 16 + (lane & 15);
            f32x4 v = acc[i][j];
            if constexpr (BIAS) v += bvv;
            if constexpr (RELU) {
                #pragma unroll
                for (int r = 0; r < 4; ++r) v[r] = fmaxf(v[r], 0.f);
            }
            if constexpr (MASK) v *= mask[nn];
            bf16x4 o;
            #pragma unroll
            for (int r = 0; r < 4; ++r) o[r] = (bf16_t)v[r];
            if constexpr (CONV == 2) {
                *(bf16x4*)(C + ((long)tap0 << 22) + (long)nn * 512 + mb) = o;
            } else if constexpr (OUTMN == 2) {
                if (m0 < 1024) {
                    *(bf16x4*)(C + (long)nn * 1024 + mb) = o;
                } else {
                    #pragma unroll
                    for (int r = 0; r < 4; ++r)
                        C[8192l * 1024 + (long)(mb - 1024 + r) * 8192 + nn] = (bf16_t)v[r];
                }
            } else if constexpr (OUTMN == 1) {
                #pragma unroll
                for (int r = 0; r < 4; ++r) C[(long)(mb + r) * ldc + nn] = (bf16_t)v[r];
            } else {
                *(bf16x4*)(C + (long)nn * ldc + mb) = o;
            }
        }
    }
}

// ---------------------------------------------------------------------------
// kb[n] = -1e4 if mask[n]==0 else 0   (additive key-side mask bias)
// ---------------------------------------------------------------------------
__global__ __launch_bounds__(256)
void mask_bias(const float* __restrict__ mask, float* __restrict__ kb)
{
    int i = blockIdx.x * 256 + threadIdx.x;
    if (i < 8192) kb[i] = (mask[i] == 0.f) ? -1e4f : 0.f;
}

// ---------------------------------------------------------------------------
// Fully-fused flash attention (unchanged from r18): static-max softmax,
// row-sum via ones-MFMA, fused rel_qk prologue, band P in LDS, band rel-v
// in epilogue. Grid (64 bh, 16 qtiles), 4 waves.
// ---------------------------------------------------------------------------
__global__ __launch_bounds__(256)
void flash_attn(const bf16_t* __restrict__ qk, const bf16_t* __restrict__ vt,
                const float* __restrict__ erk_l, const float* __restrict__ kb,
                const float* __restrict__ erv_l, bf16_t* __restrict__ out)
{
    __shared__ bf16_t P_lds[4 * 1024];             // 2KB per wave
    __shared__ float Rw[4][16 * 9];                // R tile per wave
    __shared__ float Pw[4][16 * 9];                // band P per wave
    const int w = threadIdx.x >> 6, lane = threadIdx.x & 63;
    const int hi = lane >> 4, li = lane & 15;
    const int bh = blockIdx.x, b = bh >> 3, h = bh & 7;
    const int q0 = blockIdx.y * 64 + w * 16;
    const long nbase = (long)b * 1024;
    char* pw = (char*)(P_lds + w * 1024);

    const bf16_t* qrow = qk + (nbase + q0 + li) * 1024 + h * 64 + hi * 8;
    bf16x8 aq0 = *(const bf16x8*)(qrow);
    bf16x8 aq1 = *(const bf16x8*)(qrow + 32);

    // ---- fused rel_qk: R[row][jb] = q . erk[jb], 16x9 tile via 2 MFMAs ----
    {
        bf16x8 be0, be1;
        #pragma unroll
        for (int e = 0; e < 8; ++e) {
            float v0 = (li < 9) ? erk_l[li * 64 + hi * 8 + e] : 0.f;
            float v1 = (li < 9) ? erk_l[li * 64 + 32 + hi * 8 + e] : 0.f;
            be0[e] = (bf16_t)v0; be1[e] = (bf16_t)v1;
        }
        f32x4 racc = {};
        racc = __builtin_amdgcn_mfma_f32_16x16x32_bf16(aq0, be0, racc, 0, 0, 0);
        racc = __builtin_amdgcn_mfma_f32_16x16x32_bf16(aq1, be1, racc, 0, 0, 0);
        if (li < 9) {
            #pragma unroll
            for (int r = 0; r < 4; ++r)
                Rw[w][(hi * 4 + r) * 9 + li] = racc[r];
        }
    }

    bf16x8 ones;
    #pragma unroll
    for (int e = 0; e < 8; ++e) ones[e] = (bf16_t)1.0f;

    f32x4 acc_o[4] = {};
    f32x4 acc_l = {};

    const bf16_t* kbase = qk + nbase * 1024 + 512 + h * 64 + hi * 8;
    const bf16_t* vbase = vt + (long)(h * 64 + li) * 8192 + nbase + hi * 8;
    const float* kbp = kb + b * 1024;

    bf16x8 kc[4][2], vv[4][2];
    #pragma unroll
    for (int j = 0; j < 4; ++j) {
        const bf16_t* kr = kbase + (long)(j * 16 + li) * 1024;
        kc[j][0] = *(const bf16x8*)kr;
        kc[j][1] = *(const bf16x8*)(kr + 32);
    }

    for (int it = 0; it < 16; ++it) {
        const int s0 = it * 64;
        #pragma unroll
        for (int j2 = 0; j2 < 4; ++j2) {
            const bf16_t* vr = vbase + (long)(j2 * 16) * 8192 + s0;
            vv[j2][0] = *(const bf16x8*)vr;
            vv[j2][1] = *(const bf16x8*)(vr + 32);
        }
        float kbv[4];
        #pragma unroll
        for (int j = 0; j < 4; ++j) kbv[j] = kbp[s0 + j * 16 + li];
        f32x4 sc[4];
        __builtin_amdgcn_s_setprio(1);
        #pragma unroll
        for (int j = 0; j < 4; ++j) {
            f32x4 a = {};
            a = __builtin_amdgcn_mfma_f32_16x16x32_bf16(aq0, kc[j][0], a, 0, 0, 0);
            a = __builtin_amdgcn_mfma_f32_16x16x32_bf16(aq1, kc[j][1], a, 0, 0, 0);
            sc[j] = a;
        }
        __builtin_amdgcn_s_setprio(0);
        const int s1 = (s0 + 64) & 1023;
        #pragma unroll
        for (int j = 0; j < 4; ++j) {
            const bf16_t* kr = kbase + (long)(s1 + j * 16 + li) * 1024;
            kc[j][0] = *(const bf16x8*)kr;
            kc[j][1] = *(const bf16x8*)(kr + 32);
        }
        #pragma unroll
        for (int j = 0; j < 4; ++j) {
            const int sb = s0 + j * 16;
            const bool near = (sb + 15 >= q0 - 4) && (sb <= q0 + 19);
            const int s_abs = sb + li;
            #pragma unroll
            for (int r = 0; r < 4; ++r) {
                const int row = hi * 4 + r;
                const int q_abs = q0 + row;
                float v = sc[j][r] + kbv[j];
                float pex;
                if (near) {
                    int jb = s_abs - q_abs + 4;
                    if ((unsigned)jb < 9u) v += Rw[w][row * 9 + jb];
                    pex = __expf(v - CMAX);
                    if ((unsigned)jb < 9u) Pw[w][row * 9 + jb] = pex;
                } else {
                    pex = __expf(v - CMAX);
                }
                sc[j][r] = pex;
            }
        }
        #pragma unroll
        for (int j = 0; j < 4; ++j)
            #pragma unroll
            for (int r = 0; r < 4; ++r) {
                int q = hi * 4 + r;
                int c = (j * 32 + li * 2) ^ ((q & 7) << 4);
                *(bf16_t*)(pw + q * 128 + c) = (bf16_t)sc[j][r];
            }
        asm volatile("s_waitcnt lgkmcnt(0)" ::: "memory");
        __builtin_amdgcn_s_setprio(1);
        #pragma unroll
        for (int half = 0; half < 2; ++half) {
            int cr = (half * 64 + hi * 16) ^ ((li & 7) << 4);
            bf16x8 pa = *(const bf16x8*)(pw + li * 128 + cr);
            #pragma unroll
            for (int j2 = 0; j2 < 4; ++j2)
                acc_o[j2] = __builtin_amdgcn_mfma_f32_16x16x32_bf16(pa, vv[j2][half], acc_o[j2], 0, 0, 0);
            acc_l = __builtin_amdgcn_mfma_f32_16x16x32_bf16(pa, ones, acc_l, 0, 0, 0);
        }
        __builtin_amdgcn_s_setprio(0);
    }

    // ---- epilogue: normalize + banded rel-v (Pw has all 9 values/row) ----
    #pragma unroll
    for (int r = 0; r < 4; ++r) {
        const int row = hi * 4 + r;
        const int q_abs = q0 + row;
        const float inv = 1.f / acc_l[r];
        #pragma unroll
        for (int j2 = 0; j2 < 4; ++j2) {
            const int d = j2 * 16 + li;
            float v = acc_o[j2][r];
            #pragma unroll
            for (int jb = 0; jb < 9; ++jb)
                if ((unsigned)(q_abs + jb - 4) < 1024u)   // unwritten never read
                    v += Pw[w][row * 9 + jb] * erv_l[jb * 64 + d];
            out[(nbase + q_abs) * 512 + h * 64 + d] = (bf16_t)(v * inv);
        }
    }
}

// ---------------------------------------------------------------------------
// Residual + LayerNorm over C=512 (wave per row n).
// ---------------------------------------------------------------------------
template<int MASKOUT>
__global__ __launch_bounds__(256)
void ln_residual(float* __restrict__ xres, const bf16_t* __restrict__ y,
                 bf16_t* __restrict__ xbf, const float* __restrict__ g,
                 const float* __restrict__ bvec, const float* __restrict__ mask)
{
    int gw = blockIdx.x * 4 + (threadIdx.x >> 6);
    int lane = threadIdx.x & 63;
    long base = (long)gw * 512 + lane * 8;
    f32x4 x0 = *(const f32x4*)(xres + base);
    f32x4 x1 = *(const f32x4*)(xres + base + 4);
    bf16x8 yv = *(const bf16x8*)(y + base);
    float s[8];
    #pragma unroll
    for (int e = 0; e < 4; ++e) { s[e] = x0[e] + (float)yv[e]; s[4 + e] = x1[e] + (float)yv[4 + e]; }
    float sum = 0.f, sq = 0.f;
    #pragma unroll
    for (int e = 0; e < 8; ++e) { sum += s[e]; sq += s[e] * s[e]; }
    #pragma unroll
    for (int o = 1; o < 64; o <<= 1) { sum += __shfl_xor(sum, o); sq += __shfl_xor(sq, o); }
    float mean = sum * (1.f / 512.f);
    float var  = sq * (1.f / 512.f) - mean * mean;
    float rstd = rsqrtf(var + 1e-5f);
    f32x4 g0 = *(const f32x4*)(g + lane * 8);
    f32x4 g1 = *(const f32x4*)(g + lane * 8 + 4);
    f32x4 b0 = *(const f32x4*)(bvec + lane * 8);
    f32x4 b1 = *(const f32x4*)(bvec + lane * 8 + 4);
    float mk = MASKOUT ? mask[gw] : 1.f;
    f32x4 o0, o1; bf16x8 ob;
    #pragma unroll
    for (int e = 0; e < 4; ++e) {
        float v0 = (s[e] - mean) * rstd * g0[e] + b0[e];
        float v1 = (s[4 + e] - mean) * rstd * g1[e] + b1[e];
        o0[e] = v0; o1[e] = v1;
        ob[e] = (bf16_t)(v0 * mk); ob[4 + e] = (bf16_t)(v1 * mk);
    }
    *(f32x4*)(xres + base) = o0;
    *(f32x4*)(xres + base + 4) = o1;
    *(bf16x8*)(xbf + base) = ob;
}

// ---------------------------------------------------------------------------
// Sum of 3 conv2 tap-partials + bias, mask, residual + LayerNorm (ln2).
// ---------------------------------------------------------------------------
__global__ __launch_bounds__(256)
void ln_residual_p3(float* __restrict__ xres, const bf16_t* __restrict__ part,
                    bf16_t* __restrict__ xbf, const float* __restrict__ g,
                    const float* __restrict__ bvec, const float* __restrict__ bias,
                    const float* __restrict__ mask)
{
    int gw = blockIdx.x * 4 + (threadIdx.x >> 6);
    int lane = threadIdx.x & 63;
    long base = (long)gw * 512 + lane * 8;
    bf16x8 pa = *(const bf16x8*)(part + base);
    bf16x8 pbv = *(const bf16x8*)(part + base + (1l << 22));
    bf16x8 pc = *(const bf16x8*)(part + base + (2l << 22));
    f32x4 x0 = *(const f32x4*)(xres + base);
    f32x4 x1 = *(const f32x4*)(xres + base + 4);
    f32x4 bi0 = *(const f32x4*)(bias + lane * 8);
    f32x4 bi1 = *(const f32x4*)(bias + lane * 8 + 4);
    float mk = mask[gw];
    float s[8];
    #pragma unroll
    for (int e = 0; e < 4; ++e) {
        float y0 = ((float)pa[e] + (float)pbv[e] + (float)pc[e] + bi0[e]) * mk;
        float y1 = ((float)pa[4 + e] + (float)pbv[4 + e] + (float)pc[4 + e] + bi1[e]) * mk;
        s[e] = x0[e] + y0; s[4 + e] = x1[e] + y1;
    }
    float sum = 0.f, sq = 0.f;
    #pragma unroll
    for (int e = 0; e < 8; ++e) { sum += s[e]; sq += s[e] * s[e]; }
    #pragma unroll
    for (int o = 1; o < 64; o <<= 1) { sum += __shfl_xor(sum, o); sq += __shfl_xor(sq, o); }
    float mean = sum * (1.f / 512.f);
    float var  = sq * (1.f / 512.f) - mean * mean;
    float rstd = rsqrtf(var + 1e-5f);
    f32x4 g0 = *(const f32x4*)(g + lane * 8);
    f32x4 g1 = *(const f32x4*)(g + lane * 8 + 4);
    f32x4 b0 = *(const f32x4*)(bvec + lane * 8);
    f32x4 b1 = *(const f32x4*)(bvec + lane * 8 + 4);
    f32x4 o0, o1; bf16x8 ob;
    #pragma unroll
    for (int e = 0; e < 4; ++e) {
        float v0 = (s[e] - mean) * rstd * g0[e] + b0[e];
        float v1 = (s[4 + e] - mean) * rstd * g1[e] + b1[e];
        o0[e] = v0; o1[e] = v1;
        ob[e] = (bf16_t)v0; ob[4 + e] = (bf16_t)v1;
    }
    *(f32x4*)(xres + base) = o0;
    *(f32x4*)(xres + base + 4) = o1;
    *(bf16x8*)(xbf + base) = ob;
}

// ---------------------------------------------------------------------------
// Transposes: x[B,C,T] <-> act[B*T, C]
// ---------------------------------------------------------------------------
__global__ __launch_bounds__(256)
void transpose_in_k(const float* __restrict__ x, const float* __restrict__ mask,
                    float* __restrict__ xres, bf16_t* __restrict__ xbf)
{
    __shared__ float tile[32][33];
    int b = blockIdx.z, c0 = blockIdx.y * 32, t0 = blockIdx.x * 32;
    int tx = threadIdx.x & 31, ty = threadIdx.x >> 5;
    #pragma unroll
    for (int r = 0; r < 4; ++r) {
        int cl = ty + r * 8;
        tile[cl][tx] = x[((long)b * 512 + c0 + cl) * 1024 + t0 + tx];
    }
    __syncthreads();
    #pragma unroll
    for (int r = 0; r < 4; ++r) {
        int tl = ty + r * 8;
        int n = b * 1024 + t0 + tl;
        float v = tile[tx][tl] * mask[n];
        xres[(long)n * 512 + c0 + tx] = v;
        xbf[(long)n * 512 + c0 + tx] = (bf16_t)v;
    }
}

__global__ __launch_bounds__(256)
void transpose_out_k(const float* __restrict__ xres, const float* __restrict__ mask,
                     float* __restrict__ out)
{
    __shared__ float tile[32][33];
    int b = blockIdx.z, c0 = blockIdx.y * 32, t0 = blockIdx.x * 32;
    int tx = threadIdx.x & 31, ty = threadIdx.x >> 5;
    #pragma unroll
    for (int r = 0; r < 4; ++r) {
        int tl = ty + r * 8;
        int n = b * 1024 + t0 + tl;
        tile[tl][tx] = xres[(long)n * 512 + c0 + tx] * mask[n];
    }
    __syncthreads();
    #pragma unroll
    for (int r = 0; r < 4; ++r) {
        int cl = ty + r * 8;
        out[((long)b * 512 + c0 + cl) * 1024 + t0 + tx] = tile[tx][cl];
    }
}

// ---------------------------------------------------------------------------
// Merged per-layer weight pack: attn (Wqkv q-scaled + Wo) + conv1 + conv2.
// idx ranges: [0, 1M) attn, [1M, 1M+3.14M) w1, [.., +3.14M) w2.
// ---------------------------------------------------------------------------
__global__ __launch_bounds__(256)
void pack_layer_w(const float* __restrict__ aw, const float* __restrict__ w1,
                  const float* __restrict__ w2, bf16_t* __restrict__ Wqkv,
                  bf16_t* __restrict__ Wo, bf16_t* __restrict__ W1p,
                  bf16_t* __restrict__ W2p)
{
    const int NA = 4 * 512 * 512;
    const int N1 = 2048 * 1536;
    int idx = blockIdx.x * 256 + threadIdx.x;
    if (idx < NA) {
        int c = idx & 511;
        int o = (idx >> 9) & 511;
        int which = idx >> 18;
        float v = aw[idx];
        if (which == 0) v *= 0.125f;
        if (which <= 2) Wqkv[((long)which * 512 + o) * 512 + c] = (bf16_t)v;
        else            Wo[o * 512 + c] = (bf16_t)v;
    } else if (idx < NA + N1) {
        int j = idx - NA;
        int c = j & 511;
        int k = (j >> 9) % 3;
        int f = j / 1536;
        W1p[j] = (bf16_t)w1[(f * 512 + c) * 3 + k];
    } else {
        int j = idx - NA - N1;                 // < 512*6144
        int f = j & 2047;
        int k = (j >> 11) % 3;
        int ci = j / 6144;
        W2p[j] = (bf16_t)w2[ci * 6144 + f * 3 + k];
    }
}

// bqkv[i*1536 + which*512 + c], q-part scaled by 0.125
__global__ __launch_bounds__(256)
void pack_attn_b(const float* __restrict__ bsrc, float* __restrict__ bqkv)
{
    int idx = blockIdx.x * 256 + threadIdx.x;
    if (idx >= 6 * 3 * 512) return;
    int c = idx & 511, which = (idx >> 9) % 3, i = idx / 1536;
    float v = bsrc[(i * 4 + which) * 512 + c];
    if (which == 0) v *= 0.125f;
    bqkv[i * 1536 + which * 512 + c] = v;
}

// ---------------------------------------------------------------------------
extern "C" void kernel_launch(void* const* d_in, const int* in_sizes, int n_in,
                              void* d_out, int out_size, void* d_ws, size_t ws_size,
                              hipStream_t stream)
{
    const float* x      = (const float*)d_in[0];
    const float* xmask  = (const float*)d_in[1];
    const float* attn_w = (const float*)d_in[2];
    const float* attn_b = (const float*)d_in[3];
    const float* erk    = (const float*)d_in[4];
    const float* erv    = (const float*)d_in[5];
    const float* ln1g   = (const float*)d_in[6];
    const float* ln1b   = (const float*)d_in[7];
    const float* w1     = (const float*)d_in[8];
    const float* b1in   = (const float*)d_in[9];
    const float* w2     = (const float*)d_in[10];
    const float* b2in   = (const float*)d_in[11];
    const float* ln2g   = (const float*)d_in[12];
    const float* ln2b   = (const float*)d_in[13];
    float* out = (float*)d_out;

    char* p = (char*)d_ws;
    auto alloc = [&](size_t bytes) {
        char* r = p;
        p += (bytes + 255) & ~(size_t)255;
        return r;
    };
    // total ws usage ~110 MB
    bf16_t* zpage  = (bf16_t*)alloc(1024);
    bf16_t* Wqkv_l = (bf16_t*)alloc(1536l * 512 * 2);
    bf16_t* Wo_l   = (bf16_t*)alloc(512l * 512 * 2);
    bf16_t* W1p_l  = (bf16_t*)alloc(2048l * 1536 * 2);
    bf16_t* W2p_l  = (bf16_t*)alloc(512l * 6144 * 2);
    float*  bqkv   = (float*)alloc(6l * 1536 * 4);
    float*  xres   = (float*)alloc(8192l * 512 * 4);
    bf16_t* xbf    = (bf16_t*)alloc(8192l * 512 * 2);
    bf16_t* big    = (bf16_t*)alloc(8192l * 2048 * 2);  // qk|vt|attn_out / hbuf
    bf16_t* ybuf   = (bf16_t*)alloc(8192l * 512 * 2);
    bf16_t* part   = (bf16_t*)alloc(3l * 8192 * 512 * 2); // conv2 tap partials
    float*  kb     = (float*)alloc(8192l * 4);            // key-side mask bias
    (void)in_sizes; (void)n_in; (void)out_size; (void)ws_size;

    bf16_t* qk       = big;                    // [8192][1024]
    bf16_t* vt       = big + 8192l * 1024;     // [512][8192]
    bf16_t* attn_out = vt + 512l * 8192;       // [8192][512]
    bf16_t* hbuf     = big;                    // [8192][2048], aliases all three

    hipMemsetAsync(zpage, 0, 1024, stream);
    pack_attn_b<<<36, 256, 0, stream>>>(attn_b, bqkv);
    mask_bias<<<32, 256, 0, stream>>>(xmask, kb);
    transpose_in_k<<<dim3(32, 16, 8), 256, 0, stream>>>(x, xmask, xres, xbf);

    for (int i = 0; i < 6; ++i) {
        // one merged weight-pack dispatch per layer
        pack_layer_w<<<28672, 256, 0, stream>>>(attn_w + (long)i * 4 * 512 * 512,
                                                w1 + (long)i * 2048 * 512 * 3,
                                                w2 + (long)i * 512 * 2048 * 3,
                                                Wqkv_l, Wo_l, W1p_l, W2p_l);

        // fused QKV projection: M=1536 (q|k -> qk[n][m], v -> vt[c][n])
        gemm_nt<64, 128, 2, 0, 1, 0, 0><<<dim3(64, 24, 1), 256, 0, stream>>>(
            Wqkv_l, xbf, qk, bqkv + i * 1536, nullptr, zpage,
            512, 512, 512, 1024, 0, 0, 0, 0, 0, 0, 0);
        // fully-fused flash attention (R + softmax + PV + band rel-v)
        flash_attn<<<dim3(64, 16), 256, 0, stream>>>(qk, vt, erk + i * 576, kb,
                                                     erv + i * 576, attn_out);
        // O projection -- BN=64: 1024 blocks
        gemm_nt<64, 64, 0, 0, 1, 0, 0><<<dim3(128, 8, 1), 256, 0, stream>>>(
            Wo_l, attn_out, ybuf, attn_b + (i * 4 + 3) * 512, nullptr, zpage,
            512, 512, 512, 512, 0, 0, 0, 0, 0, 0, 0);
        // LN1 (xbf masked for conv1 input)
        ln_residual<1><<<2048, 256, 0, stream>>>(xres, ybuf, xbf,
                                                 ln1g + i * 512, ln1b + i * 512, xmask);
        // conv1 (K=3*512) + bias + relu + mask  -- BM=64: 2048 blocks, 8/CU
        gemm_nt<64, 128, 0, 1, 1, 1, 1><<<dim3(64, 32, 1), 256, 0, stream>>>(
            W1p_l, xbf, hbuf, b1in + i * 2048, xmask, zpage,
            1536, 1536, 512, 2048, 512, 0, 0, 0, 0, 0, 0);
        // conv2 split-K by tap: partials [3][8192][512] bf16 (1536 blocks)
        gemm_nt<64, 128, 0, 2, 0, 0, 0><<<dim3(64, 8, 3), 256, 0, stream>>>(
            W2p_l, hbuf, part, nullptr, nullptr, zpage,
            2048, 6144, 2048, 512, 2048, 0, 0, 0, 0, 0, 0);
        // LN2 fused with partial reduce + bias + mask
        ln_residual_p3<<<2048, 256, 0, stream>>>(xres, part, xbf,
                                                 ln2g + i * 512, ln2b + i * 512,
                                                 b2in + i * 512, xmask);
    }

    transpose_out_k<<<dim3(32, 16, 8), 256, 0, stream>>>(xres, xmask, out);
}